// Round 3
// baseline (124826.733 us; speedup 1.0000x reference)
//
#include <hip/hip_runtime.h>
#include <stdint.h>

#define NB 128      // batch
#define NH 512      // hidden
#define NE 128      // embedding dim
#define NVOC 32000  // vocab
#define NNV 196     // visual tokens
#define NDV 256     // visual dim
#define NSTEPS 32
#define SORTSTRIDE 32768
#define NBUCKET 4096

// ---------------- Threefry-2x32 (20 rounds), exact JAX semantics --------------
static __device__ __forceinline__ uint32_t rotl32(uint32_t x, int r){
  return (x << r) | (x >> (32 - r));
}

static __device__ __forceinline__ void threefry2x32(uint32_t k0, uint32_t k1,
    uint32_t x0, uint32_t x1, uint32_t &o0, uint32_t &o1){
  uint32_t k2 = k0 ^ k1 ^ 0x1BD11BDAu;
  x0 += k0; x1 += k1;
#define TF_RND(r) { x0 += x1; x1 = rotl32(x1,(r)); x1 ^= x0; }
  TF_RND(13) TF_RND(15) TF_RND(26) TF_RND(6)
  x0 += k1; x1 += k2 + 1u;
  TF_RND(17) TF_RND(29) TF_RND(16) TF_RND(24)
  x0 += k2; x1 += k0 + 2u;
  TF_RND(13) TF_RND(15) TF_RND(26) TF_RND(6)
  x0 += k0; x1 += k1 + 3u;
  TF_RND(17) TF_RND(29) TF_RND(16) TF_RND(24)
  x0 += k1; x1 += k2 + 4u;
  TF_RND(13) TF_RND(15) TF_RND(26) TF_RND(6)
  x0 += k2; x1 += k0 + 5u;
#undef TF_RND
  o0 = x0; o1 = x1;
}

// ---------------- visual projection + LayerNorm ------------------------------
__global__ __launch_bounds__(256) void k_visproj(
    const float* __restrict__ vf, const float* __restrict__ vis_w,
    const float* __restrict__ vis_b, const float* __restrict__ ln_g,
    const float* __restrict__ ln_b, float* __restrict__ vp)
{
  int bn = blockIdx.x;                 // b*NNV + n
  int tid = threadIdx.x;
  __shared__ float xs[NDV];
  __shared__ float red[256];
  const float* x = vf + (size_t)bn * NDV;
  xs[tid] = x[tid];                    // 256 threads == NDV
  __syncthreads();
  float out0, out1;
  {
    const float4* h4 = (const float4*)xs;
    const float4* w0 = (const float4*)(vis_w + (size_t)tid * NDV);
    const float4* w1 = (const float4*)(vis_w + (size_t)(tid + 256) * NDV);
    float a0 = 0.f, a1 = 0.f;
    #pragma unroll 4
    for (int k = 0; k < NDV/4; k++){
      float4 hh = h4[k];
      float4 wa = w0[k], wb = w1[k];
      a0 = fmaf(hh.x, wa.x, a0); a0 = fmaf(hh.y, wa.y, a0);
      a0 = fmaf(hh.z, wa.z, a0); a0 = fmaf(hh.w, wa.w, a0);
      a1 = fmaf(hh.x, wb.x, a1); a1 = fmaf(hh.y, wb.y, a1);
      a1 = fmaf(hh.z, wb.z, a1); a1 = fmaf(hh.w, wb.w, a1);
    }
    out0 = a0 + vis_b[tid];
    out1 = a1 + vis_b[tid + 256];
  }
  red[tid] = out0 + out1; __syncthreads();
  for (int s = 128; s > 0; s >>= 1){ if (tid < s) red[tid] += red[tid + s]; __syncthreads(); }
  float mu = red[0] * (1.0f / (float)NH);
  __syncthreads();
  float d0 = out0 - mu, d1 = out1 - mu;
  red[tid] = d0*d0 + d1*d1; __syncthreads();
  for (int s = 128; s > 0; s >>= 1){ if (tid < s) red[tid] += red[tid + s]; __syncthreads(); }
  float var = red[0] * (1.0f / (float)NH);
  float r = 1.0f / sqrtf(var + 1e-5f);
  float* op = vp + (size_t)bn * NH;
  op[tid]       = d0 * r * ln_g[tid]       + ln_b[tid];
  op[tid + 256] = d1 * r * ln_g[tid + 256] + ln_b[tid + 256];
}

// ---------------- init hidden states ------------------------------------------
__global__ void k_init(const float* __restrict__ thought,
                       float* __restrict__ h0, float* __restrict__ c0,
                       float* __restrict__ h1, float* __restrict__ c1)
{
  int id = blockIdx.x * 256 + threadIdx.x;
  if (id >= NH * NB) return;
  int k = id >> 7;
  int b = id & 127;
  float v = thought[(size_t)b * NH + k];
  h0[id] = v; h1[id] = v; c0[id] = 0.f; c1[id] = 0.f;
}

// ---------------- fused LSTM layer (GEMM + cell) -------------------------------
// States stored k-major: [NH][NB]. grid = (32 j-tiles of 16, 2 b-tiles of 64).
template<int K1>
__global__ __launch_bounds__(256) void k_lstm(
    const float* __restrict__ wih, const float* __restrict__ whh,
    const float* __restrict__ bih, const float* __restrict__ bhh,
    const float* __restrict__ a1,       // K1==NE: emb table (gather via toks); else [K1][NB]
    const int*   __restrict__ toks, int step,
    const float* __restrict__ hprev, const float* __restrict__ cprev,
    float* __restrict__ hout, float* __restrict__ cout)
{
  __shared__ float As[64][64];
  __shared__ float Ws[4 * 16 * 68];
  __shared__ int tokl[64];
  int tid = threadIdx.x;
  int jl = tid & 15;
  int bg = tid >> 4;
  int jbase = blockIdx.x * 16;
  int j = jbase + jl;
  int bblk = blockIdx.y * 64;
  int bl = bg * 4;
  if (K1 == NE){
    if (tid < 64) tokl[tid] = (step == 0) ? 1 : toks[(size_t)(bblk + tid) * NSTEPS + step - 1];
  }
  __syncthreads();

  float acc[4][4];
  #pragma unroll
  for (int g = 0; g < 4; g++)
    #pragma unroll
    for (int e = 0; e < 4; e++) acc[g][e] = 0.f;

  for (int part = 0; part < 2; part++){
    const float* Wsrc = part ? whh : wih;
    const float* Asrc = part ? hprev : a1;
    const int K = part ? NH : K1;
    const bool gather = (!part) && (K1 == NE);
    for (int kc = 0; kc < K; kc += 64){
      __syncthreads();
      for (int q = tid; q < 1024; q += 256){
        int kk = q >> 4;
        int bb = (q & 15) << 2;
        float4 v;
        if (gather){
          v.x = Asrc[(size_t)tokl[bb+0] * NE + kc + kk];
          v.y = Asrc[(size_t)tokl[bb+1] * NE + kc + kk];
          v.z = Asrc[(size_t)tokl[bb+2] * NE + kc + kk];
          v.w = Asrc[(size_t)tokl[bb+3] * NE + kc + kk];
        } else {
          v = *(const float4*)(Asrc + (size_t)(kc + kk) * NB + bblk + bb);
        }
        *(float4*)&As[kk][bb] = v;
      }
      for (int q = tid; q < 1024; q += 256){
        int r = q >> 4;
        int f = q & 15;
        int g = r >> 4;
        int jj = r & 15;
        float4 w = *(const float4*)(Wsrc + (size_t)(g * NH + jbase + jj) * K + kc + f * 4);
        float* wd = &Ws[(g * 16 + jj) * 68 + f * 4];
        wd[0] = w.x; wd[1] = w.y; wd[2] = w.z; wd[3] = w.w;
      }
      __syncthreads();
      #pragma unroll 2
      for (int kk = 0; kk < 64; kk += 4){
        float4 a0 = *(const float4*)&As[kk + 0][bl];
        float4 a1v = *(const float4*)&As[kk + 1][bl];
        float4 a2 = *(const float4*)&As[kk + 2][bl];
        float4 a3 = *(const float4*)&As[kk + 3][bl];
        #pragma unroll
        for (int g = 0; g < 4; g++){
          float4 w = *(const float4*)&Ws[(g * 16 + jl) * 68 + kk];
          acc[g][0] = fmaf(a0.x, w.x, acc[g][0]);
          acc[g][1] = fmaf(a0.y, w.x, acc[g][1]);
          acc[g][2] = fmaf(a0.z, w.x, acc[g][2]);
          acc[g][3] = fmaf(a0.w, w.x, acc[g][3]);
          acc[g][0] = fmaf(a1v.x, w.y, acc[g][0]);
          acc[g][1] = fmaf(a1v.y, w.y, acc[g][1]);
          acc[g][2] = fmaf(a1v.z, w.y, acc[g][2]);
          acc[g][3] = fmaf(a1v.w, w.y, acc[g][3]);
          acc[g][0] = fmaf(a2.x, w.z, acc[g][0]);
          acc[g][1] = fmaf(a2.y, w.z, acc[g][1]);
          acc[g][2] = fmaf(a2.z, w.z, acc[g][2]);
          acc[g][3] = fmaf(a2.w, w.z, acc[g][3]);
          acc[g][0] = fmaf(a3.x, w.w, acc[g][0]);
          acc[g][1] = fmaf(a3.y, w.w, acc[g][1]);
          acc[g][2] = fmaf(a3.z, w.w, acc[g][2]);
          acc[g][3] = fmaf(a3.w, w.w, acc[g][3]);
        }
      }
    }
  }

  float bi[4];
  #pragma unroll
  for (int g = 0; g < 4; g++) bi[g] = bih[g * NH + j] + bhh[g * NH + j];
  int b0g = bblk + bl;
  float4 cp = *(const float4*)(cprev + (size_t)j * NB + b0g);
  float cpv[4] = {cp.x, cp.y, cp.z, cp.w};
  float hs[4], cs[4];
  #pragma unroll
  for (int e = 0; e < 4; e++){
    float zi = acc[0][e] + bi[0];
    float zf = acc[1][e] + bi[1];
    float zg = acc[2][e] + bi[2];
    float zo = acc[3][e] + bi[3];
    float si = 1.f / (1.f + expf(-zi));
    float sf = 1.f / (1.f + expf(-zf));
    float so = 1.f / (1.f + expf(-zo));
    float tg = tanhf(zg);
    float c2 = sf * cpv[e] + si * tg;
    cs[e] = c2;
    hs[e] = so * tanhf(c2);
  }
  *(float4*)(cout + (size_t)j * NB + b0g) = make_float4(cs[0], cs[1], cs[2], cs[3]);
  *(float4*)(hout + (size_t)j * NB + b0g) = make_float4(hs[0], hs[1], hs[2], hs[3]);
}

// ---------------- gate + visual attention --------------------------------------
__global__ __launch_bounds__(256) void k_gateattn(
    const float* __restrict__ h1t,
    const float* __restrict__ gw1, const float* __restrict__ gb1,
    const float* __restrict__ gw2, const float* __restrict__ gb2,
    const float* __restrict__ vp,
    float* __restrict__ o2t)
{
  int b = blockIdx.x;
  int tid = threadIdx.x;
  __shared__ float hsm[NH];
  __shared__ float tsm[NH];
  __shared__ float osm[NH];
  __shared__ float aw[NNV];
  __shared__ float red[256];
  for (int h = tid; h < NH; h += 256) hsm[h] = h1t[(size_t)h * NB + b];
  __syncthreads();
  for (int jj = tid; jj < NH; jj += 256){
    const float4* wr = (const float4*)(gw1 + (size_t)jj * NH);
    const float4* h4 = (const float4*)hsm;
    float acc = 0.f;
    #pragma unroll 4
    for (int k = 0; k < NH/4; k++){
      float4 w = wr[k]; float4 hh = h4[k];
      acc = fmaf(hh.x, w.x, acc);
      acc = fmaf(hh.y, w.y, acc);
      acc = fmaf(hh.z, w.z, acc);
      acc = fmaf(hh.w, w.w, acc);
    }
    tsm[jj] = tanhf(acc + gb1[jj]);
  }
  __syncthreads();
  float part = 0.f;
  for (int jj = tid; jj < NH; jj += 256) part = fmaf(tsm[jj], gw2[jj], part);
  red[tid] = part; __syncthreads();
  for (int s = 128; s > 0; s >>= 1){ if (tid < s) red[tid] += red[tid + s]; __syncthreads(); }
  float gate = 1.f / (1.f + expf(-(red[0] + gb2[0])));
  __syncthreads();
  for (int h = tid; h < NH; h += 256) osm[h] = hsm[h] * gate;
  __syncthreads();
  const float* vpb = vp + (size_t)b * NNV * NH;
  float sc = 0.f;
  if (tid < NNV){
    const float4* vr = (const float4*)(vpb + (size_t)tid * NH);
    const float4* o4 = (const float4*)osm;
    float accv = 0.f;
    #pragma unroll 4
    for (int k = 0; k < NH/4; k++){
      float4 v = vr[k]; float4 oo = o4[k];
      accv = fmaf(oo.x, v.x, accv);
      accv = fmaf(oo.y, v.y, accv);
      accv = fmaf(oo.z, v.z, accv);
      accv = fmaf(oo.w, v.w, accv);
    }
    sc = accv / 22.62741699796952f;   // scores / sqrt(512)
  }
  red[tid] = (tid < NNV) ? sc : -INFINITY;
  __syncthreads();
  for (int s = 128; s > 0; s >>= 1){ if (tid < s) red[tid] = fmaxf(red[tid], red[tid + s]); __syncthreads(); }
  float mx = red[0];
  __syncthreads();
  float ev = (tid < NNV) ? expf(sc - mx) : 0.f;
  red[tid] = ev; __syncthreads();
  for (int s = 128; s > 0; s >>= 1){ if (tid < s) red[tid] += red[tid + s]; __syncthreads(); }
  float zs = red[0];
  if (tid < NNV) aw[tid] = ev / zs;
  __syncthreads();
  for (int h = tid; h < NH; h += 256){
    float accv = 0.f;
    for (int n = 0; n < NNV; n++) accv = fmaf(aw[n], vpb[(size_t)n * NH + h], accv);
    o2t[(size_t)h * NB + b] = osm[h] + accv;
  }
}

// ---------------- logits GEMM + rep-penalty + temperature -----------------------
// 64 vocab x 128 batch per block; 256 threads; 2 vocab x 16 batch per thread.
__global__ __launch_bounds__(256, 4) void k_logits(
    const float* __restrict__ o2t,     // [NH][NB]
    const float* __restrict__ outw,    // [NVOC][NH]
    const float* __restrict__ outb,
    const int* __restrict__ toks, int step,
    float* __restrict__ logits)        // [NB][NVOC]
{
  __shared__ float osh[32][NB];        // 16 KB
  __shared__ float wsh[32][72];        // 9 KB (64 vocab + pad)
  __shared__ int hist[NB][3];
  int tid = threadIdx.x;
  int vbase = blockIdx.x * 64;
  int vl = (tid & 31) * 2;
  int b0 = (tid >> 5) * 16;
  if (tid < NB){
    hist[tid][0] = (step >= 1) ? toks[(size_t)tid * NSTEPS + step - 1] : -1;
    hist[tid][1] = (step >= 2) ? toks[(size_t)tid * NSTEPS + step - 2] : -1;
    hist[tid][2] = (step >= 3) ? toks[(size_t)tid * NSTEPS + step - 3] : -1;
  }
  float acc0[16], acc1[16];
  #pragma unroll
  for (int i = 0; i < 16; i++){ acc0[i] = 0.f; acc1[i] = 0.f; }

  for (int hc = 0; hc < NH; hc += 32){
    __syncthreads();
    #pragma unroll
    for (int q = tid; q < 1024; q += 256){
      int kk = q >> 5;
      int bb = (q & 31) << 2;
      *(float4*)&osh[kk][bb] = *(const float4*)(o2t + (size_t)(hc + kk) * NB + bb);
    }
    #pragma unroll
    for (int q = tid; q < 512; q += 256){
      int vr = q >> 3;
      int f4 = q & 7;
      float4 w = *(const float4*)(outw + (size_t)(vbase + vr) * NH + hc + f4 * 4);
      wsh[f4*4 + 0][vr] = w.x;
      wsh[f4*4 + 1][vr] = w.y;
      wsh[f4*4 + 2][vr] = w.z;
      wsh[f4*4 + 3][vr] = w.w;
    }
    __syncthreads();
    #pragma unroll 4
    for (int hl = 0; hl < 32; hl++){
      float w0 = wsh[hl][vl];
      float w1 = wsh[hl][vl + 1];
      #pragma unroll
      for (int bq = 0; bq < 4; bq++){
        float4 a = *(const float4*)&osh[hl][b0 + bq * 4];
        acc0[bq*4+0] = fmaf(a.x, w0, acc0[bq*4+0]);
        acc1[bq*4+0] = fmaf(a.x, w1, acc1[bq*4+0]);
        acc0[bq*4+1] = fmaf(a.y, w0, acc0[bq*4+1]);
        acc1[bq*4+1] = fmaf(a.y, w1, acc1[bq*4+1]);
        acc0[bq*4+2] = fmaf(a.z, w0, acc0[bq*4+2]);
        acc1[bq*4+2] = fmaf(a.z, w1, acc1[bq*4+2]);
        acc0[bq*4+3] = fmaf(a.w, w0, acc0[bq*4+3]);
        acc1[bq*4+3] = fmaf(a.w, w1, acc1[bq*4+3]);
      }
    }
  }
  __syncthreads();
  int v0 = vbase + vl;
  int v1 = v0 + 1;
  float ob0 = outb[v0], ob1 = outb[v1];
  #pragma unroll
  for (int i = 0; i < 16; i++){
    int b = b0 + i;
    float l0 = acc0[i] + ob0;
    float l1 = acc1[i] + ob1;
    int h1v = hist[b][0], h2v = hist[b][1], h3v = hist[b][2];
    if (v0 == h1v || v0 == h2v || v0 == h3v) l0 -= 2.0f;
    if (v1 == h1v || v1 == h2v || v1 == h3v) l1 -= 2.0f;
    l0 = l0 / 0.8f;
    l1 = l1 / 0.8f;
    *(float2*)(logits + (size_t)b * NVOC + v0) = make_float2(l0, l1);
  }
}

// ---------------- per-row stats: max, Z (softmax denom), min --------------------
__global__ __launch_bounds__(256) void k_rowstats(
    const float* __restrict__ logits, float* __restrict__ stats)
{
  int b = blockIdx.x, tid = threadIdx.x;
  const float4* lr = (const float4*)(logits + (size_t)b * NVOC);
  float mx = -INFINITY, mn = INFINITY;
  for (int i = tid; i < NVOC/4; i += 256){
    float4 v = lr[i];
    mx = fmaxf(mx, fmaxf(fmaxf(v.x, v.y), fmaxf(v.z, v.w)));
    mn = fminf(mn, fminf(fminf(v.x, v.y), fminf(v.z, v.w)));
  }
  __shared__ float ra[256], rb[256];
  ra[tid] = mx; rb[tid] = mn; __syncthreads();
  for (int s = 128; s > 0; s >>= 1){
    if (tid < s){ ra[tid] = fmaxf(ra[tid], ra[tid+s]); rb[tid] = fminf(rb[tid], rb[tid+s]); }
    __syncthreads();
  }
  float M = ra[0], mnv = rb[0];
  __syncthreads();
  float z = 0.f;
  for (int i = tid; i < NVOC/4; i += 256){
    float4 v = lr[i];
    z += expf(v.x - M) + expf(v.y - M) + expf(v.z - M) + expf(v.w - M);
  }
  ra[tid] = z; __syncthreads();
  for (int s = 128; s > 0; s >>= 1){ if (tid < s) ra[tid] += ra[tid+s]; __syncthreads(); }
  if (tid == 0) *(float4*)(stats + b * 4) = make_float4(M, ra[0], mnv, 0.f);
}

// ---------------- top-p (exact fp32 sequential cumsum) + gumbel sample ----------
// Serial scan rewritten register-lean (6 live float4, depth-2 prefetch from LDS)
// so the prefetch buffer cannot spill to scratch. Add/compare sequence is
// bit-identical to the previous passing version.
__global__ __launch_bounds__(1024) void k_sample(
    const float* __restrict__ logits,
    const float* __restrict__ stats,
    float* __restrict__ sortbuf,
    int* __restrict__ toks,
    int step)
{
  int b = blockIdx.x, tid = threadIdx.x;
  const float* lr = logits + (size_t)b * NVOC;
  float* sbuf = sortbuf + (size_t)b * SORTSTRIDE;
  __shared__ int cnt[NBUCKET];
  __shared__ int base[NBUCKET];
  __shared__ float pch[2048];
  __shared__ int s0[1024];
  __shared__ float redv[1024];
  __shared__ int redi[1024];
  __shared__ float sh_t;
  __shared__ int sh_c, sh_k, sh_cross;

  float4 st4 = *(const float4*)(stats + b * 4);
  float M = st4.x, Z = st4.y, mn = st4.z;
  float range = M - mn;
  float scale = (range > 0.f) ? (float)(NBUCKET - 1) / range : 0.f;

  for (int i = tid; i < NBUCKET; i += 1024) cnt[i] = 0;
  __syncthreads();
  for (int i = tid; i < NVOC; i += 1024){
    float l = lr[i];
    int bk = (int)((l - mn) * scale);
    bk = max(0, min(NBUCKET - 1, bk));
    atomicAdd(&cnt[bk], 1);
  }
  __syncthreads();
  // descending-bucket exclusive offsets
  int t4 = tid << 2;
  int c0v = cnt[t4], c1v = cnt[t4+1], c2v = cnt[t4+2], c3v = cnt[t4+3];
  s0[tid] = c0v + c1v + c2v + c3v;
  __syncthreads();
  for (int off = 1; off < 1024; off <<= 1){
    int v = s0[tid];
    int add = (tid + off < 1024) ? s0[tid + off] : 0;
    __syncthreads();
    s0[tid] = v + add;
    __syncthreads();
  }
  int exc = (tid < 1023) ? s0[tid + 1] : 0;
  base[t4+3] = exc;
  base[t4+2] = exc + c3v;
  base[t4+1] = exc + c3v + c2v;
  base[t4+0] = exc + c3v + c2v + c1v;
  __syncthreads();
  for (int i = tid; i < NBUCKET; i += 1024) cnt[i] = 0;
  __syncthreads();
  // scatter by bucket
  for (int i = tid; i < NVOC; i += 1024){
    float l = lr[i];
    int bk = (int)((l - mn) * scale);
    bk = max(0, min(NBUCKET - 1, bk));
    int pos = base[bk] + atomicAdd(&cnt[bk], 1);
    sbuf[pos] = l;
  }
  __threadfence_block();
  __syncthreads();
  // per-segment descending insertion sort (values only; ties identical bits)
  for (int bk = tid; bk < NBUCKET; bk += 1024){
    int n = cnt[bk];
    if (n > 1){
      float* seg = sbuf + base[bk];
      for (int i = 1; i < n; i++){
        float key = seg[i];
        int jj = i - 1;
        while (jj >= 0 && seg[jj] < key){ seg[jj + 1] = seg[jj]; jj--; }
        seg[jj + 1] = key;
      }
    }
  }
  __threadfence_block();
  __syncthreads();

  if (tid == 0){ sh_cross = 0; sh_k = NVOC - 1; }
  __syncthreads();

  // exact fp32 sequential cumsum of p = exp(sorted - M)/Z until > 0.9
  float scum = 0.f;
  for (int cb = 0; cb < NVOC; cb += 2048){
    int lim = min(2048, NVOC - cb);
    for (int i = tid; i < lim; i += 1024){
      pch[i] = expf(sbuf[cb + i] - M) / Z;
    }
    __syncthreads();
    if (tid == 0 && sh_cross == 0){
      const float4* p4 = (const float4*)pch;
      int ng = lim >> 3;               // groups of 8 (lim is 2048 or 1280)
      float4 c0 = p4[0], c1 = p4[1];   // current group
      float4 d0, d1;                   // next group
      if (ng > 1){ d0 = p4[2]; d1 = p4[3]; }
      int done = 0;
      for (int g = 0; g < ng; g++){
        float4 e0, e1;                 // group g+2 (prefetch)
        if (g + 2 < ng){ e0 = p4[(g + 2) * 2]; e1 = p4[(g + 2) * 2 + 1]; }
        float t0 = scum + c0.x; float t1 = t0 + c0.y;
        float t2 = t1 + c0.z;  float t3 = t2 + c0.w;
        float u0 = t3 + c1.x;  float u1 = u0 + c1.y;
        float u2 = u1 + c1.z;  float u3 = u2 + c1.w;
        if (u3 > 0.9f){
          int kk = (t0>0.9f)?0:((t1>0.9f)?1:((t2>0.9f)?2:((t3>0.9f)?3:
                   ((u0>0.9f)?4:((u1>0.9f)?5:((u2>0.9f)?6:7))))));
          sh_k = cb + g * 8 + kk;
          done = 1;
          break;
        }
        scum = u3;
        c0 = d0; c1 = d1;
        d0 = e0; d1 = e1;
      }
      if (done) sh_cross = 1;
    }
    __syncthreads();
    if (sh_cross) break;
  }

  if (tid == 0){
    int ks = sh_k;
    float tv = sbuf[ks];
    int jlo = ks;
    while (jlo > 0 && sbuf[jlo - 1] == tv) jlo--;
    sh_t = tv;
    sh_c = ks + 1 - jlo;   // how many tokens equal to tv are kept (in stable index order)
  }
  __syncthreads();

  float tval = sh_t;
  int ckeep = sh_c;
  // rank-among-equals (stable argsort tie order = ascending original index)
  int stt = tid * 32;
  int en = min(stt + 32, NVOC);
  int eqc = 0;
  for (int i = stt; i < en; i++) eqc += (lr[i] == tval) ? 1 : 0;
  s0[tid] = eqc;
  __syncthreads();
  for (int off = 1; off < 1024; off <<= 1){
    int v = s0[tid];
    int add = (tid >= off) ? s0[tid - off] : 0;
    __syncthreads();
    s0[tid] = v + add;
    __syncthreads();
  }
  int eqrank = s0[tid] - eqc;

  // gumbel-max over kept set; JAX partitionable threefry bits = y0 ^ y1
  uint32_t fk0, fk1;
  threefry2x32(0u, 42u, 0u, (uint32_t)step, fk0, fk1);   // fold_in(key(42), step)
  float best = -INFINITY;
  int besti = NVOC;
  for (int i = stt; i < en; i++){
    float l = lr[i];
    bool keep;
    if (l > tval) keep = true;
    else if (l == tval){ keep = (eqrank < ckeep); eqrank++; }
    else keep = false;
    if (keep){
      uint32_t o0, o1;
      threefry2x32(fk0, fk1, 0u, (uint32_t)(b * NVOC + i), o0, o1);
      uint32_t bits = o0 ^ o1;
      uint32_t fb = (bits >> 9) | 0x3f800000u;
      float u = __uint_as_float(fb) - 1.0f;
      if (u == 0.0f) u = 1.17549435e-38f;   // minval = tiny
      float gum = -logf(-logf(u));
      float cand = l + gum;
      if (cand > best){ best = cand; besti = i; }
    }
  }
  redv[tid] = best;
  redi[tid] = besti;
  __syncthreads();
  for (int s = 512; s > 0; s >>= 1){
    if (tid < s){
      float ov = redv[tid + s]; int oi = redi[tid + s];
      if (ov > redv[tid] || (ov == redv[tid] && oi < redi[tid])){
        redv[tid] = ov; redi[tid] = oi;
      }
    }
    __syncthreads();
  }
  if (tid == 0) toks[(size_t)b * NSTEPS + step] = redi[0];
}

// ---------------- host launcher -------------------------------------------------
extern "C" void kernel_launch(void* const* d_in, const int* in_sizes, int n_in,
                              void* d_out, int out_size, void* d_ws, size_t ws_size,
                              hipStream_t stream)
{
  (void)in_sizes; (void)n_in; (void)out_size;
  const float* thought = (const float*)d_in[0];
  const float* vfeat   = (const float*)d_in[1];
  const float* emb     = (const float*)d_in[2];
  const float* w_ih0   = (const float*)d_in[3];
  const float* w_hh0   = (const float*)d_in[4];
  const float* b_ih0   = (const float*)d_in[5];
  const float* b_hh0   = (const float*)d_in[6];
  const float* w_ih1   = (const float*)d_in[7];
  const float* w_hh1   = (const float*)d_in[8];
  const float* b_ih1   = (const float*)d_in[9];
  const float* b_hh1   = (const float*)d_in[10];
  const float* gw1     = (const float*)d_in[11];
  const float* gb1     = (const float*)d_in[12];
  const float* gw2     = (const float*)d_in[13];
  const float* gb2     = (const float*)d_in[14];
  const float* out_w   = (const float*)d_in[15];
  const float* out_b   = (const float*)d_in[16];
  const float* vis_w   = (const float*)d_in[17];
  const float* vis_b   = (const float*)d_in[18];
  const float* ln_g    = (const float*)d_in[19];
  const float* ln_b    = (const float*)d_in[20];
  int* toks = (int*)d_out;

  char* ws = (char*)d_ws;
  size_t off = 0;
  auto alloc = [&](size_t bytes) -> void* {
    void* p = ws + off;
    off += (bytes + 255) & ~(size_t)255;
    return p;
  };
  float* vp      = (float*)alloc((size_t)NB * NNV * NH * 4);
  float* h0a     = (float*)alloc((size_t)NH * NB * 4);
  float* h0b     = (float*)alloc((size_t)NH * NB * 4);
  float* c0a     = (float*)alloc((size_t)NH * NB * 4);
  float* c0b     = (float*)alloc((size_t)NH * NB * 4);
  float* h1a     = (float*)alloc((size_t)NH * NB * 4);
  float* h1b     = (float*)alloc((size_t)NH * NB * 4);
  float* c1a     = (float*)alloc((size_t)NH * NB * 4);
  float* c1b     = (float*)alloc((size_t)NH * NB * 4);
  float* o2t     = (float*)alloc((size_t)NH * NB * 4);
  float* logits  = (float*)alloc((size_t)NB * NVOC * 4);
  float* sortbuf = (float*)alloc((size_t)NB * SORTSTRIDE * 4);
  float* stats   = (float*)alloc((size_t)NB * 4 * 4);
  if (off > ws_size) return;  // insufficient scratch: fail loudly via wrong output

  k_visproj<<<NB * NNV, 256, 0, stream>>>(vfeat, vis_w, vis_b, ln_g, ln_b, vp);
  k_init<<<(NH * NB + 255) / 256, 256, 0, stream>>>(thought, h0a, c0a, h1a, c1a);

  for (int step = 0; step < NSTEPS; step++){
    float *h0r, *h0w, *c0r, *c0w, *h1r, *h1w, *c1r, *c1w;
    if ((step & 1) == 0){
      h0r = h0a; h0w = h0b; c0r = c0a; c0w = c0b;
      h1r = h1a; h1w = h1b; c1r = c1a; c1w = c1b;
    } else {
      h0r = h0b; h0w = h0a; c0r = c0b; c0w = c0a;
      h1r = h1b; h1w = h1a; c1r = c1b; c1w = c1a;
    }
    k_lstm<NE><<<dim3(32, 2), 256, 0, stream>>>(
        w_ih0, w_hh0, b_ih0, b_hh0, emb, toks, step, h0r, c0r, h0w, c0w);
    k_lstm<NH><<<dim3(32, 2), 256, 0, stream>>>(
        w_ih1, w_hh1, b_ih1, b_hh1, h0w, toks, step, h1r, c1r, h1w, c1w);
    k_gateattn<<<NB, 256, 0, stream>>>(h1w, gw1, gb1, gw2, gb2, vp, o2t);
    k_logits<<<NVOC / 64, 256, 0, stream>>>(o2t, out_w, out_b, toks, step, logits);
    k_rowstats<<<NB, 256, 0, stream>>>(logits, stats);
    k_sample<<<NB, 1024, 0, stream>>>(logits, stats, sortbuf, toks, step);
  }
}

// Round 4
// 123412.244 us; speedup vs baseline: 1.0115x; 1.0115x over previous
//
#include <hip/hip_runtime.h>
#include <stdint.h>

#define NB 128      // batch
#define NH 512      // hidden
#define NE 128      // embedding dim
#define NVOC 32000  // vocab
#define NNV 196     // visual tokens
#define NDV 256     // visual dim
#define NSTEPS 32
#define SORTSTRIDE 32768
#define NBUCKET 4096
#define SCHUNK 8192

// ---------------- Threefry-2x32 (20 rounds), exact JAX semantics --------------
static __device__ __forceinline__ uint32_t rotl32(uint32_t x, int r){
  return (x << r) | (x >> (32 - r));
}

static __device__ __forceinline__ void threefry2x32(uint32_t k0, uint32_t k1,
    uint32_t x0, uint32_t x1, uint32_t &o0, uint32_t &o1){
  uint32_t k2 = k0 ^ k1 ^ 0x1BD11BDAu;
  x0 += k0; x1 += k1;
#define TF_RND(r) { x0 += x1; x1 = rotl32(x1,(r)); x1 ^= x0; }
  TF_RND(13) TF_RND(15) TF_RND(26) TF_RND(6)
  x0 += k1; x1 += k2 + 1u;
  TF_RND(17) TF_RND(29) TF_RND(16) TF_RND(24)
  x0 += k2; x1 += k0 + 2u;
  TF_RND(13) TF_RND(15) TF_RND(26) TF_RND(6)
  x0 += k0; x1 += k1 + 3u;
  TF_RND(17) TF_RND(29) TF_RND(16) TF_RND(24)
  x0 += k1; x1 += k2 + 4u;
  TF_RND(13) TF_RND(15) TF_RND(26) TF_RND(6)
  x0 += k2; x1 += k0 + 5u;
#undef TF_RND
  o0 = x0; o1 = x1;
}

// ---------------- visual projection + LayerNorm ------------------------------
__global__ __launch_bounds__(256) void k_visproj(
    const float* __restrict__ vf, const float* __restrict__ vis_w,
    const float* __restrict__ vis_b, const float* __restrict__ ln_g,
    const float* __restrict__ ln_b, float* __restrict__ vp)
{
  int bn = blockIdx.x;                 // b*NNV + n
  int tid = threadIdx.x;
  __shared__ float xs[NDV];
  __shared__ float red[256];
  const float* x = vf + (size_t)bn * NDV;
  xs[tid] = x[tid];                    // 256 threads == NDV
  __syncthreads();
  float out0, out1;
  {
    const float4* h4 = (const float4*)xs;
    const float4* w0 = (const float4*)(vis_w + (size_t)tid * NDV);
    const float4* w1 = (const float4*)(vis_w + (size_t)(tid + 256) * NDV);
    float a0 = 0.f, a1 = 0.f;
    #pragma unroll 4
    for (int k = 0; k < NDV/4; k++){
      float4 hh = h4[k];
      float4 wa = w0[k], wb = w1[k];
      a0 = fmaf(hh.x, wa.x, a0); a0 = fmaf(hh.y, wa.y, a0);
      a0 = fmaf(hh.z, wa.z, a0); a0 = fmaf(hh.w, wa.w, a0);
      a1 = fmaf(hh.x, wb.x, a1); a1 = fmaf(hh.y, wb.y, a1);
      a1 = fmaf(hh.z, wb.z, a1); a1 = fmaf(hh.w, wb.w, a1);
    }
    out0 = a0 + vis_b[tid];
    out1 = a1 + vis_b[tid + 256];
  }
  red[tid] = out0 + out1; __syncthreads();
  for (int s = 128; s > 0; s >>= 1){ if (tid < s) red[tid] += red[tid + s]; __syncthreads(); }
  float mu = red[0] * (1.0f / (float)NH);
  __syncthreads();
  float d0 = out0 - mu, d1 = out1 - mu;
  red[tid] = d0*d0 + d1*d1; __syncthreads();
  for (int s = 128; s > 0; s >>= 1){ if (tid < s) red[tid] += red[tid + s]; __syncthreads(); }
  float var = red[0] * (1.0f / (float)NH);
  float r = 1.0f / sqrtf(var + 1e-5f);
  float* op = vp + (size_t)bn * NH;
  op[tid]       = d0 * r * ln_g[tid]       + ln_b[tid];
  op[tid + 256] = d1 * r * ln_g[tid + 256] + ln_b[tid + 256];
}

// ---------------- init hidden states ------------------------------------------
__global__ void k_init(const float* __restrict__ thought,
                       float* __restrict__ h0, float* __restrict__ c0,
                       float* __restrict__ h1, float* __restrict__ c1)
{
  int id = blockIdx.x * 256 + threadIdx.x;
  if (id >= NH * NB) return;
  int k = id >> 7;
  int b = id & 127;
  float v = thought[(size_t)b * NH + k];
  h0[id] = v; h1[id] = v; c0[id] = 0.f; c1[id] = 0.f;
}

// ---------------- fused LSTM layer (GEMM + cell) -------------------------------
template<int K1>
__global__ __launch_bounds__(256) void k_lstm(
    const float* __restrict__ wih, const float* __restrict__ whh,
    const float* __restrict__ bih, const float* __restrict__ bhh,
    const float* __restrict__ a1,
    const int*   __restrict__ toks, int step,
    const float* __restrict__ hprev, const float* __restrict__ cprev,
    float* __restrict__ hout, float* __restrict__ cout)
{
  __shared__ float As[64][64];
  __shared__ float Ws[4 * 16 * 68];
  __shared__ int tokl[64];
  int tid = threadIdx.x;
  int jl = tid & 15;
  int bg = tid >> 4;
  int jbase = blockIdx.x * 16;
  int j = jbase + jl;
  int bblk = blockIdx.y * 64;
  int bl = bg * 4;
  if (K1 == NE){
    if (tid < 64) tokl[tid] = (step == 0) ? 1 : toks[(size_t)(bblk + tid) * NSTEPS + step - 1];
  }
  __syncthreads();

  float acc[4][4];
  #pragma unroll
  for (int g = 0; g < 4; g++)
    #pragma unroll
    for (int e = 0; e < 4; e++) acc[g][e] = 0.f;

  for (int part = 0; part < 2; part++){
    const float* Wsrc = part ? whh : wih;
    const float* Asrc = part ? hprev : a1;
    const int K = part ? NH : K1;
    const bool gather = (!part) && (K1 == NE);
    for (int kc = 0; kc < K; kc += 64){
      __syncthreads();
      for (int q = tid; q < 1024; q += 256){
        int kk = q >> 4;
        int bb = (q & 15) << 2;
        float4 v;
        if (gather){
          v.x = Asrc[(size_t)tokl[bb+0] * NE + kc + kk];
          v.y = Asrc[(size_t)tokl[bb+1] * NE + kc + kk];
          v.z = Asrc[(size_t)tokl[bb+2] * NE + kc + kk];
          v.w = Asrc[(size_t)tokl[bb+3] * NE + kc + kk];
        } else {
          v = *(const float4*)(Asrc + (size_t)(kc + kk) * NB + bblk + bb);
        }
        *(float4*)&As[kk][bb] = v;
      }
      for (int q = tid; q < 1024; q += 256){
        int r = q >> 4;
        int f = q & 15;
        int g = r >> 4;
        int jj = r & 15;
        float4 w = *(const float4*)(Wsrc + (size_t)(g * NH + jbase + jj) * K + kc + f * 4);
        float* wd = &Ws[(g * 16 + jj) * 68 + f * 4];
        wd[0] = w.x; wd[1] = w.y; wd[2] = w.z; wd[3] = w.w;
      }
      __syncthreads();
      #pragma unroll 2
      for (int kk = 0; kk < 64; kk += 4){
        float4 a0 = *(const float4*)&As[kk + 0][bl];
        float4 a1v = *(const float4*)&As[kk + 1][bl];
        float4 a2 = *(const float4*)&As[kk + 2][bl];
        float4 a3 = *(const float4*)&As[kk + 3][bl];
        #pragma unroll
        for (int g = 0; g < 4; g++){
          float4 w = *(const float4*)&Ws[(g * 16 + jl) * 68 + kk];
          acc[g][0] = fmaf(a0.x, w.x, acc[g][0]);
          acc[g][1] = fmaf(a0.y, w.x, acc[g][1]);
          acc[g][2] = fmaf(a0.z, w.x, acc[g][2]);
          acc[g][3] = fmaf(a0.w, w.x, acc[g][3]);
          acc[g][0] = fmaf(a1v.x, w.y, acc[g][0]);
          acc[g][1] = fmaf(a1v.y, w.y, acc[g][1]);
          acc[g][2] = fmaf(a1v.z, w.y, acc[g][2]);
          acc[g][3] = fmaf(a1v.w, w.y, acc[g][3]);
          acc[g][0] = fmaf(a2.x, w.z, acc[g][0]);
          acc[g][1] = fmaf(a2.y, w.z, acc[g][1]);
          acc[g][2] = fmaf(a2.z, w.z, acc[g][2]);
          acc[g][3] = fmaf(a2.w, w.z, acc[g][3]);
          acc[g][0] = fmaf(a3.x, w.w, acc[g][0]);
          acc[g][1] = fmaf(a3.y, w.w, acc[g][1]);
          acc[g][2] = fmaf(a3.z, w.w, acc[g][2]);
          acc[g][3] = fmaf(a3.w, w.w, acc[g][3]);
        }
      }
    }
  }

  float bi[4];
  #pragma unroll
  for (int g = 0; g < 4; g++) bi[g] = bih[g * NH + j] + bhh[g * NH + j];
  int b0g = bblk + bl;
  float4 cp = *(const float4*)(cprev + (size_t)j * NB + b0g);
  float cpv[4] = {cp.x, cp.y, cp.z, cp.w};
  float hs[4], cs[4];
  #pragma unroll
  for (int e = 0; e < 4; e++){
    float zi = acc[0][e] + bi[0];
    float zf = acc[1][e] + bi[1];
    float zg = acc[2][e] + bi[2];
    float zo = acc[3][e] + bi[3];
    float si = 1.f / (1.f + expf(-zi));
    float sf = 1.f / (1.f + expf(-zf));
    float so = 1.f / (1.f + expf(-zo));
    float tg = tanhf(zg);
    float c2 = sf * cpv[e] + si * tg;
    cs[e] = c2;
    hs[e] = so * tanhf(c2);
  }
  *(float4*)(cout + (size_t)j * NB + b0g) = make_float4(cs[0], cs[1], cs[2], cs[3]);
  *(float4*)(hout + (size_t)j * NB + b0g) = make_float4(hs[0], hs[1], hs[2], hs[3]);
}

// ---------------- gate + visual attention --------------------------------------
__global__ __launch_bounds__(256) void k_gateattn(
    const float* __restrict__ h1t,
    const float* __restrict__ gw1, const float* __restrict__ gb1,
    const float* __restrict__ gw2, const float* __restrict__ gb2,
    const float* __restrict__ vp,
    float* __restrict__ o2t)
{
  int b = blockIdx.x;
  int tid = threadIdx.x;
  __shared__ float hsm[NH];
  __shared__ float tsm[NH];
  __shared__ float osm[NH];
  __shared__ float aw[NNV];
  __shared__ float red[256];
  for (int h = tid; h < NH; h += 256) hsm[h] = h1t[(size_t)h * NB + b];
  __syncthreads();
  for (int jj = tid; jj < NH; jj += 256){
    const float4* wr = (const float4*)(gw1 + (size_t)jj * NH);
    const float4* h4 = (const float4*)hsm;
    float acc = 0.f;
    #pragma unroll 4
    for (int k = 0; k < NH/4; k++){
      float4 w = wr[k]; float4 hh = h4[k];
      acc = fmaf(hh.x, w.x, acc);
      acc = fmaf(hh.y, w.y, acc);
      acc = fmaf(hh.z, w.z, acc);
      acc = fmaf(hh.w, w.w, acc);
    }
    tsm[jj] = tanhf(acc + gb1[jj]);
  }
  __syncthreads();
  float part = 0.f;
  for (int jj = tid; jj < NH; jj += 256) part = fmaf(tsm[jj], gw2[jj], part);
  red[tid] = part; __syncthreads();
  for (int s = 128; s > 0; s >>= 1){ if (tid < s) red[tid] += red[tid + s]; __syncthreads(); }
  float gate = 1.f / (1.f + expf(-(red[0] + gb2[0])));
  __syncthreads();
  for (int h = tid; h < NH; h += 256) osm[h] = hsm[h] * gate;
  __syncthreads();
  const float* vpb = vp + (size_t)b * NNV * NH;
  float sc = 0.f;
  if (tid < NNV){
    const float4* vr = (const float4*)(vpb + (size_t)tid * NH);
    const float4* o4 = (const float4*)osm;
    float accv = 0.f;
    #pragma unroll 4
    for (int k = 0; k < NH/4; k++){
      float4 v = vr[k]; float4 oo = o4[k];
      accv = fmaf(oo.x, v.x, accv);
      accv = fmaf(oo.y, v.y, accv);
      accv = fmaf(oo.z, v.z, accv);
      accv = fmaf(oo.w, v.w, accv);
    }
    sc = accv / 22.62741699796952f;   // scores / sqrt(512)
  }
  red[tid] = (tid < NNV) ? sc : -INFINITY;
  __syncthreads();
  for (int s = 128; s > 0; s >>= 1){ if (tid < s) red[tid] = fmaxf(red[tid], red[tid + s]); __syncthreads(); }
  float mx = red[0];
  __syncthreads();
  float ev = (tid < NNV) ? expf(sc - mx) : 0.f;
  red[tid] = ev; __syncthreads();
  for (int s = 128; s > 0; s >>= 1){ if (tid < s) red[tid] += red[tid + s]; __syncthreads(); }
  float zs = red[0];
  if (tid < NNV) aw[tid] = ev / zs;
  __syncthreads();
  for (int h = tid; h < NH; h += 256){
    float accv = 0.f;
    for (int n = 0; n < NNV; n++) accv = fmaf(aw[n], vpb[(size_t)n * NH + h], accv);
    o2t[(size_t)h * NB + b] = osm[h] + accv;
  }
}

// ---------------- logits GEMM + rep-penalty + temperature -----------------------
__global__ __launch_bounds__(256, 4) void k_logits(
    const float* __restrict__ o2t,     // [NH][NB]
    const float* __restrict__ outw,    // [NVOC][NH]
    const float* __restrict__ outb,
    const int* __restrict__ toks, int step,
    float* __restrict__ logits)        // [NB][NVOC]
{
  __shared__ float osh[32][NB];
  __shared__ float wsh[32][72];
  __shared__ int hist[NB][3];
  int tid = threadIdx.x;
  int vbase = blockIdx.x * 64;
  int vl = (tid & 31) * 2;
  int b0 = (tid >> 5) * 16;
  if (tid < NB){
    hist[tid][0] = (step >= 1) ? toks[(size_t)tid * NSTEPS + step - 1] : -1;
    hist[tid][1] = (step >= 2) ? toks[(size_t)tid * NSTEPS + step - 2] : -1;
    hist[tid][2] = (step >= 3) ? toks[(size_t)tid * NSTEPS + step - 3] : -1;
  }
  float acc0[16], acc1[16];
  #pragma unroll
  for (int i = 0; i < 16; i++){ acc0[i] = 0.f; acc1[i] = 0.f; }

  for (int hc = 0; hc < NH; hc += 32){
    __syncthreads();
    #pragma unroll
    for (int q = tid; q < 1024; q += 256){
      int kk = q >> 5;
      int bb = (q & 31) << 2;
      *(float4*)&osh[kk][bb] = *(const float4*)(o2t + (size_t)(hc + kk) * NB + bb);
    }
    #pragma unroll
    for (int q = tid; q < 512; q += 256){
      int vr = q >> 3;
      int f4 = q & 7;
      float4 w = *(const float4*)(outw + (size_t)(vbase + vr) * NH + hc + f4 * 4);
      wsh[f4*4 + 0][vr] = w.x;
      wsh[f4*4 + 1][vr] = w.y;
      wsh[f4*4 + 2][vr] = w.z;
      wsh[f4*4 + 3][vr] = w.w;
    }
    __syncthreads();
    #pragma unroll 4
    for (int hl = 0; hl < 32; hl++){
      float w0 = wsh[hl][vl];
      float w1 = wsh[hl][vl + 1];
      #pragma unroll
      for (int bq = 0; bq < 4; bq++){
        float4 a = *(const float4*)&osh[hl][b0 + bq * 4];
        acc0[bq*4+0] = fmaf(a.x, w0, acc0[bq*4+0]);
        acc1[bq*4+0] = fmaf(a.x, w1, acc1[bq*4+0]);
        acc0[bq*4+1] = fmaf(a.y, w0, acc0[bq*4+1]);
        acc1[bq*4+1] = fmaf(a.y, w1, acc1[bq*4+1]);
        acc0[bq*4+2] = fmaf(a.z, w0, acc0[bq*4+2]);
        acc1[bq*4+2] = fmaf(a.z, w1, acc1[bq*4+2]);
        acc0[bq*4+3] = fmaf(a.w, w0, acc0[bq*4+3]);
        acc1[bq*4+3] = fmaf(a.w, w1, acc1[bq*4+3]);
      }
    }
  }
  __syncthreads();
  int v0 = vbase + vl;
  int v1 = v0 + 1;
  float ob0 = outb[v0], ob1 = outb[v1];
  #pragma unroll
  for (int i = 0; i < 16; i++){
    int b = b0 + i;
    float l0 = acc0[i] + ob0;
    float l1 = acc1[i] + ob1;
    int h1v = hist[b][0], h2v = hist[b][1], h3v = hist[b][2];
    if (v0 == h1v || v0 == h2v || v0 == h3v) l0 -= 2.0f;
    if (v1 == h1v || v1 == h2v || v1 == h3v) l1 -= 2.0f;
    l0 = l0 / 0.8f;
    l1 = l1 / 0.8f;
    *(float2*)(logits + (size_t)b * NVOC + v0) = make_float2(l0, l1);
  }
}

// ---------------- per-row stats: max, Z (softmax denom), min --------------------
__global__ __launch_bounds__(256) void k_rowstats(
    const float* __restrict__ logits, float* __restrict__ stats)
{
  int b = blockIdx.x, tid = threadIdx.x;
  const float4* lr = (const float4*)(logits + (size_t)b * NVOC);
  float mx = -INFINITY, mn = INFINITY;
  for (int i = tid; i < NVOC/4; i += 256){
    float4 v = lr[i];
    mx = fmaxf(mx, fmaxf(fmaxf(v.x, v.y), fmaxf(v.z, v.w)));
    mn = fminf(mn, fminf(fminf(v.x, v.y), fminf(v.z, v.w)));
  }
  __shared__ float ra[256], rb[256];
  ra[tid] = mx; rb[tid] = mn; __syncthreads();
  for (int s = 128; s > 0; s >>= 1){
    if (tid < s){ ra[tid] = fmaxf(ra[tid], ra[tid+s]); rb[tid] = fminf(rb[tid], rb[tid+s]); }
    __syncthreads();
  }
  float M = ra[0], mnv = rb[0];
  __syncthreads();
  float z = 0.f;
  for (int i = tid; i < NVOC/4; i += 256){
    float4 v = lr[i];
    z += expf(v.x - M) + expf(v.y - M) + expf(v.z - M) + expf(v.w - M);
  }
  ra[tid] = z; __syncthreads();
  for (int s = 128; s > 0; s >>= 1){ if (tid < s) ra[tid] += ra[tid+s]; __syncthreads(); }
  if (tid == 0) *(float4*)(stats + b * 4) = make_float4(M, ra[0], mnv, 0.f);
}

// ---------------- phase A: bucket histogram + scatter + per-bucket sort ---------
__global__ __launch_bounds__(1024) void k_bucket(
    const float* __restrict__ logits,
    const float* __restrict__ stats,
    float* __restrict__ sortbuf)
{
  int b = blockIdx.x, tid = threadIdx.x;
  const float* lr = logits + (size_t)b * NVOC;
  float* sbuf = sortbuf + (size_t)b * SORTSTRIDE;
  __shared__ int cnt[NBUCKET];
  __shared__ int base[NBUCKET];
  __shared__ int s0[1024];

  float4 st4 = *(const float4*)(stats + b * 4);
  float M = st4.x, mn = st4.z;
  float range = M - mn;
  float scale = (range > 0.f) ? (float)(NBUCKET - 1) / range : 0.f;

  for (int i = tid; i < NBUCKET; i += 1024) cnt[i] = 0;
  __syncthreads();
  for (int i = tid; i < NVOC; i += 1024){
    float l = lr[i];
    int bk = (int)((l - mn) * scale);
    bk = max(0, min(NBUCKET - 1, bk));
    atomicAdd(&cnt[bk], 1);
  }
  __syncthreads();
  // descending-bucket exclusive offsets
  int t4 = tid << 2;
  int c0v = cnt[t4], c1v = cnt[t4+1], c2v = cnt[t4+2], c3v = cnt[t4+3];
  s0[tid] = c0v + c1v + c2v + c3v;
  __syncthreads();
  for (int off = 1; off < 1024; off <<= 1){
    int v = s0[tid];
    int add = (tid + off < 1024) ? s0[tid + off] : 0;
    __syncthreads();
    s0[tid] = v + add;
    __syncthreads();
  }
  int exc = (tid < 1023) ? s0[tid + 1] : 0;
  base[t4+3] = exc;
  base[t4+2] = exc + c3v;
  base[t4+1] = exc + c3v + c2v;
  base[t4+0] = exc + c3v + c2v + c1v;
  __syncthreads();
  for (int i = tid; i < NBUCKET; i += 1024) cnt[i] = 0;
  __syncthreads();
  // scatter by bucket
  for (int i = tid; i < NVOC; i += 1024){
    float l = lr[i];
    int bk = (int)((l - mn) * scale);
    bk = max(0, min(NBUCKET - 1, bk));
    int pos = base[bk] + atomicAdd(&cnt[bk], 1);
    sbuf[pos] = l;
  }
  __threadfence_block();
  __syncthreads();
  // per-segment descending insertion sort (values only; ties identical bits)
  for (int bk = tid; bk < NBUCKET; bk += 1024){
    int n = cnt[bk];
    if (n > 1){
      float* seg = sbuf + base[bk];
      for (int i = 1; i < n; i++){
        float key = seg[i];
        int jj = i - 1;
        while (jj >= 0 && seg[jj] < key){ seg[jj + 1] = seg[jj]; jj--; }
        seg[jj + 1] = key;
      }
    }
  }
}

// ---------------- phase B: exact fp32 sequential cumsum -> threshold ------------
// One block per row, 256 threads. Single-lane scan in groups of 16 with a single
// running scalar; the crossing group recomputes its prefixes from still-live
// inputs (identical values, identical add order -> bit-exact vs prior version).
__global__ __launch_bounds__(256) void k_scan(
    const float* __restrict__ sortbuf,
    const float* __restrict__ stats,
    float* __restrict__ thrv,
    int* __restrict__ thrc)
{
  int b = blockIdx.x, tid = threadIdx.x;
  const float* sbuf = sortbuf + (size_t)b * SORTSTRIDE;
  __shared__ float pch[SCHUNK];
  __shared__ float sh_scum;
  __shared__ int sh_k, sh_cross;

  float4 st4 = *(const float4*)(stats + b * 4);
  float M = st4.x, Z = st4.y;
  if (tid == 0){ sh_k = NVOC - 1; sh_cross = 0; sh_scum = 0.f; }
  __syncthreads();

  for (int cb = 0; cb < NVOC; cb += SCHUNK){
    if (sh_cross) break;               // uniform: read after barrier
    int lim = min(SCHUNK, NVOC - cb);  // 8192,8192,8192,7424 -- all %16==0
    for (int i = tid; i < lim; i += 256){
      pch[i] = expf(sbuf[cb + i] - M) / Z;
    }
    __syncthreads();
    if (tid == 0){
      const float4* p4 = (const float4*)pch;
      float scum = sh_scum;
      int ng = lim >> 4;               // groups of 16
      // depth-3 pipeline: a=current, b=next, c=next-next
      float4 a0 = p4[0],  a1 = p4[1],  a2 = p4[2],  a3 = p4[3];
      float4 b0 = p4[4],  b1 = p4[5],  b2 = p4[6],  b3 = p4[7];
      float4 c0 = p4[8],  c1 = p4[9],  c2 = p4[10], c3 = p4[11];
      for (int g = 0; g < ng; g++){
        // prefetch group g+3
        int nx = (g + 3 < ng) ? (g + 3) * 4 : 0;
        float4 d0 = p4[nx], d1 = p4[nx+1], d2 = p4[nx+2], d3 = p4[nx+3];
        float base_s = scum;
        float s = base_s;
        s = s + a0.x; s = s + a0.y; s = s + a0.z; s = s + a0.w;
        s = s + a1.x; s = s + a1.y; s = s + a1.z; s = s + a1.w;
        s = s + a2.x; s = s + a2.y; s = s + a2.z; s = s + a2.w;
        s = s + a3.x; s = s + a3.y; s = s + a3.z; s = s + a3.w;
        if (s > 0.9f){
          // crossing in this group: recompute the 16 sequential prefixes
          float t = base_s;
          int kk = 15;
          float e[16] = {a0.x,a0.y,a0.z,a0.w, a1.x,a1.y,a1.z,a1.w,
                         a2.x,a2.y,a2.z,a2.w, a3.x,a3.y,a3.z,a3.w};
          #pragma unroll
          for (int q = 0; q < 16; q++){
            t = t + e[q];
            if (t > 0.9f){ kk = q; break; }
          }
          sh_k = cb + g * 16 + kk;
          sh_cross = 1;
          break;
        }
        scum = s;
        a0 = b0; a1 = b1; a2 = b2; a3 = b3;
        b0 = c0; b1 = c1; b2 = c2; b3 = c3;
        c0 = d0; c1 = d1; c2 = d2; c3 = d3;
      }
      if (!sh_cross) sh_scum = scum;
    }
    __syncthreads();
  }

  if (tid == 0){
    int ks = sh_k;
    float tv = sbuf[ks];
    int jlo = ks;
    while (jlo > 0 && sbuf[jlo - 1] == tv) jlo--;
    thrv[b] = tv;
    thrc[b] = ks + 1 - jlo;  // tokens equal to tv kept (stable index order)
  }
}

// ---------------- phase C: gumbel-max over kept set -----------------------------
__global__ __launch_bounds__(1024) void k_pick(
    const float* __restrict__ logits,
    const float* __restrict__ thrv,
    const int* __restrict__ thrc,
    int* __restrict__ toks,
    int step)
{
  int b = blockIdx.x, tid = threadIdx.x;
  const float* lr = logits + (size_t)b * NVOC;
  __shared__ int s0[1024];
  __shared__ float redv[1024];
  __shared__ int redi[1024];

  float tval = thrv[b];
  int ckeep = thrc[b];

  // rank-among-equals (stable argsort tie order = ascending original index)
  int stt = tid * 32;
  int en = min(stt + 32, NVOC);
  int eqc = 0;
  for (int i = stt; i < en; i++) eqc += (lr[i] == tval) ? 1 : 0;
  s0[tid] = eqc;
  __syncthreads();
  for (int off = 1; off < 1024; off <<= 1){
    int v = s0[tid];
    int add = (tid >= off) ? s0[tid - off] : 0;
    __syncthreads();
    s0[tid] = v + add;
    __syncthreads();
  }
  int eqrank = s0[tid] - eqc;

  uint32_t fk0, fk1;
  threefry2x32(0u, 42u, 0u, (uint32_t)step, fk0, fk1);   // fold_in(key(42), step)
  float best = -INFINITY;
  int besti = NVOC;
  for (int i = stt; i < en; i++){
    float l = lr[i];
    bool keep;
    if (l > tval) keep = true;
    else if (l == tval){ keep = (eqrank < ckeep); eqrank++; }
    else keep = false;
    if (keep){
      uint32_t o0, o1;
      threefry2x32(fk0, fk1, 0u, (uint32_t)(b * NVOC + i), o0, o1);
      uint32_t bits = o0 ^ o1;
      uint32_t fb = (bits >> 9) | 0x3f800000u;
      float u = __uint_as_float(fb) - 1.0f;
      if (u == 0.0f) u = 1.17549435e-38f;   // minval = tiny
      float gum = -logf(-logf(u));
      float cand = l + gum;
      if (cand > best){ best = cand; besti = i; }
    }
  }
  redv[tid] = best;
  redi[tid] = besti;
  __syncthreads();
  for (int s = 512; s > 0; s >>= 1){
    if (tid < s){
      float ov = redv[tid + s]; int oi = redi[tid + s];
      if (ov > redv[tid] || (ov == redv[tid] && oi < redi[tid])){
        redv[tid] = ov; redi[tid] = oi;
      }
    }
    __syncthreads();
  }
  if (tid == 0) toks[(size_t)b * NSTEPS + step] = redi[0];
}

// ---------------- host launcher -------------------------------------------------
extern "C" void kernel_launch(void* const* d_in, const int* in_sizes, int n_in,
                              void* d_out, int out_size, void* d_ws, size_t ws_size,
                              hipStream_t stream)
{
  (void)in_sizes; (void)n_in; (void)out_size;
  const float* thought = (const float*)d_in[0];
  const float* vfeat   = (const float*)d_in[1];
  const float* emb     = (const float*)d_in[2];
  const float* w_ih0   = (const float*)d_in[3];
  const float* w_hh0   = (const float*)d_in[4];
  const float* b_ih0   = (const float*)d_in[5];
  const float* b_hh0   = (const float*)d_in[6];
  const float* w_ih1   = (const float*)d_in[7];
  const float* w_hh1   = (const float*)d_in[8];
  const float* b_ih1   = (const float*)d_in[9];
  const float* b_hh1   = (const float*)d_in[10];
  const float* gw1     = (const float*)d_in[11];
  const float* gb1     = (const float*)d_in[12];
  const float* gw2     = (const float*)d_in[13];
  const float* gb2     = (const float*)d_in[14];
  const float* out_w   = (const float*)d_in[15];
  const float* out_b   = (const float*)d_in[16];
  const float* vis_w   = (const float*)d_in[17];
  const float* vis_b   = (const float*)d_in[18];
  const float* ln_g    = (const float*)d_in[19];
  const float* ln_b    = (const float*)d_in[20];
  int* toks = (int*)d_out;

  char* ws = (char*)d_ws;
  size_t off = 0;
  auto alloc = [&](size_t bytes) -> void* {
    void* p = ws + off;
    off += (bytes + 255) & ~(size_t)255;
    return p;
  };
  float* vp      = (float*)alloc((size_t)NB * NNV * NH * 4);
  float* h0a     = (float*)alloc((size_t)NH * NB * 4);
  float* h0b     = (float*)alloc((size_t)NH * NB * 4);
  float* c0a     = (float*)alloc((size_t)NH * NB * 4);
  float* c0b     = (float*)alloc((size_t)NH * NB * 4);
  float* h1a     = (float*)alloc((size_t)NH * NB * 4);
  float* h1b     = (float*)alloc((size_t)NH * NB * 4);
  float* c1a     = (float*)alloc((size_t)NH * NB * 4);
  float* c1b     = (float*)alloc((size_t)NH * NB * 4);
  float* o2t     = (float*)alloc((size_t)NH * NB * 4);
  float* logits  = (float*)alloc((size_t)NB * NVOC * 4);
  float* sortbuf = (float*)alloc((size_t)NB * SORTSTRIDE * 4);
  float* stats   = (float*)alloc((size_t)NB * 4 * 4);
  float* thrv    = (float*)alloc((size_t)NB * 4);
  int*   thrc    = (int*)alloc((size_t)NB * 4);
  if (off > ws_size) return;  // insufficient scratch: fail loudly via wrong output

  k_visproj<<<NB * NNV, 256, 0, stream>>>(vfeat, vis_w, vis_b, ln_g, ln_b, vp);
  k_init<<<(NH * NB + 255) / 256, 256, 0, stream>>>(thought, h0a, c0a, h1a, c1a);

  for (int step = 0; step < NSTEPS; step++){
    float *h0r, *h0w, *c0r, *c0w, *h1r, *h1w, *c1r, *c1w;
    if ((step & 1) == 0){
      h0r = h0a; h0w = h0b; c0r = c0a; c0w = c0b;
      h1r = h1a; h1w = h1b; c1r = c1a; c1w = c1b;
    } else {
      h0r = h0b; h0w = h0a; c0r = c0b; c0w = c0a;
      h1r = h1b; h1w = h1a; c1r = c1b; c1w = c1a;
    }
    k_lstm<NE><<<dim3(32, 2), 256, 0, stream>>>(
        w_ih0, w_hh0, b_ih0, b_hh0, emb, toks, step, h0r, c0r, h0w, c0w);
    k_lstm<NH><<<dim3(32, 2), 256, 0, stream>>>(
        w_ih1, w_hh1, b_ih1, b_hh1, h0w, toks, step, h1r, c1r, h1w, c1w);
    k_gateattn<<<NB, 256, 0, stream>>>(h1w, gw1, gb1, gw2, gb2, vp, o2t);
    k_logits<<<NVOC / 64, 256, 0, stream>>>(o2t, out_w, out_b, toks, step, logits);
    k_rowstats<<<NB, 256, 0, stream>>>(logits, stats);
    k_bucket<<<NB, 1024, 0, stream>>>(logits, stats, sortbuf);
    k_scan<<<NB, 256, 0, stream>>>(sortbuf, stats, thrv, thrc);
    k_pick<<<NB, 1024, 0, stream>>>(logits, thrv, thrc, toks, step);
  }
}

// Round 5
// 116706.396 us; speedup vs baseline: 1.0696x; 1.0575x over previous
//
#include <hip/hip_runtime.h>
#include <stdint.h>

#define NB 128      // batch
#define NH 512      // hidden
#define NE 128      // embedding dim
#define NVOC 32000  // vocab
#define NNV 196     // visual tokens
#define NDV 256     // visual dim
#define NSTEPS 32
#define SORTSTRIDE 32768
#define NBUCKET 4096

// ---------------- Threefry-2x32 (20 rounds), exact JAX semantics --------------
static __device__ __forceinline__ uint32_t rotl32(uint32_t x, int r){
  return (x << r) | (x >> (32 - r));
}

static __device__ __forceinline__ void threefry2x32(uint32_t k0, uint32_t k1,
    uint32_t x0, uint32_t x1, uint32_t &o0, uint32_t &o1){
  uint32_t k2 = k0 ^ k1 ^ 0x1BD11BDAu;
  x0 += k0; x1 += k1;
#define TF_RND(r) { x0 += x1; x1 = rotl32(x1,(r)); x1 ^= x0; }
  TF_RND(13) TF_RND(15) TF_RND(26) TF_RND(6)
  x0 += k1; x1 += k2 + 1u;
  TF_RND(17) TF_RND(29) TF_RND(16) TF_RND(24)
  x0 += k2; x1 += k0 + 2u;
  TF_RND(13) TF_RND(15) TF_RND(26) TF_RND(6)
  x0 += k0; x1 += k1 + 3u;
  TF_RND(17) TF_RND(29) TF_RND(16) TF_RND(24)
  x0 += k1; x1 += k2 + 4u;
  TF_RND(13) TF_RND(15) TF_RND(26) TF_RND(6)
  x0 += k2; x1 += k0 + 5u;
#undef TF_RND
  o0 = x0; o1 = x1;
}

// ---------------- visual projection + LayerNorm ------------------------------
__global__ __launch_bounds__(256) void k_visproj(
    const float* __restrict__ vf, const float* __restrict__ vis_w,
    const float* __restrict__ vis_b, const float* __restrict__ ln_g,
    const float* __restrict__ ln_b, float* __restrict__ vp)
{
  int bn = blockIdx.x;                 // b*NNV + n
  int tid = threadIdx.x;
  __shared__ float xs[NDV];
  __shared__ float red[256];
  const float* x = vf + (size_t)bn * NDV;
  xs[tid] = x[tid];                    // 256 threads == NDV
  __syncthreads();
  float out0, out1;
  {
    const float4* h4 = (const float4*)xs;
    const float4* w0 = (const float4*)(vis_w + (size_t)tid * NDV);
    const float4* w1 = (const float4*)(vis_w + (size_t)(tid + 256) * NDV);
    float a0 = 0.f, a1 = 0.f;
    #pragma unroll 4
    for (int k = 0; k < NDV/4; k++){
      float4 hh = h4[k];
      float4 wa = w0[k], wb = w1[k];
      a0 = fmaf(hh.x, wa.x, a0); a0 = fmaf(hh.y, wa.y, a0);
      a0 = fmaf(hh.z, wa.z, a0); a0 = fmaf(hh.w, wa.w, a0);
      a1 = fmaf(hh.x, wb.x, a1); a1 = fmaf(hh.y, wb.y, a1);
      a1 = fmaf(hh.z, wb.z, a1); a1 = fmaf(hh.w, wb.w, a1);
    }
    out0 = a0 + vis_b[tid];
    out1 = a1 + vis_b[tid + 256];
  }
  red[tid] = out0 + out1; __syncthreads();
  for (int s = 128; s > 0; s >>= 1){ if (tid < s) red[tid] += red[tid + s]; __syncthreads(); }
  float mu = red[0] * (1.0f / (float)NH);
  __syncthreads();
  float d0 = out0 - mu, d1 = out1 - mu;
  red[tid] = d0*d0 + d1*d1; __syncthreads();
  for (int s = 128; s > 0; s >>= 1){ if (tid < s) red[tid] += red[tid + s]; __syncthreads(); }
  float var = red[0] * (1.0f / (float)NH);
  float r = 1.0f / sqrtf(var + 1e-5f);
  float* op = vp + (size_t)bn * NH;
  op[tid]       = d0 * r * ln_g[tid]       + ln_b[tid];
  op[tid + 256] = d1 * r * ln_g[tid + 256] + ln_b[tid + 256];
}

// ---------------- init hidden states ------------------------------------------
__global__ void k_init(const float* __restrict__ thought,
                       float* __restrict__ h0, float* __restrict__ c0,
                       float* __restrict__ h1, float* __restrict__ c1)
{
  int id = blockIdx.x * 256 + threadIdx.x;
  if (id >= NH * NB) return;
  int k = id >> 7;
  int b = id & 127;
  float v = thought[(size_t)b * NH + k];
  h0[id] = v; h1[id] = v; c0[id] = 0.f; c1[id] = 0.f;
}

// ---------------- fused LSTM layer (GEMM + cell) -------------------------------
template<int K1>
__global__ __launch_bounds__(256) void k_lstm(
    const float* __restrict__ wih, const float* __restrict__ whh,
    const float* __restrict__ bih, const float* __restrict__ bhh,
    const float* __restrict__ a1,
    const int*   __restrict__ toks, int step,
    const float* __restrict__ hprev, const float* __restrict__ cprev,
    float* __restrict__ hout, float* __restrict__ cout)
{
  __shared__ float As[64][64];
  __shared__ float Ws[4 * 16 * 68];
  __shared__ int tokl[64];
  int tid = threadIdx.x;
  int jl = tid & 15;
  int bg = tid >> 4;
  int jbase = blockIdx.x * 16;
  int j = jbase + jl;
  int bblk = blockIdx.y * 64;
  int bl = bg * 4;
  if (K1 == NE){
    if (tid < 64) tokl[tid] = (step == 0) ? 1 : toks[(size_t)(bblk + tid) * NSTEPS + step - 1];
  }
  __syncthreads();

  float acc[4][4];
  #pragma unroll
  for (int g = 0; g < 4; g++)
    #pragma unroll
    for (int e = 0; e < 4; e++) acc[g][e] = 0.f;

  for (int part = 0; part < 2; part++){
    const float* Wsrc = part ? whh : wih;
    const float* Asrc = part ? hprev : a1;
    const int K = part ? NH : K1;
    const bool gather = (!part) && (K1 == NE);
    for (int kc = 0; kc < K; kc += 64){
      __syncthreads();
      for (int q = tid; q < 1024; q += 256){
        int kk = q >> 4;
        int bb = (q & 15) << 2;
        float4 v;
        if (gather){
          v.x = Asrc[(size_t)tokl[bb+0] * NE + kc + kk];
          v.y = Asrc[(size_t)tokl[bb+1] * NE + kc + kk];
          v.z = Asrc[(size_t)tokl[bb+2] * NE + kc + kk];
          v.w = Asrc[(size_t)tokl[bb+3] * NE + kc + kk];
        } else {
          v = *(const float4*)(Asrc + (size_t)(kc + kk) * NB + bblk + bb);
        }
        *(float4*)&As[kk][bb] = v;
      }
      for (int q = tid; q < 1024; q += 256){
        int r = q >> 4;
        int f = q & 15;
        int g = r >> 4;
        int jj = r & 15;
        float4 w = *(const float4*)(Wsrc + (size_t)(g * NH + jbase + jj) * K + kc + f * 4);
        float* wd = &Ws[(g * 16 + jj) * 68 + f * 4];
        wd[0] = w.x; wd[1] = w.y; wd[2] = w.z; wd[3] = w.w;
      }
      __syncthreads();
      #pragma unroll 2
      for (int kk = 0; kk < 64; kk += 4){
        float4 a0 = *(const float4*)&As[kk + 0][bl];
        float4 a1v = *(const float4*)&As[kk + 1][bl];
        float4 a2 = *(const float4*)&As[kk + 2][bl];
        float4 a3 = *(const float4*)&As[kk + 3][bl];
        #pragma unroll
        for (int g = 0; g < 4; g++){
          float4 w = *(const float4*)&Ws[(g * 16 + jl) * 68 + kk];
          acc[g][0] = fmaf(a0.x, w.x, acc[g][0]);
          acc[g][1] = fmaf(a0.y, w.x, acc[g][1]);
          acc[g][2] = fmaf(a0.z, w.x, acc[g][2]);
          acc[g][3] = fmaf(a0.w, w.x, acc[g][3]);
          acc[g][0] = fmaf(a1v.x, w.y, acc[g][0]);
          acc[g][1] = fmaf(a1v.y, w.y, acc[g][1]);
          acc[g][2] = fmaf(a1v.z, w.y, acc[g][2]);
          acc[g][3] = fmaf(a1v.w, w.y, acc[g][3]);
          acc[g][0] = fmaf(a2.x, w.z, acc[g][0]);
          acc[g][1] = fmaf(a2.y, w.z, acc[g][1]);
          acc[g][2] = fmaf(a2.z, w.z, acc[g][2]);
          acc[g][3] = fmaf(a2.w, w.z, acc[g][3]);
          acc[g][0] = fmaf(a3.x, w.w, acc[g][0]);
          acc[g][1] = fmaf(a3.y, w.w, acc[g][1]);
          acc[g][2] = fmaf(a3.z, w.w, acc[g][2]);
          acc[g][3] = fmaf(a3.w, w.w, acc[g][3]);
        }
      }
    }
  }

  float bi[4];
  #pragma unroll
  for (int g = 0; g < 4; g++) bi[g] = bih[g * NH + j] + bhh[g * NH + j];
  int b0g = bblk + bl;
  float4 cp = *(const float4*)(cprev + (size_t)j * NB + b0g);
  float cpv[4] = {cp.x, cp.y, cp.z, cp.w};
  float hs[4], cs[4];
  #pragma unroll
  for (int e = 0; e < 4; e++){
    float zi = acc[0][e] + bi[0];
    float zf = acc[1][e] + bi[1];
    float zg = acc[2][e] + bi[2];
    float zo = acc[3][e] + bi[3];
    float si = 1.f / (1.f + expf(-zi));
    float sf = 1.f / (1.f + expf(-zf));
    float so = 1.f / (1.f + expf(-zo));
    float tg = tanhf(zg);
    float c2 = sf * cpv[e] + si * tg;
    cs[e] = c2;
    hs[e] = so * tanhf(c2);
  }
  *(float4*)(cout + (size_t)j * NB + b0g) = make_float4(cs[0], cs[1], cs[2], cs[3]);
  *(float4*)(hout + (size_t)j * NB + b0g) = make_float4(hs[0], hs[1], hs[2], hs[3]);
}

// ---------------- gate + visual attention --------------------------------------
__global__ __launch_bounds__(256) void k_gateattn(
    const float* __restrict__ h1t,
    const float* __restrict__ gw1, const float* __restrict__ gb1,
    const float* __restrict__ gw2, const float* __restrict__ gb2,
    const float* __restrict__ vp,
    float* __restrict__ o2t)
{
  int b = blockIdx.x;
  int tid = threadIdx.x;
  __shared__ float hsm[NH];
  __shared__ float tsm[NH];
  __shared__ float osm[NH];
  __shared__ float aw[NNV];
  __shared__ float red[256];
  for (int h = tid; h < NH; h += 256) hsm[h] = h1t[(size_t)h * NB + b];
  __syncthreads();
  for (int jj = tid; jj < NH; jj += 256){
    const float4* wr = (const float4*)(gw1 + (size_t)jj * NH);
    const float4* h4 = (const float4*)hsm;
    float acc = 0.f;
    #pragma unroll 4
    for (int k = 0; k < NH/4; k++){
      float4 w = wr[k]; float4 hh = h4[k];
      acc = fmaf(hh.x, w.x, acc);
      acc = fmaf(hh.y, w.y, acc);
      acc = fmaf(hh.z, w.z, acc);
      acc = fmaf(hh.w, w.w, acc);
    }
    tsm[jj] = tanhf(acc + gb1[jj]);
  }
  __syncthreads();
  float part = 0.f;
  for (int jj = tid; jj < NH; jj += 256) part = fmaf(tsm[jj], gw2[jj], part);
  red[tid] = part; __syncthreads();
  for (int s = 128; s > 0; s >>= 1){ if (tid < s) red[tid] += red[tid + s]; __syncthreads(); }
  float gate = 1.f / (1.f + expf(-(red[0] + gb2[0])));
  __syncthreads();
  for (int h = tid; h < NH; h += 256) osm[h] = hsm[h] * gate;
  __syncthreads();
  const float* vpb = vp + (size_t)b * NNV * NH;
  float sc = 0.f;
  if (tid < NNV){
    const float4* vr = (const float4*)(vpb + (size_t)tid * NH);
    const float4* o4 = (const float4*)osm;
    float accv = 0.f;
    #pragma unroll 4
    for (int k = 0; k < NH/4; k++){
      float4 v = vr[k]; float4 oo = o4[k];
      accv = fmaf(oo.x, v.x, accv);
      accv = fmaf(oo.y, v.y, accv);
      accv = fmaf(oo.z, v.z, accv);
      accv = fmaf(oo.w, v.w, accv);
    }
    sc = accv / 22.62741699796952f;   // scores / sqrt(512)
  }
  red[tid] = (tid < NNV) ? sc : -INFINITY;
  __syncthreads();
  for (int s = 128; s > 0; s >>= 1){ if (tid < s) red[tid] = fmaxf(red[tid], red[tid + s]); __syncthreads(); }
  float mx = red[0];
  __syncthreads();
  float ev = (tid < NNV) ? expf(sc - mx) : 0.f;
  red[tid] = ev; __syncthreads();
  for (int s = 128; s > 0; s >>= 1){ if (tid < s) red[tid] += red[tid + s]; __syncthreads(); }
  float zs = red[0];
  if (tid < NNV) aw[tid] = ev / zs;
  __syncthreads();
  for (int h = tid; h < NH; h += 256){
    float accv = 0.f;
    for (int n = 0; n < NNV; n++) accv = fmaf(aw[n], vpb[(size_t)n * NH + h], accv);
    o2t[(size_t)h * NB + b] = osm[h] + accv;
  }
}

// ---------------- logits GEMM + rep-penalty + temperature -----------------------
__global__ __launch_bounds__(256, 4) void k_logits(
    const float* __restrict__ o2t,     // [NH][NB]
    const float* __restrict__ outw,    // [NVOC][NH]
    const float* __restrict__ outb,
    const int* __restrict__ toks, int step,
    float* __restrict__ logits)        // [NB][NVOC]
{
  __shared__ float osh[32][NB];
  __shared__ float wsh[32][72];
  __shared__ int hist[NB][3];
  int tid = threadIdx.x;
  int vbase = blockIdx.x * 64;
  int vl = (tid & 31) * 2;
  int b0 = (tid >> 5) * 16;
  if (tid < NB){
    hist[tid][0] = (step >= 1) ? toks[(size_t)tid * NSTEPS + step - 1] : -1;
    hist[tid][1] = (step >= 2) ? toks[(size_t)tid * NSTEPS + step - 2] : -1;
    hist[tid][2] = (step >= 3) ? toks[(size_t)tid * NSTEPS + step - 3] : -1;
  }
  float acc0[16], acc1[16];
  #pragma unroll
  for (int i = 0; i < 16; i++){ acc0[i] = 0.f; acc1[i] = 0.f; }

  for (int hc = 0; hc < NH; hc += 32){
    __syncthreads();
    #pragma unroll
    for (int q = tid; q < 1024; q += 256){
      int kk = q >> 5;
      int bb = (q & 31) << 2;
      *(float4*)&osh[kk][bb] = *(const float4*)(o2t + (size_t)(hc + kk) * NB + bb);
    }
    #pragma unroll
    for (int q = tid; q < 512; q += 256){
      int vr = q >> 3;
      int f4 = q & 7;
      float4 w = *(const float4*)(outw + (size_t)(vbase + vr) * NH + hc + f4 * 4);
      wsh[f4*4 + 0][vr] = w.x;
      wsh[f4*4 + 1][vr] = w.y;
      wsh[f4*4 + 2][vr] = w.z;
      wsh[f4*4 + 3][vr] = w.w;
    }
    __syncthreads();
    #pragma unroll 4
    for (int hl = 0; hl < 32; hl++){
      float w0 = wsh[hl][vl];
      float w1 = wsh[hl][vl + 1];
      #pragma unroll
      for (int bq = 0; bq < 4; bq++){
        float4 a = *(const float4*)&osh[hl][b0 + bq * 4];
        acc0[bq*4+0] = fmaf(a.x, w0, acc0[bq*4+0]);
        acc1[bq*4+0] = fmaf(a.x, w1, acc1[bq*4+0]);
        acc0[bq*4+1] = fmaf(a.y, w0, acc0[bq*4+1]);
        acc1[bq*4+1] = fmaf(a.y, w1, acc1[bq*4+1]);
        acc0[bq*4+2] = fmaf(a.z, w0, acc0[bq*4+2]);
        acc1[bq*4+2] = fmaf(a.z, w1, acc1[bq*4+2]);
        acc0[bq*4+3] = fmaf(a.w, w0, acc0[bq*4+3]);
        acc1[bq*4+3] = fmaf(a.w, w1, acc1[bq*4+3]);
      }
    }
  }
  __syncthreads();
  int v0 = vbase + vl;
  int v1 = v0 + 1;
  float ob0 = outb[v0], ob1 = outb[v1];
  #pragma unroll
  for (int i = 0; i < 16; i++){
    int b = b0 + i;
    float l0 = acc0[i] + ob0;
    float l1 = acc1[i] + ob1;
    int h1v = hist[b][0], h2v = hist[b][1], h3v = hist[b][2];
    if (v0 == h1v || v0 == h2v || v0 == h3v) l0 -= 2.0f;
    if (v1 == h1v || v1 == h2v || v1 == h3v) l1 -= 2.0f;
    l0 = l0 / 0.8f;
    l1 = l1 / 0.8f;
    *(float2*)(logits + (size_t)b * NVOC + v0) = make_float2(l0, l1);
  }
}

// ---------------- per-row stats: max, Z (softmax denom), min --------------------
__global__ __launch_bounds__(256) void k_rowstats(
    const float* __restrict__ logits, float* __restrict__ stats)
{
  int b = blockIdx.x, tid = threadIdx.x;
  const float4* lr = (const float4*)(logits + (size_t)b * NVOC);
  float mx = -INFINITY, mn = INFINITY;
  for (int i = tid; i < NVOC/4; i += 256){
    float4 v = lr[i];
    mx = fmaxf(mx, fmaxf(fmaxf(v.x, v.y), fmaxf(v.z, v.w)));
    mn = fminf(mn, fminf(fminf(v.x, v.y), fminf(v.z, v.w)));
  }
  __shared__ float ra[256], rb[256];
  ra[tid] = mx; rb[tid] = mn; __syncthreads();
  for (int s = 128; s > 0; s >>= 1){
    if (tid < s){ ra[tid] = fmaxf(ra[tid], ra[tid+s]); rb[tid] = fminf(rb[tid], rb[tid+s]); }
    __syncthreads();
  }
  float M = ra[0], mnv = rb[0];
  __syncthreads();
  float z = 0.f;
  for (int i = tid; i < NVOC/4; i += 256){
    float4 v = lr[i];
    z += expf(v.x - M) + expf(v.y - M) + expf(v.z - M) + expf(v.w - M);
  }
  ra[tid] = z; __syncthreads();
  for (int s = 128; s > 0; s >>= 1){ if (tid < s) ra[tid] += ra[tid+s]; __syncthreads(); }
  if (tid == 0) *(float4*)(stats + b * 4) = make_float4(M, ra[0], mnv, 0.f);
}

// ---------------- phase A: bucket histogram + scatter + sort + exp fill ---------
__global__ __launch_bounds__(1024) void k_bucket(
    const float* __restrict__ logits,
    const float* __restrict__ stats,
    float* __restrict__ sortbuf,
    float* __restrict__ pbuf)
{
  int b = blockIdx.x, tid = threadIdx.x;
  const float* lr = logits + (size_t)b * NVOC;
  float* sbuf = sortbuf + (size_t)b * SORTSTRIDE;
  __shared__ int cnt[NBUCKET];
  __shared__ int base[NBUCKET];
  __shared__ int s0[1024];

  float4 st4 = *(const float4*)(stats + b * 4);
  float M = st4.x, Z = st4.y, mn = st4.z;
  float range = M - mn;
  float scale = (range > 0.f) ? (float)(NBUCKET - 1) / range : 0.f;

  for (int i = tid; i < NBUCKET; i += 1024) cnt[i] = 0;
  __syncthreads();
  for (int i = tid; i < NVOC; i += 1024){
    float l = lr[i];
    int bk = (int)((l - mn) * scale);
    bk = max(0, min(NBUCKET - 1, bk));
    atomicAdd(&cnt[bk], 1);
  }
  __syncthreads();
  // descending-bucket exclusive offsets
  int t4 = tid << 2;
  int c0v = cnt[t4], c1v = cnt[t4+1], c2v = cnt[t4+2], c3v = cnt[t4+3];
  s0[tid] = c0v + c1v + c2v + c3v;
  __syncthreads();
  for (int off = 1; off < 1024; off <<= 1){
    int v = s0[tid];
    int add = (tid + off < 1024) ? s0[tid + off] : 0;
    __syncthreads();
    s0[tid] = v + add;
    __syncthreads();
  }
  int exc = (tid < 1023) ? s0[tid + 1] : 0;
  base[t4+3] = exc;
  base[t4+2] = exc + c3v;
  base[t4+1] = exc + c3v + c2v;
  base[t4+0] = exc + c3v + c2v + c1v;
  __syncthreads();
  for (int i = tid; i < NBUCKET; i += 1024) cnt[i] = 0;
  __syncthreads();
  // scatter by bucket
  for (int i = tid; i < NVOC; i += 1024){
    float l = lr[i];
    int bk = (int)((l - mn) * scale);
    bk = max(0, min(NBUCKET - 1, bk));
    int pos = base[bk] + atomicAdd(&cnt[bk], 1);
    sbuf[pos] = l;
  }
  __threadfence_block();
  __syncthreads();
  // per-segment descending insertion sort (values only; ties identical bits)
  for (int bk = tid; bk < NBUCKET; bk += 1024){
    int n = cnt[bk];
    if (n > 1){
      float* seg = sbuf + base[bk];
      for (int i = 1; i < n; i++){
        float key = seg[i];
        int jj = i - 1;
        while (jj >= 0 && seg[jj] < key){ seg[jj + 1] = seg[jj]; jj--; }
        seg[jj + 1] = key;
      }
    }
  }
  __threadfence_block();
  __syncthreads();
  // p-array for the serial scan (bit-identical expression to prior versions)
  float* prow = pbuf + (size_t)b * NVOC;
  for (int i = tid; i < NVOC; i += 1024){
    prow[i] = expf(sbuf[i] - M) / Z;
  }
}

// ---------------- phase B: exact fp32 sequential cumsum (inline asm) ------------
// Single lane per row. Hand-scheduled GCN loop: 8 global_load_dwordx4 in flight
// (pinned v[40:71]), running sum chained through one VGPR in exact element
// order -> bit-identical to the prior sequential scan. ~6-9 cyc/element.
__global__ __launch_bounds__(64) void k_scan(
    const float* __restrict__ pbuf,
    const float* __restrict__ sortbuf,
    float* __restrict__ thrv,
    int* __restrict__ thrc)
{
  int b = blockIdx.x;
  if (threadIdx.x != 0) return;
  const float* prow = pbuf + (size_t)b * NVOC;
  const float* sbuf = sortbuf + (size_t)b * SORTSTRIDE;

  float s = 0.f;
  float prev = 0.f;
  uint32_t voff = 0;
  const uint32_t vend = NVOC * 4u;   // 128000 bytes; 1000 iters of 32 elems

#define QBLK(R0,R1,R2,R3,RQ,OFF) \
  "s_waitcnt vmcnt(7)\n\t" \
  "v_add_f32 %[s], %[s], " R0 "\n\t" \
  "v_add_f32 %[s], %[s], " R1 "\n\t" \
  "v_add_f32 %[s], %[s], " R2 "\n\t" \
  "v_add_f32 %[s], %[s], " R3 "\n\t" \
  "global_load_dwordx4 " RQ ", %[voff], %[base] offset:" OFF "\n\t"

  asm volatile(
    "global_load_dwordx4 v[40:43], %[voff], %[base] offset:0\n\t"
    "global_load_dwordx4 v[44:47], %[voff], %[base] offset:16\n\t"
    "global_load_dwordx4 v[48:51], %[voff], %[base] offset:32\n\t"
    "global_load_dwordx4 v[52:55], %[voff], %[base] offset:48\n\t"
    "global_load_dwordx4 v[56:59], %[voff], %[base] offset:64\n\t"
    "global_load_dwordx4 v[60:63], %[voff], %[base] offset:80\n\t"
    "global_load_dwordx4 v[64:67], %[voff], %[base] offset:96\n\t"
    "global_load_dwordx4 v[68:71], %[voff], %[base] offset:112\n\t"
    "Lscan%=:\n\t"
    "v_mov_b32 %[prev], %[s]\n\t"
    QBLK("v40","v41","v42","v43","v[40:43]","128")
    QBLK("v44","v45","v46","v47","v[44:47]","144")
    QBLK("v48","v49","v50","v51","v[48:51]","160")
    QBLK("v52","v53","v54","v55","v[52:55]","176")
    QBLK("v56","v57","v58","v59","v[56:59]","192")
    QBLK("v60","v61","v62","v63","v[60:63]","208")
    QBLK("v64","v65","v66","v67","v[64:67]","224")
    QBLK("v68","v69","v70","v71","v[68:71]","240")
    "v_add_u32 %[voff], 128, %[voff]\n\t"
    "v_cmp_lt_f32 vcc, 0x3f666666, %[s]\n\t"   // 0.9f < s
    "s_cbranch_vccnz Ldone%=\n\t"
    "v_cmp_lt_u32 vcc, %[voff], %[vend]\n\t"
    "s_cbranch_vccnz Lscan%=\n\t"
    "Ldone%=:\n\t"
    "s_waitcnt vmcnt(0)\n\t"
    : [s]"+v"(s), [voff]"+v"(voff), [prev]"+v"(prev)
    : [base]"s"(prow), [vend]"v"(vend)
    : "vcc", "memory",
      "v40","v41","v42","v43","v44","v45","v46","v47",
      "v48","v49","v50","v51","v52","v53","v54","v55",
      "v56","v57","v58","v59","v60","v61","v62","v63",
      "v64","v65","v66","v67","v68","v69","v70","v71");
#undef QBLK

  int ks;
  if (s > 0.9f){
    int idx0 = (int)(voff >> 2) - 32;   // first element of the crossing group
    float t = prev;                     // exact running sum at group start
    ks = idx0 + 31;
    for (int q = 0; q < 32; q++){
      t = t + prow[idx0 + q];           // same values, same add order -> bit-exact
      if (t > 0.9f){ ks = idx0 + q; break; }
    }
  } else {
    ks = NVOC - 1;
  }
  float tv = sbuf[ks];
  int jlo = ks;
  while (jlo > 0 && sbuf[jlo - 1] == tv) jlo--;
  thrv[b] = tv;
  thrc[b] = ks + 1 - jlo;   // tokens equal to tv kept (stable index order)
}

// ---------------- phase C: gumbel-max over kept set -----------------------------
__global__ __launch_bounds__(1024) void k_pick(
    const float* __restrict__ logits,
    const float* __restrict__ thrv,
    const int* __restrict__ thrc,
    int* __restrict__ toks,
    int step)
{
  int b = blockIdx.x, tid = threadIdx.x;
  const float* lr = logits + (size_t)b * NVOC;
  __shared__ int s0[1024];
  __shared__ float redv[1024];
  __shared__ int redi[1024];

  float tval = thrv[b];
  int ckeep = thrc[b];

  // rank-among-equals (stable argsort tie order = ascending original index)
  int stt = tid * 32;
  int en = min(stt + 32, NVOC);
  int eqc = 0;
  for (int i = stt; i < en; i++) eqc += (lr[i] == tval) ? 1 : 0;
  s0[tid] = eqc;
  __syncthreads();
  for (int off = 1; off < 1024; off <<= 1){
    int v = s0[tid];
    int add = (tid >= off) ? s0[tid - off] : 0;
    __syncthreads();
    s0[tid] = v + add;
    __syncthreads();
  }
  int eqrank = s0[tid] - eqc;

  uint32_t fk0, fk1;
  threefry2x32(0u, 42u, 0u, (uint32_t)step, fk0, fk1);   // fold_in(key(42), step)
  float best = -INFINITY;
  int besti = NVOC;
  for (int i = stt; i < en; i++){
    float l = lr[i];
    bool keep;
    if (l > tval) keep = true;
    else if (l == tval){ keep = (eqrank < ckeep); eqrank++; }
    else keep = false;
    if (keep){
      uint32_t o0, o1;
      threefry2x32(fk0, fk1, 0u, (uint32_t)(b * NVOC + i), o0, o1);
      uint32_t bits = o0 ^ o1;
      uint32_t fb = (bits >> 9) | 0x3f800000u;
      float u = __uint_as_float(fb) - 1.0f;
      if (u == 0.0f) u = 1.17549435e-38f;   // minval = tiny
      float gum = -logf(-logf(u));
      float cand = l + gum;
      if (cand > best){ best = cand; besti = i; }
    }
  }
  redv[tid] = best;
  redi[tid] = besti;
  __syncthreads();
  for (int s = 512; s > 0; s >>= 1){
    if (tid < s){
      float ov = redv[tid + s]; int oi = redi[tid + s];
      if (ov > redv[tid] || (ov == redv[tid] && oi < redi[tid])){
        redv[tid] = ov; redi[tid] = oi;
      }
    }
    __syncthreads();
  }
  if (tid == 0) toks[(size_t)b * NSTEPS + step] = redi[0];
}

// ---------------- host launcher -------------------------------------------------
extern "C" void kernel_launch(void* const* d_in, const int* in_sizes, int n_in,
                              void* d_out, int out_size, void* d_ws, size_t ws_size,
                              hipStream_t stream)
{
  (void)in_sizes; (void)n_in; (void)out_size;
  const float* thought = (const float*)d_in[0];
  const float* vfeat   = (const float*)d_in[1];
  const float* emb     = (const float*)d_in[2];
  const float* w_ih0   = (const float*)d_in[3];
  const float* w_hh0   = (const float*)d_in[4];
  const float* b_ih0   = (const float*)d_in[5];
  const float* b_hh0   = (const float*)d_in[6];
  const float* w_ih1   = (const float*)d_in[7];
  const float* w_hh1   = (const float*)d_in[8];
  const float* b_ih1   = (const float*)d_in[9];
  const float* b_hh1   = (const float*)d_in[10];
  const float* gw1     = (const float*)d_in[11];
  const float* gb1     = (const float*)d_in[12];
  const float* gw2     = (const float*)d_in[13];
  const float* gb2     = (const float*)d_in[14];
  const float* out_w   = (const float*)d_in[15];
  const float* out_b   = (const float*)d_in[16];
  const float* vis_w   = (const float*)d_in[17];
  const float* vis_b   = (const float*)d_in[18];
  const float* ln_g    = (const float*)d_in[19];
  const float* ln_b    = (const float*)d_in[20];
  int* toks = (int*)d_out;

  char* ws = (char*)d_ws;
  size_t off = 0;
  auto alloc = [&](size_t bytes) -> void* {
    void* p = ws + off;
    off += (bytes + 255) & ~(size_t)255;
    return p;
  };
  float* vp      = (float*)alloc((size_t)NB * NNV * NH * 4);
  float* h0a     = (float*)alloc((size_t)NH * NB * 4);
  float* h0b     = (float*)alloc((size_t)NH * NB * 4);
  float* c0a     = (float*)alloc((size_t)NH * NB * 4);
  float* c0b     = (float*)alloc((size_t)NH * NB * 4);
  float* h1a     = (float*)alloc((size_t)NH * NB * 4);
  float* h1b     = (float*)alloc((size_t)NH * NB * 4);
  float* c1a     = (float*)alloc((size_t)NH * NB * 4);
  float* c1b     = (float*)alloc((size_t)NH * NB * 4);
  float* o2t     = (float*)alloc((size_t)NH * NB * 4);
  float* logits  = (float*)alloc((size_t)NB * NVOC * 4);
  float* pbuf    = (float*)alloc((size_t)NB * NVOC * 4);      // before sortbuf: asm overrun lands in sortbuf
  float* sortbuf = (float*)alloc((size_t)NB * SORTSTRIDE * 4);
  float* stats   = (float*)alloc((size_t)NB * 4 * 4);
  float* thrv    = (float*)alloc((size_t)NB * 4);
  int*   thrc    = (int*)alloc((size_t)NB * 4);
  if (off > ws_size) return;  // insufficient scratch: fail loudly via wrong output

  k_visproj<<<NB * NNV, 256, 0, stream>>>(vfeat, vis_w, vis_b, ln_g, ln_b, vp);
  k_init<<<(NH * NB + 255) / 256, 256, 0, stream>>>(thought, h0a, c0a, h1a, c1a);

  for (int step = 0; step < NSTEPS; step++){
    float *h0r, *h0w, *c0r, *c0w, *h1r, *h1w, *c1r, *c1w;
    if ((step & 1) == 0){
      h0r = h0a; h0w = h0b; c0r = c0a; c0w = c0b;
      h1r = h1a; h1w = h1b; c1r = c1a; c1w = c1b;
    } else {
      h0r = h0b; h0w = h0a; c0r = c0b; c0w = c0a;
      h1r = h1b; h1w = h1a; c1r = c1b; c1w = c1a;
    }
    k_lstm<NE><<<dim3(32, 2), 256, 0, stream>>>(
        w_ih0, w_hh0, b_ih0, b_hh0, emb, toks, step, h0r, c0r, h0w, c0w);
    k_lstm<NH><<<dim3(32, 2), 256, 0, stream>>>(
        w_ih1, w_hh1, b_ih1, b_hh1, h0w, toks, step, h1r, c1r, h1w, c1w);
    k_gateattn<<<NB, 256, 0, stream>>>(h1w, gw1, gb1, gw2, gb2, vp, o2t);
    k_logits<<<NVOC / 64, 256, 0, stream>>>(o2t, out_w, out_b, toks, step, logits);
    k_rowstats<<<NB, 256, 0, stream>>>(logits, stats);
    k_bucket<<<NB, 1024, 0, stream>>>(logits, stats, sortbuf, pbuf);
    k_scan<<<NB, 64, 0, stream>>>(pbuf, sortbuf, thrv, thrc);
    k_pick<<<NB, 1024, 0, stream>>>(logits, thrv, thrc, toks, step);
  }
}

// Round 6
// 26708.749 us; speedup vs baseline: 4.6736x; 4.3696x over previous
//
#include <hip/hip_runtime.h>
#include <stdint.h>

#define NB 128      // batch
#define NH 512      // hidden
#define NE 128      // embedding dim
#define NVOC 32000  // vocab
#define NNV 196     // visual tokens
#define NDV 256     // visual dim
#define NSTEPS 32
#define SORTSTRIDE 32768

// ---------------- Threefry-2x32 (20 rounds), exact JAX semantics --------------
static __device__ __forceinline__ uint32_t rotl32(uint32_t x, int r){
  return (x << r) | (x >> (32 - r));
}

static __device__ __forceinline__ void threefry2x32(uint32_t k0, uint32_t k1,
    uint32_t x0, uint32_t x1, uint32_t &o0, uint32_t &o1){
  uint32_t k2 = k0 ^ k1 ^ 0x1BD11BDAu;
  x0 += k0; x1 += k1;
#define TF_RND(r) { x0 += x1; x1 = rotl32(x1,(r)); x1 ^= x0; }
  TF_RND(13) TF_RND(15) TF_RND(26) TF_RND(6)
  x0 += k1; x1 += k2 + 1u;
  TF_RND(17) TF_RND(29) TF_RND(16) TF_RND(24)
  x0 += k2; x1 += k0 + 2u;
  TF_RND(13) TF_RND(15) TF_RND(26) TF_RND(6)
  x0 += k0; x1 += k1 + 3u;
  TF_RND(17) TF_RND(29) TF_RND(16) TF_RND(24)
  x0 += k1; x1 += k2 + 4u;
  TF_RND(13) TF_RND(15) TF_RND(26) TF_RND(6)
  x0 += k2; x1 += k0 + 5u;
#undef TF_RND
  o0 = x0; o1 = x1;
}

// ---------------- visual projection + LayerNorm ------------------------------
__global__ __launch_bounds__(256) void k_visproj(
    const float* __restrict__ vf, const float* __restrict__ vis_w,
    const float* __restrict__ vis_b, const float* __restrict__ ln_g,
    const float* __restrict__ ln_b, float* __restrict__ vp)
{
  int bn = blockIdx.x;                 // b*NNV + n
  int tid = threadIdx.x;
  __shared__ float xs[NDV];
  __shared__ float red[256];
  const float* x = vf + (size_t)bn * NDV;
  xs[tid] = x[tid];                    // 256 threads == NDV
  __syncthreads();
  float out0, out1;
  {
    const float4* h4 = (const float4*)xs;
    const float4* w0 = (const float4*)(vis_w + (size_t)tid * NDV);
    const float4* w1 = (const float4*)(vis_w + (size_t)(tid + 256) * NDV);
    float a0 = 0.f, a1 = 0.f;
    #pragma unroll 4
    for (int k = 0; k < NDV/4; k++){
      float4 hh = h4[k];
      float4 wa = w0[k], wb = w1[k];
      a0 = fmaf(hh.x, wa.x, a0); a0 = fmaf(hh.y, wa.y, a0);
      a0 = fmaf(hh.z, wa.z, a0); a0 = fmaf(hh.w, wa.w, a0);
      a1 = fmaf(hh.x, wb.x, a1); a1 = fmaf(hh.y, wb.y, a1);
      a1 = fmaf(hh.z, wb.z, a1); a1 = fmaf(hh.w, wb.w, a1);
    }
    out0 = a0 + vis_b[tid];
    out1 = a1 + vis_b[tid + 256];
  }
  red[tid] = out0 + out1; __syncthreads();
  for (int s = 128; s > 0; s >>= 1){ if (tid < s) red[tid] += red[tid + s]; __syncthreads(); }
  float mu = red[0] * (1.0f / (float)NH);
  __syncthreads();
  float d0 = out0 - mu, d1 = out1 - mu;
  red[tid] = d0*d0 + d1*d1; __syncthreads();
  for (int s = 128; s > 0; s >>= 1){ if (tid < s) red[tid] += red[tid + s]; __syncthreads(); }
  float var = red[0] * (1.0f / (float)NH);
  float r = 1.0f / sqrtf(var + 1e-5f);
  float* op = vp + (size_t)bn * NH;
  op[tid]       = d0 * r * ln_g[tid]       + ln_b[tid];
  op[tid + 256] = d1 * r * ln_g[tid + 256] + ln_b[tid + 256];
}

// ---------------- init hidden states ------------------------------------------
__global__ void k_init(const float* __restrict__ thought,
                       float* __restrict__ h0, float* __restrict__ c0,
                       float* __restrict__ h1, float* __restrict__ c1)
{
  int id = blockIdx.x * 256 + threadIdx.x;
  if (id >= NH * NB) return;
  int k = id >> 7;
  int b = id & 127;
  float v = thought[(size_t)b * NH + k];
  h0[id] = v; h1[id] = v; c0[id] = 0.f; c1[id] = 0.f;
}

// ---------------- fused LSTM layer (GEMM + cell) -------------------------------
template<int K1>
__global__ __launch_bounds__(256) void k_lstm(
    const float* __restrict__ wih, const float* __restrict__ whh,
    const float* __restrict__ bih, const float* __restrict__ bhh,
    const float* __restrict__ a1,
    const int*   __restrict__ toks, int step,
    const float* __restrict__ hprev, const float* __restrict__ cprev,
    float* __restrict__ hout, float* __restrict__ cout)
{
  __shared__ float As[64][64];
  __shared__ float Ws[4 * 16 * 68];
  __shared__ int tokl[64];
  int tid = threadIdx.x;
  int jl = tid & 15;
  int bg = tid >> 4;
  int jbase = blockIdx.x * 16;
  int j = jbase + jl;
  int bblk = blockIdx.y * 64;
  int bl = bg * 4;
  if (K1 == NE){
    if (tid < 64) tokl[tid] = (step == 0) ? 1 : toks[(size_t)(bblk + tid) * NSTEPS + step - 1];
  }
  __syncthreads();

  float acc[4][4];
  #pragma unroll
  for (int g = 0; g < 4; g++)
    #pragma unroll
    for (int e = 0; e < 4; e++) acc[g][e] = 0.f;

  for (int part = 0; part < 2; part++){
    const float* Wsrc = part ? whh : wih;
    const float* Asrc = part ? hprev : a1;
    const int K = part ? NH : K1;
    const bool gather = (!part) && (K1 == NE);
    for (int kc = 0; kc < K; kc += 64){
      __syncthreads();
      for (int q = tid; q < 1024; q += 256){
        int kk = q >> 4;
        int bb = (q & 15) << 2;
        float4 v;
        if (gather){
          v.x = Asrc[(size_t)tokl[bb+0] * NE + kc + kk];
          v.y = Asrc[(size_t)tokl[bb+1] * NE + kc + kk];
          v.z = Asrc[(size_t)tokl[bb+2] * NE + kc + kk];
          v.w = Asrc[(size_t)tokl[bb+3] * NE + kc + kk];
        } else {
          v = *(const float4*)(Asrc + (size_t)(kc + kk) * NB + bblk + bb);
        }
        *(float4*)&As[kk][bb] = v;
      }
      for (int q = tid; q < 1024; q += 256){
        int r = q >> 4;
        int f = q & 15;
        int g = r >> 4;
        int jj = r & 15;
        float4 w = *(const float4*)(Wsrc + (size_t)(g * NH + jbase + jj) * K + kc + f * 4);
        float* wd = &Ws[(g * 16 + jj) * 68 + f * 4];
        wd[0] = w.x; wd[1] = w.y; wd[2] = w.z; wd[3] = w.w;
      }
      __syncthreads();
      #pragma unroll 2
      for (int kk = 0; kk < 64; kk += 4){
        float4 a0 = *(const float4*)&As[kk + 0][bl];
        float4 a1v = *(const float4*)&As[kk + 1][bl];
        float4 a2 = *(const float4*)&As[kk + 2][bl];
        float4 a3 = *(const float4*)&As[kk + 3][bl];
        #pragma unroll
        for (int g = 0; g < 4; g++){
          float4 w = *(const float4*)&Ws[(g * 16 + jl) * 68 + kk];
          acc[g][0] = fmaf(a0.x, w.x, acc[g][0]);
          acc[g][1] = fmaf(a0.y, w.x, acc[g][1]);
          acc[g][2] = fmaf(a0.z, w.x, acc[g][2]);
          acc[g][3] = fmaf(a0.w, w.x, acc[g][3]);
          acc[g][0] = fmaf(a1v.x, w.y, acc[g][0]);
          acc[g][1] = fmaf(a1v.y, w.y, acc[g][1]);
          acc[g][2] = fmaf(a1v.z, w.y, acc[g][2]);
          acc[g][3] = fmaf(a1v.w, w.y, acc[g][3]);
          acc[g][0] = fmaf(a2.x, w.z, acc[g][0]);
          acc[g][1] = fmaf(a2.y, w.z, acc[g][1]);
          acc[g][2] = fmaf(a2.z, w.z, acc[g][2]);
          acc[g][3] = fmaf(a2.w, w.z, acc[g][3]);
          acc[g][0] = fmaf(a3.x, w.w, acc[g][0]);
          acc[g][1] = fmaf(a3.y, w.w, acc[g][1]);
          acc[g][2] = fmaf(a3.z, w.w, acc[g][2]);
          acc[g][3] = fmaf(a3.w, w.w, acc[g][3]);
        }
      }
    }
  }

  float bi[4];
  #pragma unroll
  for (int g = 0; g < 4; g++) bi[g] = bih[g * NH + j] + bhh[g * NH + j];
  int b0g = bblk + bl;
  float4 cp = *(const float4*)(cprev + (size_t)j * NB + b0g);
  float cpv[4] = {cp.x, cp.y, cp.z, cp.w};
  float hs[4], cs[4];
  #pragma unroll
  for (int e = 0; e < 4; e++){
    float zi = acc[0][e] + bi[0];
    float zf = acc[1][e] + bi[1];
    float zg = acc[2][e] + bi[2];
    float zo = acc[3][e] + bi[3];
    float si = 1.f / (1.f + expf(-zi));
    float sf = 1.f / (1.f + expf(-zf));
    float so = 1.f / (1.f + expf(-zo));
    float tg = tanhf(zg);
    float c2 = sf * cpv[e] + si * tg;
    cs[e] = c2;
    hs[e] = so * tanhf(c2);
  }
  *(float4*)(cout + (size_t)j * NB + b0g) = make_float4(cs[0], cs[1], cs[2], cs[3]);
  *(float4*)(hout + (size_t)j * NB + b0g) = make_float4(hs[0], hs[1], hs[2], hs[3]);
}

// ---------------- gate + visual attention --------------------------------------
__global__ __launch_bounds__(256) void k_gateattn(
    const float* __restrict__ h1t,
    const float* __restrict__ gw1, const float* __restrict__ gb1,
    const float* __restrict__ gw2, const float* __restrict__ gb2,
    const float* __restrict__ vp,
    float* __restrict__ o2t)
{
  int b = blockIdx.x;
  int tid = threadIdx.x;
  __shared__ float hsm[NH];
  __shared__ float tsm[NH];
  __shared__ float osm[NH];
  __shared__ float aw[NNV];
  __shared__ float red[256];
  for (int h = tid; h < NH; h += 256) hsm[h] = h1t[(size_t)h * NB + b];
  __syncthreads();
  for (int jj = tid; jj < NH; jj += 256){
    const float4* wr = (const float4*)(gw1 + (size_t)jj * NH);
    const float4* h4 = (const float4*)hsm;
    float acc = 0.f;
    #pragma unroll 4
    for (int k = 0; k < NH/4; k++){
      float4 w = wr[k]; float4 hh = h4[k];
      acc = fmaf(hh.x, w.x, acc);
      acc = fmaf(hh.y, w.y, acc);
      acc = fmaf(hh.z, w.z, acc);
      acc = fmaf(hh.w, w.w, acc);
    }
    tsm[jj] = tanhf(acc + gb1[jj]);
  }
  __syncthreads();
  float part = 0.f;
  for (int jj = tid; jj < NH; jj += 256) part = fmaf(tsm[jj], gw2[jj], part);
  red[tid] = part; __syncthreads();
  for (int s = 128; s > 0; s >>= 1){ if (tid < s) red[tid] += red[tid + s]; __syncthreads(); }
  float gate = 1.f / (1.f + expf(-(red[0] + gb2[0])));
  __syncthreads();
  for (int h = tid; h < NH; h += 256) osm[h] = hsm[h] * gate;
  __syncthreads();
  const float* vpb = vp + (size_t)b * NNV * NH;
  float sc = 0.f;
  if (tid < NNV){
    const float4* vr = (const float4*)(vpb + (size_t)tid * NH);
    const float4* o4 = (const float4*)osm;
    float accv = 0.f;
    #pragma unroll 4
    for (int k = 0; k < NH/4; k++){
      float4 v = vr[k]; float4 oo = o4[k];
      accv = fmaf(oo.x, v.x, accv);
      accv = fmaf(oo.y, v.y, accv);
      accv = fmaf(oo.z, v.z, accv);
      accv = fmaf(oo.w, v.w, accv);
    }
    sc = accv / 22.62741699796952f;   // scores / sqrt(512)
  }
  red[tid] = (tid < NNV) ? sc : -INFINITY;
  __syncthreads();
  for (int s = 128; s > 0; s >>= 1){ if (tid < s) red[tid] = fmaxf(red[tid], red[tid + s]); __syncthreads(); }
  float mx = red[0];
  __syncthreads();
  float ev = (tid < NNV) ? expf(sc - mx) : 0.f;
  red[tid] = ev; __syncthreads();
  for (int s = 128; s > 0; s >>= 1){ if (tid < s) red[tid] += red[tid + s]; __syncthreads(); }
  float zs = red[0];
  if (tid < NNV) aw[tid] = ev / zs;
  __syncthreads();
  for (int h = tid; h < NH; h += 256){
    float accv = 0.f;
    for (int n = 0; n < NNV; n++) accv = fmaf(aw[n], vpb[(size_t)n * NH + h], accv);
    o2t[(size_t)h * NB + b] = osm[h] + accv;
  }
}

// ---------------- logits GEMM + rep-penalty + temperature -----------------------
__global__ __launch_bounds__(256, 4) void k_logits(
    const float* __restrict__ o2t,     // [NH][NB]
    const float* __restrict__ outw,    // [NVOC][NH]
    const float* __restrict__ outb,
    const int* __restrict__ toks, int step,
    float* __restrict__ logits)        // [NB][NVOC]
{
  __shared__ float osh[32][NB];
  __shared__ float wsh[32][72];
  __shared__ int hist[NB][3];
  int tid = threadIdx.x;
  int vbase = blockIdx.x * 64;
  int vl = (tid & 31) * 2;
  int b0 = (tid >> 5) * 16;
  if (tid < NB){
    hist[tid][0] = (step >= 1) ? toks[(size_t)tid * NSTEPS + step - 1] : -1;
    hist[tid][1] = (step >= 2) ? toks[(size_t)tid * NSTEPS + step - 2] : -1;
    hist[tid][2] = (step >= 3) ? toks[(size_t)tid * NSTEPS + step - 3] : -1;
  }
  float acc0[16], acc1[16];
  #pragma unroll
  for (int i = 0; i < 16; i++){ acc0[i] = 0.f; acc1[i] = 0.f; }

  for (int hc = 0; hc < NH; hc += 32){
    __syncthreads();
    #pragma unroll
    for (int q = tid; q < 1024; q += 256){
      int kk = q >> 5;
      int bb = (q & 31) << 2;
      *(float4*)&osh[kk][bb] = *(const float4*)(o2t + (size_t)(hc + kk) * NB + bb);
    }
    #pragma unroll
    for (int q = tid; q < 512; q += 256){
      int vr = q >> 3;
      int f4 = q & 7;
      float4 w = *(const float4*)(outw + (size_t)(vbase + vr) * NH + hc + f4 * 4);
      wsh[f4*4 + 0][vr] = w.x;
      wsh[f4*4 + 1][vr] = w.y;
      wsh[f4*4 + 2][vr] = w.z;
      wsh[f4*4 + 3][vr] = w.w;
    }
    __syncthreads();
    #pragma unroll 4
    for (int hl = 0; hl < 32; hl++){
      float w0 = wsh[hl][vl];
      float w1 = wsh[hl][vl + 1];
      #pragma unroll
      for (int bq = 0; bq < 4; bq++){
        float4 a = *(const float4*)&osh[hl][b0 + bq * 4];
        acc0[bq*4+0] = fmaf(a.x, w0, acc0[bq*4+0]);
        acc1[bq*4+0] = fmaf(a.x, w1, acc1[bq*4+0]);
        acc0[bq*4+1] = fmaf(a.y, w0, acc0[bq*4+1]);
        acc1[bq*4+1] = fmaf(a.y, w1, acc1[bq*4+1]);
        acc0[bq*4+2] = fmaf(a.z, w0, acc0[bq*4+2]);
        acc1[bq*4+2] = fmaf(a.z, w1, acc1[bq*4+2]);
        acc0[bq*4+3] = fmaf(a.w, w0, acc0[bq*4+3]);
        acc1[bq*4+3] = fmaf(a.w, w1, acc1[bq*4+3]);
      }
    }
  }
  __syncthreads();
  int v0 = vbase + vl;
  int v1 = v0 + 1;
  float ob0 = outb[v0], ob1 = outb[v1];
  #pragma unroll
  for (int i = 0; i < 16; i++){
    int b = b0 + i;
    float l0 = acc0[i] + ob0;
    float l1 = acc1[i] + ob1;
    int h1v = hist[b][0], h2v = hist[b][1], h3v = hist[b][2];
    if (v0 == h1v || v0 == h2v || v0 == h3v) l0 -= 2.0f;
    if (v1 == h1v || v1 == h2v || v1 == h3v) l1 -= 2.0f;
    l0 = l0 / 0.8f;
    l1 = l1 / 0.8f;
    *(float2*)(logits + (size_t)b * NVOC + v0) = make_float2(l0, l1);
  }
}

// ---------------- per-row stats: max, Z (softmax denom), min --------------------
__global__ __launch_bounds__(256) void k_rowstats(
    const float* __restrict__ logits, float* __restrict__ stats)
{
  int b = blockIdx.x, tid = threadIdx.x;
  const float4* lr = (const float4*)(logits + (size_t)b * NVOC);
  float mx = -INFINITY, mn = INFINITY;
  for (int i = tid; i < NVOC/4; i += 256){
    float4 v = lr[i];
    mx = fmaxf(mx, fmaxf(fmaxf(v.x, v.y), fmaxf(v.z, v.w)));
    mn = fminf(mn, fminf(fminf(v.x, v.y), fminf(v.z, v.w)));
  }
  __shared__ float ra[256], rb[256];
  ra[tid] = mx; rb[tid] = mn; __syncthreads();
  for (int s = 128; s > 0; s >>= 1){
    if (tid < s){ ra[tid] = fmaxf(ra[tid], ra[tid+s]); rb[tid] = fminf(rb[tid], rb[tid+s]); }
    __syncthreads();
  }
  float M = ra[0], mnv = rb[0];
  __syncthreads();
  float z = 0.f;
  for (int i = tid; i < NVOC/4; i += 256){
    float4 v = lr[i];
    z += expf(v.x - M) + expf(v.y - M) + expf(v.z - M) + expf(v.w - M);
  }
  ra[tid] = z; __syncthreads();
  for (int s = 128; s > 0; s >>= 1){ if (tid < s) ra[tid] += ra[tid+s]; __syncthreads(); }
  if (tid == 0) *(float4*)(stats + b * 4) = make_float4(M, ra[0], mnv, 0.f);
}

// ---------------- phase A: parallel LSD radix sort (descending) + exp fill ------
// One block (1024 threads) per row. 8 passes x 4-bit on key = ~(u ^ (neg ?
// 0xFFFFFFFF : 0x80000000)) so ascending-key == descending-float. Stable via
// contiguous 32-element chunks per thread + per-thread sequential ranks held
// in exclusive LDS u16 columns (no atomics, no dynamic-indexed reg arrays).
// Produces the exact descending multiset of float bit patterns.
__global__ __launch_bounds__(1024) void k_radix(
    const float* __restrict__ logits,
    const float* __restrict__ stats,
    float* __restrict__ pbuf,       // ping buffer A (NB x NVOC), ends as p-array
    float* __restrict__ sortbuf)    // pong buffer B (NB x SORTSTRIDE), final sorted
{
  int b = blockIdx.x, tid = threadIdx.x;
  const float* lrow = logits + (size_t)b * NVOC;
  float* A = pbuf + (size_t)b * NVOC;
  float* B = sortbuf + (size_t)b * SORTSTRIDE;
  __shared__ unsigned short hist[16 * 1024];   // [digit][thread], 32 KB
  __shared__ int s0[1024];

  int base = tid * 32;                 // this thread's contiguous element chunk
  bool active = (base < NVOC);         // threads 1000..1023 idle (1000*32 = 32000)

  for (int pass = 0; pass < 8; pass++){
    const float* src = (pass == 0) ? lrow : ((pass & 1) ? A : B);
    float* dst = (pass & 1) ? B : A;   // pass 7 (odd) -> B = sortbuf (final)
    int sh = pass * 4;

    // zero histogram
    for (int i = tid; i < 8192; i += 1024) ((unsigned int*)hist)[i] = 0;
    __syncthreads();

    // per-thread histogram of 32 contiguous elements (LDS u16 column, exclusive)
    if (active){
      for (int q = 0; q < 32; q++){
        unsigned int u = __float_as_uint(src[base + q]);
        unsigned int key = ~(u ^ ((unsigned int)(((int)u) >> 31) | 0x80000000u));
        unsigned int d = (key >> sh) & 15u;
        hist[d * 1024 + tid]++;
      }
    }
    __syncthreads();

    // exclusive prefix over flat [d*1024+t] order (digit-major, thread-minor):
    // thread q owns 16 consecutive flat entries [q*16, q*16+16)
    int fbase = tid * 16;
    unsigned short loc[16];
    int mysum = 0;
    #pragma unroll
    for (int i = 0; i < 16; i++){ loc[i] = hist[fbase + i]; mysum += loc[i]; }
    s0[tid] = mysum;
    __syncthreads();
    for (int off = 1; off < 1024; off <<= 1){
      int v = s0[tid];
      int add = (tid >= off) ? s0[tid - off] : 0;
      __syncthreads();
      s0[tid] = v + add;
      __syncthreads();
    }
    int run = (tid > 0) ? s0[tid - 1] : 0;
    #pragma unroll
    for (int i = 0; i < 16; i++){
      hist[fbase + i] = (unsigned short)run;
      run += loc[i];
    }
    __syncthreads();

    // stable scatter: rank = hist[d][tid]++ (exclusive column, no atomics)
    if (active){
      for (int q = 0; q < 32; q++){
        float f = src[base + q];
        unsigned int u = __float_as_uint(f);
        unsigned int key = ~(u ^ ((unsigned int)(((int)u) >> 31) | 0x80000000u));
        unsigned int d = (key >> sh) & 15u;
        unsigned short pos = hist[d * 1024 + tid]++;
        dst[pos] = f;
      }
    }
    __syncthreads();
  }

  // p-array for the serial scan (bit-identical expression to prior versions)
  float4 st4 = *(const float4*)(stats + b * 4);
  float M = st4.x, Z = st4.y;
  for (int i = tid; i < NVOC; i += 1024){
    A[i] = expf(B[i] - M) / Z;
  }
}

// ---------------- phase B: exact fp32 sequential cumsum (inline asm) ------------
// Single lane per row. Hand-scheduled GCN loop: 8 global_load_dwordx4 in flight
// (pinned v[40:71]), running sum chained through one VGPR in exact element
// order -> bit-identical to the prior sequential scan. ~6-9 cyc/element.
__global__ __launch_bounds__(64) void k_scan(
    const float* __restrict__ pbuf,
    const float* __restrict__ sortbuf,
    float* __restrict__ thrv,
    int* __restrict__ thrc)
{
  int b = blockIdx.x;
  if (threadIdx.x != 0) return;
  const float* prow = pbuf + (size_t)b * NVOC;
  const float* sbuf = sortbuf + (size_t)b * SORTSTRIDE;

  float s = 0.f;
  float prev = 0.f;
  uint32_t voff = 0;
  const uint32_t vend = NVOC * 4u;   // 128000 bytes; 1000 iters of 32 elems

#define QBLK(R0,R1,R2,R3,RQ,OFF) \
  "s_waitcnt vmcnt(7)\n\t" \
  "v_add_f32 %[s], %[s], " R0 "\n\t" \
  "v_add_f32 %[s], %[s], " R1 "\n\t" \
  "v_add_f32 %[s], %[s], " R2 "\n\t" \
  "v_add_f32 %[s], %[s], " R3 "\n\t" \
  "global_load_dwordx4 " RQ ", %[voff], %[base] offset:" OFF "\n\t"

  asm volatile(
    "global_load_dwordx4 v[40:43], %[voff], %[base] offset:0\n\t"
    "global_load_dwordx4 v[44:47], %[voff], %[base] offset:16\n\t"
    "global_load_dwordx4 v[48:51], %[voff], %[base] offset:32\n\t"
    "global_load_dwordx4 v[52:55], %[voff], %[base] offset:48\n\t"
    "global_load_dwordx4 v[56:59], %[voff], %[base] offset:64\n\t"
    "global_load_dwordx4 v[60:63], %[voff], %[base] offset:80\n\t"
    "global_load_dwordx4 v[64:67], %[voff], %[base] offset:96\n\t"
    "global_load_dwordx4 v[68:71], %[voff], %[base] offset:112\n\t"
    "Lscan%=:\n\t"
    "v_mov_b32 %[prev], %[s]\n\t"
    QBLK("v40","v41","v42","v43","v[40:43]","128")
    QBLK("v44","v45","v46","v47","v[44:47]","144")
    QBLK("v48","v49","v50","v51","v[48:51]","160")
    QBLK("v52","v53","v54","v55","v[52:55]","176")
    QBLK("v56","v57","v58","v59","v[56:59]","192")
    QBLK("v60","v61","v62","v63","v[60:63]","208")
    QBLK("v64","v65","v66","v67","v[64:67]","224")
    QBLK("v68","v69","v70","v71","v[68:71]","240")
    "v_add_u32 %[voff], 128, %[voff]\n\t"
    "v_cmp_lt_f32 vcc, 0x3f666666, %[s]\n\t"   // 0.9f < s
    "s_cbranch_vccnz Ldone%=\n\t"
    "v_cmp_lt_u32 vcc, %[voff], %[vend]\n\t"
    "s_cbranch_vccnz Lscan%=\n\t"
    "Ldone%=:\n\t"
    "s_waitcnt vmcnt(0)\n\t"
    : [s]"+v"(s), [voff]"+v"(voff), [prev]"+v"(prev)
    : [base]"s"(prow), [vend]"v"(vend)
    : "vcc", "memory",
      "v40","v41","v42","v43","v44","v45","v46","v47",
      "v48","v49","v50","v51","v52","v53","v54","v55",
      "v56","v57","v58","v59","v60","v61","v62","v63",
      "v64","v65","v66","v67","v68","v69","v70","v71");
#undef QBLK

  int ks;
  if (s > 0.9f){
    int idx0 = (int)(voff >> 2) - 32;   // first element of the crossing group
    float t = prev;                     // exact running sum at group start
    ks = idx0 + 31;
    for (int q = 0; q < 32; q++){
      t = t + prow[idx0 + q];           // same values, same add order -> bit-exact
      if (t > 0.9f){ ks = idx0 + q; break; }
    }
  } else {
    ks = NVOC - 1;
  }
  float tv = sbuf[ks];
  int jlo = ks;
  while (jlo > 0 && sbuf[jlo - 1] == tv) jlo--;
  thrv[b] = tv;
  thrc[b] = ks + 1 - jlo;   // tokens equal to tv kept (stable index order)
}

// ---------------- phase C: gumbel-max over kept set -----------------------------
__global__ __launch_bounds__(1024) void k_pick(
    const float* __restrict__ logits,
    const float* __restrict__ thrv,
    const int* __restrict__ thrc,
    int* __restrict__ toks,
    int step)
{
  int b = blockIdx.x, tid = threadIdx.x;
  const float* lr = logits + (size_t)b * NVOC;
  __shared__ int s0[1024];
  __shared__ float redv[1024];
  __shared__ int redi[1024];

  float tval = thrv[b];
  int ckeep = thrc[b];

  // rank-among-equals (stable argsort tie order = ascending original index)
  int stt = tid * 32;
  int en = min(stt + 32, NVOC);
  int eqc = 0;
  for (int i = stt; i < en; i++) eqc += (lr[i] == tval) ? 1 : 0;
  s0[tid] = eqc;
  __syncthreads();
  for (int off = 1; off < 1024; off <<= 1){
    int v = s0[tid];
    int add = (tid >= off) ? s0[tid - off] : 0;
    __syncthreads();
    s0[tid] = v + add;
    __syncthreads();
  }
  int eqrank = s0[tid] - eqc;

  uint32_t fk0, fk1;
  threefry2x32(0u, 42u, 0u, (uint32_t)step, fk0, fk1);   // fold_in(key(42), step)
  float best = -INFINITY;
  int besti = NVOC;
  for (int i = stt; i < en; i++){
    float l = lr[i];
    bool keep;
    if (l > tval) keep = true;
    else if (l == tval){ keep = (eqrank < ckeep); eqrank++; }
    else keep = false;
    if (keep){
      uint32_t o0, o1;
      threefry2x32(fk0, fk1, 0u, (uint32_t)(b * NVOC + i), o0, o1);
      uint32_t bits = o0 ^ o1;
      uint32_t fb = (bits >> 9) | 0x3f800000u;
      float u = __uint_as_float(fb) - 1.0f;
      if (u == 0.0f) u = 1.17549435e-38f;   // minval = tiny
      float gum = -logf(-logf(u));
      float cand = l + gum;
      if (cand > best){ best = cand; besti = i; }
    }
  }
  redv[tid] = best;
  redi[tid] = besti;
  __syncthreads();
  for (int s = 512; s > 0; s >>= 1){
    if (tid < s){
      float ov = redv[tid + s]; int oi = redi[tid + s];
      if (ov > redv[tid] || (ov == redv[tid] && oi < redi[tid])){
        redv[tid] = ov; redi[tid] = oi;
      }
    }
    __syncthreads();
  }
  if (tid == 0) toks[(size_t)b * NSTEPS + step] = redi[0];
}

// ---------------- host launcher -------------------------------------------------
extern "C" void kernel_launch(void* const* d_in, const int* in_sizes, int n_in,
                              void* d_out, int out_size, void* d_ws, size_t ws_size,
                              hipStream_t stream)
{
  (void)in_sizes; (void)n_in; (void)out_size;
  const float* thought = (const float*)d_in[0];
  const float* vfeat   = (const float*)d_in[1];
  const float* emb     = (const float*)d_in[2];
  const float* w_ih0   = (const float*)d_in[3];
  const float* w_hh0   = (const float*)d_in[4];
  const float* b_ih0   = (const float*)d_in[5];
  const float* b_hh0   = (const float*)d_in[6];
  const float* w_ih1   = (const float*)d_in[7];
  const float* w_hh1   = (const float*)d_in[8];
  const float* b_ih1   = (const float*)d_in[9];
  const float* b_hh1   = (const float*)d_in[10];
  const float* gw1     = (const float*)d_in[11];
  const float* gb1     = (const float*)d_in[12];
  const float* gw2     = (const float*)d_in[13];
  const float* gb2     = (const float*)d_in[14];
  const float* out_w   = (const float*)d_in[15];
  const float* out_b   = (const float*)d_in[16];
  const float* vis_w   = (const float*)d_in[17];
  const float* vis_b   = (const float*)d_in[18];
  const float* ln_g    = (const float*)d_in[19];
  const float* ln_b    = (const float*)d_in[20];
  int* toks = (int*)d_out;

  char* ws = (char*)d_ws;
  size_t off = 0;
  auto alloc = [&](size_t bytes) -> void* {
    void* p = ws + off;
    off += (bytes + 255) & ~(size_t)255;
    return p;
  };
  float* vp      = (float*)alloc((size_t)NB * NNV * NH * 4);
  float* h0a     = (float*)alloc((size_t)NH * NB * 4);
  float* h0b     = (float*)alloc((size_t)NH * NB * 4);
  float* c0a     = (float*)alloc((size_t)NH * NB * 4);
  float* c0b     = (float*)alloc((size_t)NH * NB * 4);
  float* h1a     = (float*)alloc((size_t)NH * NB * 4);
  float* h1b     = (float*)alloc((size_t)NH * NB * 4);
  float* c1a     = (float*)alloc((size_t)NH * NB * 4);
  float* c1b     = (float*)alloc((size_t)NH * NB * 4);
  float* o2t     = (float*)alloc((size_t)NH * NB * 4);
  float* logits  = (float*)alloc((size_t)NB * NVOC * 4);
  float* pbuf    = (float*)alloc((size_t)NB * NVOC * 4);      // radix ping / p-array
  float* sortbuf = (float*)alloc((size_t)NB * SORTSTRIDE * 4);// radix pong / sorted
  float* stats   = (float*)alloc((size_t)NB * 4 * 4);
  float* thrv    = (float*)alloc((size_t)NB * 4);
  int*   thrc    = (int*)alloc((size_t)NB * 4);
  if (off > ws_size) return;  // insufficient scratch: fail loudly via wrong output

  k_visproj<<<NB * NNV, 256, 0, stream>>>(vfeat, vis_w, vis_b, ln_g, ln_b, vp);
  k_init<<<(NH * NB + 255) / 256, 256, 0, stream>>>(thought, h0a, c0a, h1a, c1a);

  for (int step = 0; step < NSTEPS; step++){
    float *h0r, *h0w, *c0r, *c0w, *h1r, *h1w, *c1r, *c1w;
    if ((step & 1) == 0){
      h0r = h0a; h0w = h0b; c0r = c0a; c0w = c0b;
      h1r = h1a; h1w = h1b; c1r = c1a; c1w = c1b;
    } else {
      h0r = h0b; h0w = h0a; c0r = c0b; c0w = c0a;
      h1r = h1b; h1w = h1a; c1r = c1b; c1w = c1a;
    }
    k_lstm<NE><<<dim3(32, 2), 256, 0, stream>>>(
        w_ih0, w_hh0, b_ih0, b_hh0, emb, toks, step, h0r, c0r, h0w, c0w);
    k_lstm<NH><<<dim3(32, 2), 256, 0, stream>>>(
        w_ih1, w_hh1, b_ih1, b_hh1, h0w, toks, step, h1r, c1r, h1w, c1w);
    k_gateattn<<<NB, 256, 0, stream>>>(h1w, gw1, gb1, gw2, gb2, vp, o2t);
    k_logits<<<NVOC / 64, 256, 0, stream>>>(o2t, out_w, out_b, toks, step, logits);
    k_rowstats<<<NB, 256, 0, stream>>>(logits, stats);
    k_radix<<<NB, 1024, 0, stream>>>(logits, stats, pbuf, sortbuf);
    k_scan<<<NB, 64, 0, stream>>>(pbuf, sortbuf, thrv, thrc);
    k_pick<<<NB, 1024, 0, stream>>>(logits, thrv, thrc, toks, step);
  }
}

// Round 7
// 26498.792 us; speedup vs baseline: 4.7107x; 1.0079x over previous
//
#include <hip/hip_runtime.h>
#include <stdint.h>

#define NB 128      // batch
#define NH 512      // hidden
#define NE 128      // embedding dim
#define NVOC 32000  // vocab
#define NNV 196     // visual tokens
#define NDV 256     // visual dim
#define NSTEPS 32
#define SORTSTRIDE 32768

// ---------------- Threefry-2x32 (20 rounds), exact JAX semantics --------------
static __device__ __forceinline__ uint32_t rotl32(uint32_t x, int r){
  return (x << r) | (x >> (32 - r));
}

static __device__ __forceinline__ void threefry2x32(uint32_t k0, uint32_t k1,
    uint32_t x0, uint32_t x1, uint32_t &o0, uint32_t &o1){
  uint32_t k2 = k0 ^ k1 ^ 0x1BD11BDAu;
  x0 += k0; x1 += k1;
#define TF_RND(r) { x0 += x1; x1 = rotl32(x1,(r)); x1 ^= x0; }
  TF_RND(13) TF_RND(15) TF_RND(26) TF_RND(6)
  x0 += k1; x1 += k2 + 1u;
  TF_RND(17) TF_RND(29) TF_RND(16) TF_RND(24)
  x0 += k2; x1 += k0 + 2u;
  TF_RND(13) TF_RND(15) TF_RND(26) TF_RND(6)
  x0 += k0; x1 += k1 + 3u;
  TF_RND(17) TF_RND(29) TF_RND(16) TF_RND(24)
  x0 += k1; x1 += k2 + 4u;
  TF_RND(13) TF_RND(15) TF_RND(26) TF_RND(6)
  x0 += k2; x1 += k0 + 5u;
#undef TF_RND
  o0 = x0; o1 = x1;
}

// ---------------- visual projection + LayerNorm ------------------------------
__global__ __launch_bounds__(256) void k_visproj(
    const float* __restrict__ vf, const float* __restrict__ vis_w,
    const float* __restrict__ vis_b, const float* __restrict__ ln_g,
    const float* __restrict__ ln_b, float* __restrict__ vp)
{
  int bn = blockIdx.x;                 // b*NNV + n
  int tid = threadIdx.x;
  __shared__ float xs[NDV];
  __shared__ float red[256];
  const float* x = vf + (size_t)bn * NDV;
  xs[tid] = x[tid];                    // 256 threads == NDV
  __syncthreads();
  float out0, out1;
  {
    const float4* h4 = (const float4*)xs;
    const float4* w0 = (const float4*)(vis_w + (size_t)tid * NDV);
    const float4* w1 = (const float4*)(vis_w + (size_t)(tid + 256) * NDV);
    float a0 = 0.f, a1 = 0.f;
    #pragma unroll 4
    for (int k = 0; k < NDV/4; k++){
      float4 hh = h4[k];
      float4 wa = w0[k], wb = w1[k];
      a0 = fmaf(hh.x, wa.x, a0); a0 = fmaf(hh.y, wa.y, a0);
      a0 = fmaf(hh.z, wa.z, a0); a0 = fmaf(hh.w, wa.w, a0);
      a1 = fmaf(hh.x, wb.x, a1); a1 = fmaf(hh.y, wb.y, a1);
      a1 = fmaf(hh.z, wb.z, a1); a1 = fmaf(hh.w, wb.w, a1);
    }
    out0 = a0 + vis_b[tid];
    out1 = a1 + vis_b[tid + 256];
  }
  red[tid] = out0 + out1; __syncthreads();
  for (int s = 128; s > 0; s >>= 1){ if (tid < s) red[tid] += red[tid + s]; __syncthreads(); }
  float mu = red[0] * (1.0f / (float)NH);
  __syncthreads();
  float d0 = out0 - mu, d1 = out1 - mu;
  red[tid] = d0*d0 + d1*d1; __syncthreads();
  for (int s = 128; s > 0; s >>= 1){ if (tid < s) red[tid] += red[tid + s]; __syncthreads(); }
  float var = red[0] * (1.0f / (float)NH);
  float r = 1.0f / sqrtf(var + 1e-5f);
  float* op = vp + (size_t)bn * NH;
  op[tid]       = d0 * r * ln_g[tid]       + ln_b[tid];
  op[tid + 256] = d1 * r * ln_g[tid + 256] + ln_b[tid + 256];
}

// ---------------- init hidden states ------------------------------------------
__global__ void k_init(const float* __restrict__ thought,
                       float* __restrict__ h0, float* __restrict__ c0,
                       float* __restrict__ h1, float* __restrict__ c1)
{
  int id = blockIdx.x * 256 + threadIdx.x;
  if (id >= NH * NB) return;
  int k = id >> 7;
  int b = id & 127;
  float v = thought[(size_t)b * NH + k];
  h0[id] = v; h1[id] = v; c0[id] = 0.f; c1[id] = 0.f;
}

// ---------------- fused LSTM layer (GEMM + cell) -------------------------------
template<int K1>
__global__ __launch_bounds__(256) void k_lstm(
    const float* __restrict__ wih, const float* __restrict__ whh,
    const float* __restrict__ bih, const float* __restrict__ bhh,
    const float* __restrict__ a1,
    const int*   __restrict__ toks, int step,
    const float* __restrict__ hprev, const float* __restrict__ cprev,
    float* __restrict__ hout, float* __restrict__ cout)
{
  __shared__ float As[64][64];
  __shared__ float Ws[4 * 16 * 68];
  __shared__ int tokl[64];
  int tid = threadIdx.x;
  int jl = tid & 15;
  int bg = tid >> 4;
  int jbase = blockIdx.x * 16;
  int j = jbase + jl;
  int bblk = blockIdx.y * 64;
  int bl = bg * 4;
  if (K1 == NE){
    if (tid < 64) tokl[tid] = (step == 0) ? 1 : toks[(size_t)(bblk + tid) * NSTEPS + step - 1];
  }
  __syncthreads();

  float acc[4][4];
  #pragma unroll
  for (int g = 0; g < 4; g++)
    #pragma unroll
    for (int e = 0; e < 4; e++) acc[g][e] = 0.f;

  for (int part = 0; part < 2; part++){
    const float* Wsrc = part ? whh : wih;
    const float* Asrc = part ? hprev : a1;
    const int K = part ? NH : K1;
    const bool gather = (!part) && (K1 == NE);
    for (int kc = 0; kc < K; kc += 64){
      __syncthreads();
      for (int q = tid; q < 1024; q += 256){
        int kk = q >> 4;
        int bb = (q & 15) << 2;
        float4 v;
        if (gather){
          v.x = Asrc[(size_t)tokl[bb+0] * NE + kc + kk];
          v.y = Asrc[(size_t)tokl[bb+1] * NE + kc + kk];
          v.z = Asrc[(size_t)tokl[bb+2] * NE + kc + kk];
          v.w = Asrc[(size_t)tokl[bb+3] * NE + kc + kk];
        } else {
          v = *(const float4*)(Asrc + (size_t)(kc + kk) * NB + bblk + bb);
        }
        *(float4*)&As[kk][bb] = v;
      }
      for (int q = tid; q < 1024; q += 256){
        int r = q >> 4;
        int f = q & 15;
        int g = r >> 4;
        int jj = r & 15;
        float4 w = *(const float4*)(Wsrc + (size_t)(g * NH + jbase + jj) * K + kc + f * 4);
        float* wd = &Ws[(g * 16 + jj) * 68 + f * 4];
        wd[0] = w.x; wd[1] = w.y; wd[2] = w.z; wd[3] = w.w;
      }
      __syncthreads();
      #pragma unroll 2
      for (int kk = 0; kk < 64; kk += 4){
        float4 a0 = *(const float4*)&As[kk + 0][bl];
        float4 a1v = *(const float4*)&As[kk + 1][bl];
        float4 a2 = *(const float4*)&As[kk + 2][bl];
        float4 a3 = *(const float4*)&As[kk + 3][bl];
        #pragma unroll
        for (int g = 0; g < 4; g++){
          float4 w = *(const float4*)&Ws[(g * 16 + jl) * 68 + kk];
          acc[g][0] = fmaf(a0.x, w.x, acc[g][0]);
          acc[g][1] = fmaf(a0.y, w.x, acc[g][1]);
          acc[g][2] = fmaf(a0.z, w.x, acc[g][2]);
          acc[g][3] = fmaf(a0.w, w.x, acc[g][3]);
          acc[g][0] = fmaf(a1v.x, w.y, acc[g][0]);
          acc[g][1] = fmaf(a1v.y, w.y, acc[g][1]);
          acc[g][2] = fmaf(a1v.z, w.y, acc[g][2]);
          acc[g][3] = fmaf(a1v.w, w.y, acc[g][3]);
          acc[g][0] = fmaf(a2.x, w.z, acc[g][0]);
          acc[g][1] = fmaf(a2.y, w.z, acc[g][1]);
          acc[g][2] = fmaf(a2.z, w.z, acc[g][2]);
          acc[g][3] = fmaf(a2.w, w.z, acc[g][3]);
          acc[g][0] = fmaf(a3.x, w.w, acc[g][0]);
          acc[g][1] = fmaf(a3.y, w.w, acc[g][1]);
          acc[g][2] = fmaf(a3.z, w.w, acc[g][2]);
          acc[g][3] = fmaf(a3.w, w.w, acc[g][3]);
        }
      }
    }
  }

  float bi[4];
  #pragma unroll
  for (int g = 0; g < 4; g++) bi[g] = bih[g * NH + j] + bhh[g * NH + j];
  int b0g = bblk + bl;
  float4 cp = *(const float4*)(cprev + (size_t)j * NB + b0g);
  float cpv[4] = {cp.x, cp.y, cp.z, cp.w};
  float hs[4], cs[4];
  #pragma unroll
  for (int e = 0; e < 4; e++){
    float zi = acc[0][e] + bi[0];
    float zf = acc[1][e] + bi[1];
    float zg = acc[2][e] + bi[2];
    float zo = acc[3][e] + bi[3];
    float si = 1.f / (1.f + expf(-zi));
    float sf = 1.f / (1.f + expf(-zf));
    float so = 1.f / (1.f + expf(-zo));
    float tg = tanhf(zg);
    float c2 = sf * cpv[e] + si * tg;
    cs[e] = c2;
    hs[e] = so * tanhf(c2);
  }
  *(float4*)(cout + (size_t)j * NB + b0g) = make_float4(cs[0], cs[1], cs[2], cs[3]);
  *(float4*)(hout + (size_t)j * NB + b0g) = make_float4(hs[0], hs[1], hs[2], hs[3]);
}

// ---------------- gate + visual attention --------------------------------------
__global__ __launch_bounds__(256) void k_gateattn(
    const float* __restrict__ h1t,
    const float* __restrict__ gw1, const float* __restrict__ gb1,
    const float* __restrict__ gw2, const float* __restrict__ gb2,
    const float* __restrict__ vp,
    float* __restrict__ o2t)
{
  int b = blockIdx.x;
  int tid = threadIdx.x;
  __shared__ float hsm[NH];
  __shared__ float tsm[NH];
  __shared__ float osm[NH];
  __shared__ float aw[NNV];
  __shared__ float red[256];
  for (int h = tid; h < NH; h += 256) hsm[h] = h1t[(size_t)h * NB + b];
  __syncthreads();
  for (int jj = tid; jj < NH; jj += 256){
    const float4* wr = (const float4*)(gw1 + (size_t)jj * NH);
    const float4* h4 = (const float4*)hsm;
    float acc = 0.f;
    #pragma unroll 4
    for (int k = 0; k < NH/4; k++){
      float4 w = wr[k]; float4 hh = h4[k];
      acc = fmaf(hh.x, w.x, acc);
      acc = fmaf(hh.y, w.y, acc);
      acc = fmaf(hh.z, w.z, acc);
      acc = fmaf(hh.w, w.w, acc);
    }
    tsm[jj] = tanhf(acc + gb1[jj]);
  }
  __syncthreads();
  float part = 0.f;
  for (int jj = tid; jj < NH; jj += 256) part = fmaf(tsm[jj], gw2[jj], part);
  red[tid] = part; __syncthreads();
  for (int s = 128; s > 0; s >>= 1){ if (tid < s) red[tid] += red[tid + s]; __syncthreads(); }
  float gate = 1.f / (1.f + expf(-(red[0] + gb2[0])));
  __syncthreads();
  for (int h = tid; h < NH; h += 256) osm[h] = hsm[h] * gate;
  __syncthreads();
  const float* vpb = vp + (size_t)b * NNV * NH;
  float sc = 0.f;
  if (tid < NNV){
    const float4* vr = (const float4*)(vpb + (size_t)tid * NH);
    const float4* o4 = (const float4*)osm;
    float accv = 0.f;
    #pragma unroll 4
    for (int k = 0; k < NH/4; k++){
      float4 v = vr[k]; float4 oo = o4[k];
      accv = fmaf(oo.x, v.x, accv);
      accv = fmaf(oo.y, v.y, accv);
      accv = fmaf(oo.z, v.z, accv);
      accv = fmaf(oo.w, v.w, accv);
    }
    sc = accv / 22.62741699796952f;   // scores / sqrt(512)
  }
  red[tid] = (tid < NNV) ? sc : -INFINITY;
  __syncthreads();
  for (int s = 128; s > 0; s >>= 1){ if (tid < s) red[tid] = fmaxf(red[tid], red[tid + s]); __syncthreads(); }
  float mx = red[0];
  __syncthreads();
  float ev = (tid < NNV) ? expf(sc - mx) : 0.f;
  red[tid] = ev; __syncthreads();
  for (int s = 128; s > 0; s >>= 1){ if (tid < s) red[tid] += red[tid + s]; __syncthreads(); }
  float zs = red[0];
  if (tid < NNV) aw[tid] = ev / zs;
  __syncthreads();
  for (int h = tid; h < NH; h += 256){
    float accv = 0.f;
    for (int n = 0; n < NNV; n++) accv = fmaf(aw[n], vpb[(size_t)n * NH + h], accv);
    o2t[(size_t)h * NB + b] = osm[h] + accv;
  }
}

// ---------------- logits GEMM + rep-penalty + temperature -----------------------
__global__ __launch_bounds__(256, 4) void k_logits(
    const float* __restrict__ o2t,     // [NH][NB]
    const float* __restrict__ outw,    // [NVOC][NH]
    const float* __restrict__ outb,
    const int* __restrict__ toks, int step,
    float* __restrict__ logits)        // [NB][NVOC]
{
  __shared__ float osh[32][NB];
  __shared__ float wsh[32][72];
  __shared__ int hist[NB][3];
  int tid = threadIdx.x;
  int vbase = blockIdx.x * 64;
  int vl = (tid & 31) * 2;
  int b0 = (tid >> 5) * 16;
  if (tid < NB){
    hist[tid][0] = (step >= 1) ? toks[(size_t)tid * NSTEPS + step - 1] : -1;
    hist[tid][1] = (step >= 2) ? toks[(size_t)tid * NSTEPS + step - 2] : -1;
    hist[tid][2] = (step >= 3) ? toks[(size_t)tid * NSTEPS + step - 3] : -1;
  }
  float acc0[16], acc1[16];
  #pragma unroll
  for (int i = 0; i < 16; i++){ acc0[i] = 0.f; acc1[i] = 0.f; }

  for (int hc = 0; hc < NH; hc += 32){
    __syncthreads();
    #pragma unroll
    for (int q = tid; q < 1024; q += 256){
      int kk = q >> 5;
      int bb = (q & 31) << 2;
      *(float4*)&osh[kk][bb] = *(const float4*)(o2t + (size_t)(hc + kk) * NB + bb);
    }
    #pragma unroll
    for (int q = tid; q < 512; q += 256){
      int vr = q >> 3;
      int f4 = q & 7;
      float4 w = *(const float4*)(outw + (size_t)(vbase + vr) * NH + hc + f4 * 4);
      wsh[f4*4 + 0][vr] = w.x;
      wsh[f4*4 + 1][vr] = w.y;
      wsh[f4*4 + 2][vr] = w.z;
      wsh[f4*4 + 3][vr] = w.w;
    }
    __syncthreads();
    #pragma unroll 4
    for (int hl = 0; hl < 32; hl++){
      float w0 = wsh[hl][vl];
      float w1 = wsh[hl][vl + 1];
      #pragma unroll
      for (int bq = 0; bq < 4; bq++){
        float4 a = *(const float4*)&osh[hl][b0 + bq * 4];
        acc0[bq*4+0] = fmaf(a.x, w0, acc0[bq*4+0]);
        acc1[bq*4+0] = fmaf(a.x, w1, acc1[bq*4+0]);
        acc0[bq*4+1] = fmaf(a.y, w0, acc0[bq*4+1]);
        acc1[bq*4+1] = fmaf(a.y, w1, acc1[bq*4+1]);
        acc0[bq*4+2] = fmaf(a.z, w0, acc0[bq*4+2]);
        acc1[bq*4+2] = fmaf(a.z, w1, acc1[bq*4+2]);
        acc0[bq*4+3] = fmaf(a.w, w0, acc0[bq*4+3]);
        acc1[bq*4+3] = fmaf(a.w, w1, acc1[bq*4+3]);
      }
    }
  }
  __syncthreads();
  int v0 = vbase + vl;
  int v1 = v0 + 1;
  float ob0 = outb[v0], ob1 = outb[v1];
  #pragma unroll
  for (int i = 0; i < 16; i++){
    int b = b0 + i;
    float l0 = acc0[i] + ob0;
    float l1 = acc1[i] + ob1;
    int h1v = hist[b][0], h2v = hist[b][1], h3v = hist[b][2];
    if (v0 == h1v || v0 == h2v || v0 == h3v) l0 -= 2.0f;
    if (v1 == h1v || v1 == h2v || v1 == h3v) l1 -= 2.0f;
    l0 = l0 / 0.8f;
    l1 = l1 / 0.8f;
    *(float2*)(logits + (size_t)b * NVOC + v0) = make_float2(l0, l1);
  }
}

// ---------------- per-row stats: max, Z (softmax denom), min --------------------
__global__ __launch_bounds__(256) void k_rowstats(
    const float* __restrict__ logits, float* __restrict__ stats)
{
  int b = blockIdx.x, tid = threadIdx.x;
  const float4* lr = (const float4*)(logits + (size_t)b * NVOC);
  float mx = -INFINITY, mn = INFINITY;
  for (int i = tid; i < NVOC/4; i += 256){
    float4 v = lr[i];
    mx = fmaxf(mx, fmaxf(fmaxf(v.x, v.y), fmaxf(v.z, v.w)));
    mn = fminf(mn, fminf(fminf(v.x, v.y), fminf(v.z, v.w)));
  }
  __shared__ float ra[256], rb[256];
  ra[tid] = mx; rb[tid] = mn; __syncthreads();
  for (int s = 128; s > 0; s >>= 1){
    if (tid < s){ ra[tid] = fmaxf(ra[tid], ra[tid+s]); rb[tid] = fminf(rb[tid], rb[tid+s]); }
    __syncthreads();
  }
  float M = ra[0], mnv = rb[0];
  __syncthreads();
  float z = 0.f;
  for (int i = tid; i < NVOC/4; i += 256){
    float4 v = lr[i];
    z += expf(v.x - M) + expf(v.y - M) + expf(v.z - M) + expf(v.w - M);
  }
  ra[tid] = z; __syncthreads();
  for (int s = 128; s > 0; s >>= 1){ if (tid < s) ra[tid] += ra[tid+s]; __syncthreads(); }
  if (tid == 0) *(float4*)(stats + b * 4) = make_float4(M, ra[0], mnv, 0.f);
}

// ---------------- phase A: 4-pass 8-bit LSD radix (ballot-ranked) + exp fill ----
// One block (1024 threads = 16 waves) per row. Wave w owns contiguous chunk
// [w*2048, w*2048+qmax*64); element order (w, q, lane) == ascending index, so
// the per-(digit,wave) offset scatter is stable -> LSD correct. Key map
// ~(u ^ (neg ? 0xFFFFFFFF : 0x80000000)): ascending key == descending float.
// Values-only output -> bit-identical sorted array.
__global__ __launch_bounds__(1024) void k_radix(
    const float* __restrict__ logits,
    const float* __restrict__ stats,
    float* __restrict__ pbuf,       // ping A (NB x NVOC), ends as p-array
    float* __restrict__ sortbuf)    // pong B (NB x SORTSTRIDE), final sorted
{
  int b = blockIdx.x, tid = threadIdx.x;
  int lane = tid & 63, w = tid >> 6;
  const float* lrow = logits + (size_t)b * NVOC;
  float* A = pbuf + (size_t)b * NVOC;
  float* B = sortbuf + (size_t)b * SORTSTRIDE;
  __shared__ unsigned int offs[256 * 16];   // [digit][wave], 16 KB
  __shared__ int s0[1024];

  int ebase = w * 2048;
  int qmax = (NVOC - ebase) >> 6;           // waves 0-14: 32, wave 15: 20
  if (qmax > 32) qmax = 32;
  unsigned long long below = (1ull << lane) - 1ull;

  for (int pass = 0; pass < 4; pass++){
    const float* src = (pass == 0) ? lrow : ((pass & 1) ? A : B);
    float* dst = (pass & 1) ? B : A;        // pass 3 (odd) -> B = sortbuf
    int sh = pass * 8;

    for (int i = tid; i < 4096; i += 1024) offs[i] = 0u;
    __syncthreads();

    // histogram: ballot-match per q, one leader lane updates per-(d,w) counter
    for (int q = 0; q < qmax; q++){
      float f = src[ebase + q * 64 + lane];
      unsigned u = __float_as_uint(f);
      unsigned key = ~(u ^ ((unsigned)(((int)u) >> 31) | 0x80000000u));
      unsigned d = (key >> sh) & 255u;
      unsigned long long m = ~0ull;
      #pragma unroll
      for (int bit = 0; bit < 8; bit++){
        unsigned long long bb = __ballot((d >> bit) & 1u);
        m &= ((d >> bit) & 1u) ? bb : ~bb;
      }
      int rank = __popcll(m & below);
      if (rank == 0) offs[d * 16 + w] += (unsigned)__popcll(m);
    }
    __syncthreads();

    // exclusive prefix over flat [d*16 + w]; thread owns 4 consecutive entries
    int fb = tid * 4;
    unsigned l0 = offs[fb], l1 = offs[fb+1], l2 = offs[fb+2], l3 = offs[fb+3];
    s0[tid] = (int)(l0 + l1 + l2 + l3);
    __syncthreads();
    for (int off = 1; off < 1024; off <<= 1){
      int v = s0[tid];
      int add = (tid >= off) ? s0[tid - off] : 0;
      __syncthreads();
      s0[tid] = v + add;
      __syncthreads();
    }
    unsigned run = (tid > 0) ? (unsigned)s0[tid - 1] : 0u;
    offs[fb]   = run; run += l0;
    offs[fb+1] = run; run += l1;
    offs[fb+2] = run; run += l2;
    offs[fb+3] = run;
    __syncthreads();

    // stable scatter: all equal-digit lanes read the shared offset (broadcast),
    // leader bumps it after (same-wave DS ops are in program order)
    for (int q = 0; q < qmax; q++){
      float f = src[ebase + q * 64 + lane];
      unsigned u = __float_as_uint(f);
      unsigned key = ~(u ^ ((unsigned)(((int)u) >> 31) | 0x80000000u));
      unsigned d = (key >> sh) & 255u;
      unsigned long long m = ~0ull;
      #pragma unroll
      for (int bit = 0; bit < 8; bit++){
        unsigned long long bb = __ballot((d >> bit) & 1u);
        m &= ((d >> bit) & 1u) ? bb : ~bb;
      }
      int rank = __popcll(m & below);
      unsigned cur = offs[d * 16 + w];
      dst[cur + rank] = f;
      if (rank == 0) offs[d * 16 + w] = cur + (unsigned)__popcll(m);
    }
    __syncthreads();
  }

  // p-array for the serial scan (bit-identical expression to prior versions)
  float4 st4 = *(const float4*)(stats + b * 4);
  float M = st4.x, Z = st4.y;
  for (int i = tid; i < NVOC; i += 1024){
    A[i] = expf(B[i] - M) / Z;
  }
}

// ---------------- phase B: exact fp32 sequential cumsum (inline asm) ------------
__global__ __launch_bounds__(64) void k_scan(
    const float* __restrict__ pbuf,
    const float* __restrict__ sortbuf,
    float* __restrict__ thrv,
    int* __restrict__ thrc)
{
  int b = blockIdx.x;
  if (threadIdx.x != 0) return;
  const float* prow = pbuf + (size_t)b * NVOC;
  const float* sbuf = sortbuf + (size_t)b * SORTSTRIDE;

  float s = 0.f;
  float prev = 0.f;
  uint32_t voff = 0;
  const uint32_t vend = NVOC * 4u;   // 128000 bytes; 1000 iters of 32 elems

#define QBLK(R0,R1,R2,R3,RQ,OFF) \
  "s_waitcnt vmcnt(7)\n\t" \
  "v_add_f32 %[s], %[s], " R0 "\n\t" \
  "v_add_f32 %[s], %[s], " R1 "\n\t" \
  "v_add_f32 %[s], %[s], " R2 "\n\t" \
  "v_add_f32 %[s], %[s], " R3 "\n\t" \
  "global_load_dwordx4 " RQ ", %[voff], %[base] offset:" OFF "\n\t"

  asm volatile(
    "global_load_dwordx4 v[40:43], %[voff], %[base] offset:0\n\t"
    "global_load_dwordx4 v[44:47], %[voff], %[base] offset:16\n\t"
    "global_load_dwordx4 v[48:51], %[voff], %[base] offset:32\n\t"
    "global_load_dwordx4 v[52:55], %[voff], %[base] offset:48\n\t"
    "global_load_dwordx4 v[56:59], %[voff], %[base] offset:64\n\t"
    "global_load_dwordx4 v[60:63], %[voff], %[base] offset:80\n\t"
    "global_load_dwordx4 v[64:67], %[voff], %[base] offset:96\n\t"
    "global_load_dwordx4 v[68:71], %[voff], %[base] offset:112\n\t"
    "Lscan%=:\n\t"
    "v_mov_b32 %[prev], %[s]\n\t"
    QBLK("v40","v41","v42","v43","v[40:43]","128")
    QBLK("v44","v45","v46","v47","v[44:47]","144")
    QBLK("v48","v49","v50","v51","v[48:51]","160")
    QBLK("v52","v53","v54","v55","v[52:55]","176")
    QBLK("v56","v57","v58","v59","v[56:59]","192")
    QBLK("v60","v61","v62","v63","v[60:63]","208")
    QBLK("v64","v65","v66","v67","v[64:67]","224")
    QBLK("v68","v69","v70","v71","v[68:71]","240")
    "v_add_u32 %[voff], 128, %[voff]\n\t"
    "v_cmp_lt_f32 vcc, 0x3f666666, %[s]\n\t"   // 0.9f < s
    "s_cbranch_vccnz Ldone%=\n\t"
    "v_cmp_lt_u32 vcc, %[voff], %[vend]\n\t"
    "s_cbranch_vccnz Lscan%=\n\t"
    "Ldone%=:\n\t"
    "s_waitcnt vmcnt(0)\n\t"
    : [s]"+v"(s), [voff]"+v"(voff), [prev]"+v"(prev)
    : [base]"s"(prow), [vend]"v"(vend)
    : "vcc", "memory",
      "v40","v41","v42","v43","v44","v45","v46","v47",
      "v48","v49","v50","v51","v52","v53","v54","v55",
      "v56","v57","v58","v59","v60","v61","v62","v63",
      "v64","v65","v66","v67","v68","v69","v70","v71");
#undef QBLK

  int ks;
  if (s > 0.9f){
    int idx0 = (int)(voff >> 2) - 32;   // first element of the crossing group
    float t = prev;                     // exact running sum at group start
    ks = idx0 + 31;
    for (int q = 0; q < 32; q++){
      t = t + prow[idx0 + q];           // same values, same add order -> bit-exact
      if (t > 0.9f){ ks = idx0 + q; break; }
    }
  } else {
    ks = NVOC - 1;
  }
  float tv = sbuf[ks];
  int jlo = ks;
  while (jlo > 0 && sbuf[jlo - 1] == tv) jlo--;
  thrv[b] = tv;
  thrc[b] = ks + 1 - jlo;   // tokens equal to tv kept (stable index order)
}

// ---------------- phase C: gumbel-max over kept set -----------------------------
__global__ __launch_bounds__(1024) void k_pick(
    const float* __restrict__ logits,
    const float* __restrict__ thrv,
    const int* __restrict__ thrc,
    int* __restrict__ toks,
    int step)
{
  int b = blockIdx.x, tid = threadIdx.x;
  const float* lr = logits + (size_t)b * NVOC;
  __shared__ int s0[1024];
  __shared__ float redv[1024];
  __shared__ int redi[1024];

  float tval = thrv[b];
  int ckeep = thrc[b];

  // rank-among-equals (stable argsort tie order = ascending original index)
  int stt = tid * 32;
  int en = min(stt + 32, NVOC);
  int eqc = 0;
  for (int i = stt; i < en; i++) eqc += (lr[i] == tval) ? 1 : 0;
  s0[tid] = eqc;
  __syncthreads();
  for (int off = 1; off < 1024; off <<= 1){
    int v = s0[tid];
    int add = (tid >= off) ? s0[tid - off] : 0;
    __syncthreads();
    s0[tid] = v + add;
    __syncthreads();
  }
  int eqrank = s0[tid] - eqc;

  uint32_t fk0, fk1;
  threefry2x32(0u, 42u, 0u, (uint32_t)step, fk0, fk1);   // fold_in(key(42), step)
  float best = -INFINITY;
  int besti = NVOC;
  for (int i = stt; i < en; i++){
    float l = lr[i];
    bool keep;
    if (l > tval) keep = true;
    else if (l == tval){ keep = (eqrank < ckeep); eqrank++; }
    else keep = false;
    if (keep){
      uint32_t o0, o1;
      threefry2x32(fk0, fk1, 0u, (uint32_t)(b * NVOC + i), o0, o1);
      uint32_t bits = o0 ^ o1;
      uint32_t fb = (bits >> 9) | 0x3f800000u;
      float u = __uint_as_float(fb) - 1.0f;
      if (u == 0.0f) u = 1.17549435e-38f;   // minval = tiny
      float gum = -logf(-logf(u));
      float cand = l + gum;
      if (cand > best){ best = cand; besti = i; }
    }
  }
  redv[tid] = best;
  redi[tid] = besti;
  __syncthreads();
  for (int s = 512; s > 0; s >>= 1){
    if (tid < s){
      float ov = redv[tid + s]; int oi = redi[tid + s];
      if (ov > redv[tid] || (ov == redv[tid] && oi < redi[tid])){
        redv[tid] = ov; redi[tid] = oi;
      }
    }
    __syncthreads();
  }
  if (tid == 0) toks[(size_t)b * NSTEPS + step] = redi[0];
}

// ---------------- host launcher -------------------------------------------------
extern "C" void kernel_launch(void* const* d_in, const int* in_sizes, int n_in,
                              void* d_out, int out_size, void* d_ws, size_t ws_size,
                              hipStream_t stream)
{
  (void)in_sizes; (void)n_in; (void)out_size;
  const float* thought = (const float*)d_in[0];
  const float* vfeat   = (const float*)d_in[1];
  const float* emb     = (const float*)d_in[2];
  const float* w_ih0   = (const float*)d_in[3];
  const float* w_hh0   = (const float*)d_in[4];
  const float* b_ih0   = (const float*)d_in[5];
  const float* b_hh0   = (const float*)d_in[6];
  const float* w_ih1   = (const float*)d_in[7];
  const float* w_hh1   = (const float*)d_in[8];
  const float* b_ih1   = (const float*)d_in[9];
  const float* b_hh1   = (const float*)d_in[10];
  const float* gw1     = (const float*)d_in[11];
  const float* gb1     = (const float*)d_in[12];
  const float* gw2     = (const float*)d_in[13];
  const float* gb2     = (const float*)d_in[14];
  const float* out_w   = (const float*)d_in[15];
  const float* out_b   = (const float*)d_in[16];
  const float* vis_w   = (const float*)d_in[17];
  const float* vis_b   = (const float*)d_in[18];
  const float* ln_g    = (const float*)d_in[19];
  const float* ln_b    = (const float*)d_in[20];
  int* toks = (int*)d_out;

  char* ws = (char*)d_ws;
  size_t off = 0;
  auto alloc = [&](size_t bytes) -> void* {
    void* p = ws + off;
    off += (bytes + 255) & ~(size_t)255;
    return p;
  };
  float* vp      = (float*)alloc((size_t)NB * NNV * NH * 4);
  float* h0a     = (float*)alloc((size_t)NH * NB * 4);
  float* h0b     = (float*)alloc((size_t)NH * NB * 4);
  float* c0a     = (float*)alloc((size_t)NH * NB * 4);
  float* c0b     = (float*)alloc((size_t)NH * NB * 4);
  float* h1a     = (float*)alloc((size_t)NH * NB * 4);
  float* h1b     = (float*)alloc((size_t)NH * NB * 4);
  float* c1a     = (float*)alloc((size_t)NH * NB * 4);
  float* c1b     = (float*)alloc((size_t)NH * NB * 4);
  float* o2t     = (float*)alloc((size_t)NH * NB * 4);
  float* logits  = (float*)alloc((size_t)NB * NVOC * 4);
  float* pbuf    = (float*)alloc((size_t)NB * NVOC * 4);      // radix ping / p-array
  float* sortbuf = (float*)alloc((size_t)NB * SORTSTRIDE * 4);// radix pong / sorted
  float* stats   = (float*)alloc((size_t)NB * 4 * 4);
  float* thrv    = (float*)alloc((size_t)NB * 4);
  int*   thrc    = (int*)alloc((size_t)NB * 4);
  if (off > ws_size) return;  // insufficient scratch: fail loudly via wrong output

  k_visproj<<<NB * NNV, 256, 0, stream>>>(vfeat, vis_w, vis_b, ln_g, ln_b, vp);
  k_init<<<(NH * NB + 255) / 256, 256, 0, stream>>>(thought, h0a, c0a, h1a, c1a);

  for (int step = 0; step < NSTEPS; step++){
    float *h0r, *h0w, *c0r, *c0w, *h1r, *h1w, *c1r, *c1w;
    if ((step & 1) == 0){
      h0r = h0a; h0w = h0b; c0r = c0a; c0w = c0b;
      h1r = h1a; h1w = h1b; c1r = c1a; c1w = c1b;
    } else {
      h0r = h0b; h0w = h0a; c0r = c0b; c0w = c0a;
      h1r = h1b; h1w = h1a; c1r = c1b; c1w = c1a;
    }
    k_lstm<NE><<<dim3(32, 2), 256, 0, stream>>>(
        w_ih0, w_hh0, b_ih0, b_hh0, emb, toks, step, h0r, c0r, h0w, c0w);
    k_lstm<NH><<<dim3(32, 2), 256, 0, stream>>>(
        w_ih1, w_hh1, b_ih1, b_hh1, h0w, toks, step, h1r, c1r, h1w, c1w);
    k_gateattn<<<NB, 256, 0, stream>>>(h1w, gw1, gb1, gw2, gb2, vp, o2t);
    k_logits<<<NVOC / 64, 256, 0, stream>>>(o2t, out_w, out_b, toks, step, logits);
    k_rowstats<<<NB, 256, 0, stream>>>(logits, stats);
    k_radix<<<NB, 1024, 0, stream>>>(logits, stats, pbuf, sortbuf);
    k_scan<<<NB, 64, 0, stream>>>(pbuf, sortbuf, thrv, thrc);
    k_pick<<<NB, 1024, 0, stream>>>(logits, thrv, thrc, toks, step);
  }
}

// Round 8
// 24349.513 us; speedup vs baseline: 5.1265x; 1.0883x over previous
//
#include <hip/hip_runtime.h>
#include <stdint.h>

#define NB 128      // batch
#define NH 512      // hidden
#define NE 128      // embedding dim
#define NVOC 32000  // vocab
#define NNV 196     // visual tokens
#define NDV 256     // visual dim
#define NSTEPS 32
#define SORTSTRIDE 32768
#define SCHUNK 16000   // k_scan LDS chunk (floats); 2 chunks cover NVOC

// ---------------- Threefry-2x32 (20 rounds), exact JAX semantics --------------
static __device__ __forceinline__ uint32_t rotl32(uint32_t x, int r){
  return (x << r) | (x >> (32 - r));
}

static __device__ __forceinline__ void threefry2x32(uint32_t k0, uint32_t k1,
    uint32_t x0, uint32_t x1, uint32_t &o0, uint32_t &o1){
  uint32_t k2 = k0 ^ k1 ^ 0x1BD11BDAu;
  x0 += k0; x1 += k1;
#define TF_RND(r) { x0 += x1; x1 = rotl32(x1,(r)); x1 ^= x0; }
  TF_RND(13) TF_RND(15) TF_RND(26) TF_RND(6)
  x0 += k1; x1 += k2 + 1u;
  TF_RND(17) TF_RND(29) TF_RND(16) TF_RND(24)
  x0 += k2; x1 += k0 + 2u;
  TF_RND(13) TF_RND(15) TF_RND(26) TF_RND(6)
  x0 += k0; x1 += k1 + 3u;
  TF_RND(17) TF_RND(29) TF_RND(16) TF_RND(24)
  x0 += k1; x1 += k2 + 4u;
  TF_RND(13) TF_RND(15) TF_RND(26) TF_RND(6)
  x0 += k2; x1 += k0 + 5u;
#undef TF_RND
  o0 = x0; o1 = x1;
}

// ---------------- visual projection + LayerNorm ------------------------------
__global__ __launch_bounds__(256) void k_visproj(
    const float* __restrict__ vf, const float* __restrict__ vis_w,
    const float* __restrict__ vis_b, const float* __restrict__ ln_g,
    const float* __restrict__ ln_b, float* __restrict__ vp)
{
  int bn = blockIdx.x;                 // b*NNV + n
  int tid = threadIdx.x;
  __shared__ float xs[NDV];
  __shared__ float red[256];
  const float* x = vf + (size_t)bn * NDV;
  xs[tid] = x[tid];                    // 256 threads == NDV
  __syncthreads();
  float out0, out1;
  {
    const float4* h4 = (const float4*)xs;
    const float4* w0 = (const float4*)(vis_w + (size_t)tid * NDV);
    const float4* w1 = (const float4*)(vis_w + (size_t)(tid + 256) * NDV);
    float a0 = 0.f, a1 = 0.f;
    #pragma unroll 4
    for (int k = 0; k < NDV/4; k++){
      float4 hh = h4[k];
      float4 wa = w0[k], wb = w1[k];
      a0 = fmaf(hh.x, wa.x, a0); a0 = fmaf(hh.y, wa.y, a0);
      a0 = fmaf(hh.z, wa.z, a0); a0 = fmaf(hh.w, wa.w, a0);
      a1 = fmaf(hh.x, wb.x, a1); a1 = fmaf(hh.y, wb.y, a1);
      a1 = fmaf(hh.z, wb.z, a1); a1 = fmaf(hh.w, wb.w, a1);
    }
    out0 = a0 + vis_b[tid];
    out1 = a1 + vis_b[tid + 256];
  }
  red[tid] = out0 + out1; __syncthreads();
  for (int s = 128; s > 0; s >>= 1){ if (tid < s) red[tid] += red[tid + s]; __syncthreads(); }
  float mu = red[0] * (1.0f / (float)NH);
  __syncthreads();
  float d0 = out0 - mu, d1 = out1 - mu;
  red[tid] = d0*d0 + d1*d1; __syncthreads();
  for (int s = 128; s > 0; s >>= 1){ if (tid < s) red[tid] += red[tid + s]; __syncthreads(); }
  float var = red[0] * (1.0f / (float)NH);
  float r = 1.0f / sqrtf(var + 1e-5f);
  float* op = vp + (size_t)bn * NH;
  op[tid]       = d0 * r * ln_g[tid]       + ln_b[tid];
  op[tid + 256] = d1 * r * ln_g[tid + 256] + ln_b[tid + 256];
}

// ---------------- init hidden states ------------------------------------------
__global__ void k_init(const float* __restrict__ thought,
                       float* __restrict__ h0, float* __restrict__ c0,
                       float* __restrict__ h1, float* __restrict__ c1)
{
  int id = blockIdx.x * 256 + threadIdx.x;
  if (id >= NH * NB) return;
  int k = id >> 7;
  int b = id & 127;
  float v = thought[(size_t)b * NH + k];
  h0[id] = v; h1[id] = v; c0[id] = 0.f; c1[id] = 0.f;
}

// ---------------- fused LSTM layer (GEMM + cell) -------------------------------
template<int K1>
__global__ __launch_bounds__(256) void k_lstm(
    const float* __restrict__ wih, const float* __restrict__ whh,
    const float* __restrict__ bih, const float* __restrict__ bhh,
    const float* __restrict__ a1,
    const int*   __restrict__ toks, int step,
    const float* __restrict__ hprev, const float* __restrict__ cprev,
    float* __restrict__ hout, float* __restrict__ cout)
{
  __shared__ float As[64][64];
  __shared__ float Ws[4 * 16 * 68];
  __shared__ int tokl[64];
  int tid = threadIdx.x;
  int jl = tid & 15;
  int bg = tid >> 4;
  int jbase = blockIdx.x * 16;
  int j = jbase + jl;
  int bblk = blockIdx.y * 64;
  int bl = bg * 4;
  if (K1 == NE){
    if (tid < 64) tokl[tid] = (step == 0) ? 1 : toks[(size_t)(bblk + tid) * NSTEPS + step - 1];
  }
  __syncthreads();

  float acc[4][4];
  #pragma unroll
  for (int g = 0; g < 4; g++)
    #pragma unroll
    for (int e = 0; e < 4; e++) acc[g][e] = 0.f;

  for (int part = 0; part < 2; part++){
    const float* Wsrc = part ? whh : wih;
    const float* Asrc = part ? hprev : a1;
    const int K = part ? NH : K1;
    const bool gather = (!part) && (K1 == NE);
    for (int kc = 0; kc < K; kc += 64){
      __syncthreads();
      for (int q = tid; q < 1024; q += 256){
        int kk = q >> 4;
        int bb = (q & 15) << 2;
        float4 v;
        if (gather){
          v.x = Asrc[(size_t)tokl[bb+0] * NE + kc + kk];
          v.y = Asrc[(size_t)tokl[bb+1] * NE + kc + kk];
          v.z = Asrc[(size_t)tokl[bb+2] * NE + kc + kk];
          v.w = Asrc[(size_t)tokl[bb+3] * NE + kc + kk];
        } else {
          v = *(const float4*)(Asrc + (size_t)(kc + kk) * NB + bblk + bb);
        }
        *(float4*)&As[kk][bb] = v;
      }
      for (int q = tid; q < 1024; q += 256){
        int r = q >> 4;
        int f = q & 15;
        int g = r >> 4;
        int jj = r & 15;
        float4 w = *(const float4*)(Wsrc + (size_t)(g * NH + jbase + jj) * K + kc + f * 4);
        float* wd = &Ws[(g * 16 + jj) * 68 + f * 4];
        wd[0] = w.x; wd[1] = w.y; wd[2] = w.z; wd[3] = w.w;
      }
      __syncthreads();
      #pragma unroll 2
      for (int kk = 0; kk < 64; kk += 4){
        float4 a0 = *(const float4*)&As[kk + 0][bl];
        float4 a1v = *(const float4*)&As[kk + 1][bl];
        float4 a2 = *(const float4*)&As[kk + 2][bl];
        float4 a3 = *(const float4*)&As[kk + 3][bl];
        #pragma unroll
        for (int g = 0; g < 4; g++){
          float4 w = *(const float4*)&Ws[(g * 16 + jl) * 68 + kk];
          acc[g][0] = fmaf(a0.x, w.x, acc[g][0]);
          acc[g][1] = fmaf(a0.y, w.x, acc[g][1]);
          acc[g][2] = fmaf(a0.z, w.x, acc[g][2]);
          acc[g][3] = fmaf(a0.w, w.x, acc[g][3]);
          acc[g][0] = fmaf(a1v.x, w.y, acc[g][0]);
          acc[g][1] = fmaf(a1v.y, w.y, acc[g][1]);
          acc[g][2] = fmaf(a1v.z, w.y, acc[g][2]);
          acc[g][3] = fmaf(a1v.w, w.y, acc[g][3]);
          acc[g][0] = fmaf(a2.x, w.z, acc[g][0]);
          acc[g][1] = fmaf(a2.y, w.z, acc[g][1]);
          acc[g][2] = fmaf(a2.z, w.z, acc[g][2]);
          acc[g][3] = fmaf(a2.w, w.z, acc[g][3]);
          acc[g][0] = fmaf(a3.x, w.w, acc[g][0]);
          acc[g][1] = fmaf(a3.y, w.w, acc[g][1]);
          acc[g][2] = fmaf(a3.z, w.w, acc[g][2]);
          acc[g][3] = fmaf(a3.w, w.w, acc[g][3]);
        }
      }
    }
  }

  float bi[4];
  #pragma unroll
  for (int g = 0; g < 4; g++) bi[g] = bih[g * NH + j] + bhh[g * NH + j];
  int b0g = bblk + bl;
  float4 cp = *(const float4*)(cprev + (size_t)j * NB + b0g);
  float cpv[4] = {cp.x, cp.y, cp.z, cp.w};
  float hs[4], cs[4];
  #pragma unroll
  for (int e = 0; e < 4; e++){
    float zi = acc[0][e] + bi[0];
    float zf = acc[1][e] + bi[1];
    float zg = acc[2][e] + bi[2];
    float zo = acc[3][e] + bi[3];
    float si = 1.f / (1.f + expf(-zi));
    float sf = 1.f / (1.f + expf(-zf));
    float so = 1.f / (1.f + expf(-zo));
    float tg = tanhf(zg);
    float c2 = sf * cpv[e] + si * tg;
    cs[e] = c2;
    hs[e] = so * tanhf(c2);
  }
  *(float4*)(cout + (size_t)j * NB + b0g) = make_float4(cs[0], cs[1], cs[2], cs[3]);
  *(float4*)(hout + (size_t)j * NB + b0g) = make_float4(hs[0], hs[1], hs[2], hs[3]);
}

// ---------------- gate + visual attention --------------------------------------
__global__ __launch_bounds__(256) void k_gateattn(
    const float* __restrict__ h1t,
    const float* __restrict__ gw1, const float* __restrict__ gb1,
    const float* __restrict__ gw2, const float* __restrict__ gb2,
    const float* __restrict__ vp,
    float* __restrict__ o2t)
{
  int b = blockIdx.x;
  int tid = threadIdx.x;
  __shared__ float hsm[NH];
  __shared__ float tsm[NH];
  __shared__ float osm[NH];
  __shared__ float aw[NNV];
  __shared__ float red[256];
  for (int h = tid; h < NH; h += 256) hsm[h] = h1t[(size_t)h * NB + b];
  __syncthreads();
  for (int jj = tid; jj < NH; jj += 256){
    const float4* wr = (const float4*)(gw1 + (size_t)jj * NH);
    const float4* h4 = (const float4*)hsm;
    float acc = 0.f;
    #pragma unroll 4
    for (int k = 0; k < NH/4; k++){
      float4 w = wr[k]; float4 hh = h4[k];
      acc = fmaf(hh.x, w.x, acc);
      acc = fmaf(hh.y, w.y, acc);
      acc = fmaf(hh.z, w.z, acc);
      acc = fmaf(hh.w, w.w, acc);
    }
    tsm[jj] = tanhf(acc + gb1[jj]);
  }
  __syncthreads();
  float part = 0.f;
  for (int jj = tid; jj < NH; jj += 256) part = fmaf(tsm[jj], gw2[jj], part);
  red[tid] = part; __syncthreads();
  for (int s = 128; s > 0; s >>= 1){ if (tid < s) red[tid] += red[tid + s]; __syncthreads(); }
  float gate = 1.f / (1.f + expf(-(red[0] + gb2[0])));
  __syncthreads();
  for (int h = tid; h < NH; h += 256) osm[h] = hsm[h] * gate;
  __syncthreads();
  const float* vpb = vp + (size_t)b * NNV * NH;
  float sc = 0.f;
  if (tid < NNV){
    const float4* vr = (const float4*)(vpb + (size_t)tid * NH);
    const float4* o4 = (const float4*)osm;
    float accv = 0.f;
    #pragma unroll 4
    for (int k = 0; k < NH/4; k++){
      float4 v = vr[k]; float4 oo = o4[k];
      accv = fmaf(oo.x, v.x, accv);
      accv = fmaf(oo.y, v.y, accv);
      accv = fmaf(oo.z, v.z, accv);
      accv = fmaf(oo.w, v.w, accv);
    }
    sc = accv / 22.62741699796952f;   // scores / sqrt(512)
  }
  red[tid] = (tid < NNV) ? sc : -INFINITY;
  __syncthreads();
  for (int s = 128; s > 0; s >>= 1){ if (tid < s) red[tid] = fmaxf(red[tid], red[tid + s]); __syncthreads(); }
  float mx = red[0];
  __syncthreads();
  float ev = (tid < NNV) ? expf(sc - mx) : 0.f;
  red[tid] = ev; __syncthreads();
  for (int s = 128; s > 0; s >>= 1){ if (tid < s) red[tid] += red[tid + s]; __syncthreads(); }
  float zs = red[0];
  if (tid < NNV) aw[tid] = ev / zs;
  __syncthreads();
  for (int h = tid; h < NH; h += 256){
    float accv = 0.f;
    for (int n = 0; n < NNV; n++) accv = fmaf(aw[n], vpb[(size_t)n * NH + h], accv);
    o2t[(size_t)h * NB + b] = osm[h] + accv;
  }
}

// ---------------- logits GEMM + rep-penalty + temperature -----------------------
__global__ __launch_bounds__(256, 4) void k_logits(
    const float* __restrict__ o2t,     // [NH][NB]
    const float* __restrict__ outw,    // [NVOC][NH]
    const float* __restrict__ outb,
    const int* __restrict__ toks, int step,
    float* __restrict__ logits)        // [NB][NVOC]
{
  __shared__ float osh[32][NB];
  __shared__ float wsh[32][72];
  __shared__ int hist[NB][3];
  int tid = threadIdx.x;
  int vbase = blockIdx.x * 64;
  int vl = (tid & 31) * 2;
  int b0 = (tid >> 5) * 16;
  if (tid < NB){
    hist[tid][0] = (step >= 1) ? toks[(size_t)tid * NSTEPS + step - 1] : -1;
    hist[tid][1] = (step >= 2) ? toks[(size_t)tid * NSTEPS + step - 2] : -1;
    hist[tid][2] = (step >= 3) ? toks[(size_t)tid * NSTEPS + step - 3] : -1;
  }
  float acc0[16], acc1[16];
  #pragma unroll
  for (int i = 0; i < 16; i++){ acc0[i] = 0.f; acc1[i] = 0.f; }

  for (int hc = 0; hc < NH; hc += 32){
    __syncthreads();
    #pragma unroll
    for (int q = tid; q < 1024; q += 256){
      int kk = q >> 5;
      int bb = (q & 31) << 2;
      *(float4*)&osh[kk][bb] = *(const float4*)(o2t + (size_t)(hc + kk) * NB + bb);
    }
    #pragma unroll
    for (int q = tid; q < 512; q += 256){
      int vr = q >> 3;
      int f4 = q & 7;
      float4 w = *(const float4*)(outw + (size_t)(vbase + vr) * NH + hc + f4 * 4);
      wsh[f4*4 + 0][vr] = w.x;
      wsh[f4*4 + 1][vr] = w.y;
      wsh[f4*4 + 2][vr] = w.z;
      wsh[f4*4 + 3][vr] = w.w;
    }
    __syncthreads();
    #pragma unroll 4
    for (int hl = 0; hl < 32; hl++){
      float w0 = wsh[hl][vl];
      float w1 = wsh[hl][vl + 1];
      #pragma unroll
      for (int bq = 0; bq < 4; bq++){
        float4 a = *(const float4*)&osh[hl][b0 + bq * 4];
        acc0[bq*4+0] = fmaf(a.x, w0, acc0[bq*4+0]);
        acc1[bq*4+0] = fmaf(a.x, w1, acc1[bq*4+0]);
        acc0[bq*4+1] = fmaf(a.y, w0, acc0[bq*4+1]);
        acc1[bq*4+1] = fmaf(a.y, w1, acc1[bq*4+1]);
        acc0[bq*4+2] = fmaf(a.z, w0, acc0[bq*4+2]);
        acc1[bq*4+2] = fmaf(a.z, w1, acc1[bq*4+2]);
        acc0[bq*4+3] = fmaf(a.w, w0, acc0[bq*4+3]);
        acc1[bq*4+3] = fmaf(a.w, w1, acc1[bq*4+3]);
      }
    }
  }
  __syncthreads();
  int v0 = vbase + vl;
  int v1 = v0 + 1;
  float ob0 = outb[v0], ob1 = outb[v1];
  #pragma unroll
  for (int i = 0; i < 16; i++){
    int b = b0 + i;
    float l0 = acc0[i] + ob0;
    float l1 = acc1[i] + ob1;
    int h1v = hist[b][0], h2v = hist[b][1], h3v = hist[b][2];
    if (v0 == h1v || v0 == h2v || v0 == h3v) l0 -= 2.0f;
    if (v1 == h1v || v1 == h2v || v1 == h3v) l1 -= 2.0f;
    l0 = l0 / 0.8f;
    l1 = l1 / 0.8f;
    *(float2*)(logits + (size_t)b * NVOC + v0) = make_float2(l0, l1);
  }
}

// ---------------- per-row stats: max, Z (softmax denom), min --------------------
__global__ __launch_bounds__(256) void k_rowstats(
    const float* __restrict__ logits, float* __restrict__ stats)
{
  int b = blockIdx.x, tid = threadIdx.x;
  const float4* lr = (const float4*)(logits + (size_t)b * NVOC);
  float mx = -INFINITY, mn = INFINITY;
  for (int i = tid; i < NVOC/4; i += 256){
    float4 v = lr[i];
    mx = fmaxf(mx, fmaxf(fmaxf(v.x, v.y), fmaxf(v.z, v.w)));
    mn = fminf(mn, fminf(fminf(v.x, v.y), fminf(v.z, v.w)));
  }
  __shared__ float ra[256], rb[256];
  ra[tid] = mx; rb[tid] = mn; __syncthreads();
  for (int s = 128; s > 0; s >>= 1){
    if (tid < s){ ra[tid] = fmaxf(ra[tid], ra[tid+s]); rb[tid] = fminf(rb[tid], rb[tid+s]); }
    __syncthreads();
  }
  float M = ra[0], mnv = rb[0];
  __syncthreads();
  float z = 0.f;
  for (int i = tid; i < NVOC/4; i += 256){
    float4 v = lr[i];
    z += expf(v.x - M) + expf(v.y - M) + expf(v.z - M) + expf(v.w - M);
  }
  ra[tid] = z; __syncthreads();
  for (int s = 128; s > 0; s >>= 1){ if (tid < s) ra[tid] += ra[tid+s]; __syncthreads(); }
  if (tid == 0) *(float4*)(stats + b * 4) = make_float4(M, ra[0], mnv, 0.f);
}

// ---------------- phase A: 4-pass 8-bit LSD radix (ballot-ranked) ---------------
// One block (1024 threads = 16 waves) per row. Wave w owns contiguous chunk
// [w*2048, ...); element order (w, q, lane) == ascending index -> stable.
// Key map ~(u ^ (neg ? 0xFFFFFFFF : 0x80000000)): ascending key == descending
// float. Prefix over [digit][wave] via shuffle scan (2 barriers, not 20).
__global__ __launch_bounds__(1024) void k_radix(
    const float* __restrict__ logits,
    float* __restrict__ pbuf,       // ping A (NB x NVOC)
    float* __restrict__ sortbuf)    // pong B (NB x SORTSTRIDE), final sorted
{
  int b = blockIdx.x, tid = threadIdx.x;
  int lane = tid & 63, w = tid >> 6;
  const float* lrow = logits + (size_t)b * NVOC;
  float* A = pbuf + (size_t)b * NVOC;
  float* B = sortbuf + (size_t)b * SORTSTRIDE;
  __shared__ unsigned int offs[256 * 16];   // [digit][wave], 16 KB
  __shared__ int wtot[16];

  int ebase = w * 2048;
  int qmax = (NVOC - ebase) >> 6;           // waves 0-14: 32, wave 15: 20
  if (qmax > 32) qmax = 32;
  unsigned long long below = (1ull << lane) - 1ull;

  for (int pass = 0; pass < 4; pass++){
    const float* src = (pass == 0) ? lrow : ((pass & 1) ? A : B);
    float* dst = (pass & 1) ? B : A;        // pass 3 (odd) -> B = sortbuf
    int sh = pass * 8;

    for (int i = tid; i < 4096; i += 1024) offs[i] = 0u;
    __syncthreads();

    // histogram: ballot-match per q, leader lane bumps per-(d,w) counter
    for (int q = 0; q < qmax; q++){
      float f = src[ebase + q * 64 + lane];
      unsigned u = __float_as_uint(f);
      unsigned key = ~(u ^ ((unsigned)(((int)u) >> 31) | 0x80000000u));
      unsigned d = (key >> sh) & 255u;
      unsigned long long m = ~0ull;
      #pragma unroll
      for (int bit = 0; bit < 8; bit++){
        unsigned long long bb = __ballot((d >> bit) & 1u);
        m &= ((d >> bit) & 1u) ? bb : ~bb;
      }
      int rank = __popcll(m & below);
      if (rank == 0) offs[d * 16 + w] += (unsigned)__popcll(m);
    }
    __syncthreads();

    // exclusive prefix over flat [d*16 + w]; thread owns 4 consecutive entries.
    // Wave shuffle scan + wave totals: 2 barriers total.
    int fb = tid * 4;
    unsigned l0 = offs[fb], l1 = offs[fb+1], l2 = offs[fb+2], l3 = offs[fb+3];
    int v = (int)(l0 + l1 + l2 + l3);
    int inc = v;
    #pragma unroll
    for (int dd = 1; dd < 64; dd <<= 1){
      int o = __shfl_up(inc, dd);
      if (lane >= dd) inc += o;
    }
    if (lane == 63) wtot[w] = inc;
    __syncthreads();
    int woff = 0;
    #pragma unroll
    for (int ww = 0; ww < 16; ww++) woff += (ww < w) ? wtot[ww] : 0;
    unsigned run = (unsigned)(woff + inc - v);
    offs[fb]   = run; run += l0;
    offs[fb+1] = run; run += l1;
    offs[fb+2] = run; run += l2;
    offs[fb+3] = run;
    __syncthreads();

    // stable scatter: equal-digit lanes broadcast-read the offset, leader bumps
    for (int q = 0; q < qmax; q++){
      float f = src[ebase + q * 64 + lane];
      unsigned u = __float_as_uint(f);
      unsigned key = ~(u ^ ((unsigned)(((int)u) >> 31) | 0x80000000u));
      unsigned d = (key >> sh) & 255u;
      unsigned long long m = ~0ull;
      #pragma unroll
      for (int bit = 0; bit < 8; bit++){
        unsigned long long bb = __ballot((d >> bit) & 1u);
        m &= ((d >> bit) & 1u) ? bb : ~bb;
      }
      int rank = __popcll(m & below);
      unsigned cur = offs[d * 16 + w];
      dst[cur + rank] = f;
      if (rank == 0) offs[d * 16 + w] = cur + (unsigned)__popcll(m);
    }
    __syncthreads();
  }
}

// ---------------- phase B: exact fp32 sequential cumsum (LDS-staged asm) --------
// 1024 threads stage 16000-element chunks of the sorted row into LDS, computing
// p = expf(B[i]-M)/Z during staging (same expression/inputs as before ->
// identical bits). Lane 0 then runs the hand-scheduled serial add chain over
// LDS via ds_read_b128 + lgkmcnt(7) pipelining (in-order DS). Add order is
// element-exact -> bit-identical crossing index.
__global__ __launch_bounds__(1024) void k_scan(
    const float* __restrict__ sortbuf,
    const float* __restrict__ stats,
    float* __restrict__ thrv,
    int* __restrict__ thrc)
{
  int b = blockIdx.x, tid = threadIdx.x;
  const float* sbuf = sortbuf + (size_t)b * SORTSTRIDE;
  __shared__ __align__(16) float pch[SCHUNK];   // 64000 B
  __shared__ int sh_k, sh_cross;

  float4 st4 = *(const float4*)(stats + b * 4);
  float M = st4.x, Z = st4.y;
  if (tid == 0){ sh_k = NVOC - 1; sh_cross = 0; }
  __syncthreads();

  float s = 0.f, prev = 0.f;
  uint32_t base = (uint32_t)(uintptr_t)(void*)&pch[0];  // low 32b of flat = LDS offset

  for (int cb = 0; cb < NVOC; cb += SCHUNK){
    // stage chunk with exp transform (coalesced float4)
    const float4* s4 = (const float4*)(sbuf + cb);
    for (int i = tid; i < SCHUNK/4; i += 1024){
      float4 v = s4[i];
      float4 p;
      p.x = expf(v.x - M) / Z;
      p.y = expf(v.y - M) / Z;
      p.z = expf(v.z - M) / Z;
      p.w = expf(v.w - M) / Z;
      *(float4*)&pch[i * 4] = p;
    }
    __syncthreads();

    if (tid == 0 && sh_cross == 0){
      uint32_t voff = base;
      uint32_t vend = base + SCHUNK * 4u;   // 500 iters of 32 elems

#define QBLK(R0,R1,R2,R3,RQ,OFF) \
  "s_waitcnt lgkmcnt(7)\n\t" \
  "v_add_f32 %[s], %[s], " R0 "\n\t" \
  "v_add_f32 %[s], %[s], " R1 "\n\t" \
  "v_add_f32 %[s], %[s], " R2 "\n\t" \
  "v_add_f32 %[s], %[s], " R3 "\n\t" \
  "ds_read_b128 " RQ ", %[voff] offset:" OFF "\n\t"

      asm volatile(
        "s_waitcnt lgkmcnt(0)\n\t"
        "ds_read_b128 v[40:43], %[voff] offset:0\n\t"
        "ds_read_b128 v[44:47], %[voff] offset:16\n\t"
        "ds_read_b128 v[48:51], %[voff] offset:32\n\t"
        "ds_read_b128 v[52:55], %[voff] offset:48\n\t"
        "ds_read_b128 v[56:59], %[voff] offset:64\n\t"
        "ds_read_b128 v[60:63], %[voff] offset:80\n\t"
        "ds_read_b128 v[64:67], %[voff] offset:96\n\t"
        "ds_read_b128 v[68:71], %[voff] offset:112\n\t"
        "Lscan%=:\n\t"
        "v_mov_b32 %[prev], %[s]\n\t"
        QBLK("v40","v41","v42","v43","v[40:43]","128")
        QBLK("v44","v45","v46","v47","v[44:47]","144")
        QBLK("v48","v49","v50","v51","v[48:51]","160")
        QBLK("v52","v53","v54","v55","v[52:55]","176")
        QBLK("v56","v57","v58","v59","v[56:59]","192")
        QBLK("v60","v61","v62","v63","v[60:63]","208")
        QBLK("v64","v65","v66","v67","v[64:67]","224")
        QBLK("v68","v69","v70","v71","v[68:71]","240")
        "v_add_u32 %[voff], 128, %[voff]\n\t"
        "v_cmp_lt_f32 vcc, 0x3f666666, %[s]\n\t"   // 0.9f < s
        "s_cbranch_vccnz Ldone%=\n\t"
        "v_cmp_lt_u32 vcc, %[voff], %[vend]\n\t"
        "s_cbranch_vccnz Lscan%=\n\t"
        "Ldone%=:\n\t"
        "s_waitcnt lgkmcnt(0)\n\t"
        : [s]"+v"(s), [voff]"+v"(voff), [prev]"+v"(prev)
        : [vend]"v"(vend)
        : "vcc", "memory",
          "v40","v41","v42","v43","v44","v45","v46","v47",
          "v48","v49","v50","v51","v52","v53","v54","v55",
          "v56","v57","v58","v59","v60","v61","v62","v63",
          "v64","v65","v66","v67","v68","v69","v70","v71");
#undef QBLK

      if (s > 0.9f){
        int il0 = (int)((voff - base) >> 2) - 32;  // crossing group start (local)
        float t = prev;                            // exact sum at group start
        int kk = 31;
        for (int q = 0; q < 32; q++){
          t = t + pch[il0 + q];                    // same values, same order
          if (t > 0.9f){ kk = q; break; }
        }
        sh_k = cb + il0 + kk;
        sh_cross = 1;
      }
    }
    __syncthreads();
    if (sh_cross) break;
  }

  if (tid == 0){
    int ks = sh_k;
    float tv = sbuf[ks];
    int jlo = ks;
    while (jlo > 0 && sbuf[jlo - 1] == tv) jlo--;
    thrv[b] = tv;
    thrc[b] = ks + 1 - jlo;   // tokens equal to tv kept (stable index order)
  }
}

// ---------------- phase C: gumbel-max over kept set -----------------------------
__global__ __launch_bounds__(1024) void k_pick(
    const float* __restrict__ logits,
    const float* __restrict__ thrv,
    const int* __restrict__ thrc,
    int* __restrict__ toks,
    int step)
{
  int b = blockIdx.x, tid = threadIdx.x;
  int lane = tid & 63, w = tid >> 6;
  const float* lr = logits + (size_t)b * NVOC;
  __shared__ int wtot[16];
  __shared__ float redv[1024];
  __shared__ int redi[1024];

  float tval = thrv[b];
  int ckeep = thrc[b];

  // rank-among-equals (stable argsort tie order = ascending original index)
  // exclusive prefix via wave shuffle scan + wave totals (2 barriers)
  int stt = tid * 32;
  int en = min(stt + 32, NVOC);
  int eqc = 0;
  for (int i = stt; i < en; i++) eqc += (lr[i] == tval) ? 1 : 0;
  int inc = eqc;
  #pragma unroll
  for (int dd = 1; dd < 64; dd <<= 1){
    int o = __shfl_up(inc, dd);
    if (lane >= dd) inc += o;
  }
  if (lane == 63) wtot[w] = inc;
  __syncthreads();
  int woff = 0;
  #pragma unroll
  for (int ww = 0; ww < 16; ww++) woff += (ww < w) ? wtot[ww] : 0;
  int eqrank = woff + inc - eqc;

  uint32_t fk0, fk1;
  threefry2x32(0u, 42u, 0u, (uint32_t)step, fk0, fk1);   // fold_in(key(42), step)
  float best = -INFINITY;
  int besti = NVOC;
  for (int i = stt; i < en; i++){
    float l = lr[i];
    bool keep;
    if (l > tval) keep = true;
    else if (l == tval){ keep = (eqrank < ckeep); eqrank++; }
    else keep = false;
    if (keep){
      uint32_t o0, o1;
      threefry2x32(fk0, fk1, 0u, (uint32_t)(b * NVOC + i), o0, o1);
      uint32_t bits = o0 ^ o1;
      uint32_t fb = (bits >> 9) | 0x3f800000u;
      float u = __uint_as_float(fb) - 1.0f;
      if (u == 0.0f) u = 1.17549435e-38f;   // minval = tiny
      float gum = -logf(-logf(u));
      float cand = l + gum;
      if (cand > best){ best = cand; besti = i; }
    }
  }
  redv[tid] = best;
  redi[tid] = besti;
  __syncthreads();
  for (int s = 512; s > 0; s >>= 1){
    if (tid < s){
      float ov = redv[tid + s]; int oi = redi[tid + s];
      if (ov > redv[tid] || (ov == redv[tid] && oi < redi[tid])){
        redv[tid] = ov; redi[tid] = oi;
      }
    }
    __syncthreads();
  }
  if (tid == 0) toks[(size_t)b * NSTEPS + step] = redi[0];
}

// ---------------- host launcher -------------------------------------------------
extern "C" void kernel_launch(void* const* d_in, const int* in_sizes, int n_in,
                              void* d_out, int out_size, void* d_ws, size_t ws_size,
                              hipStream_t stream)
{
  (void)in_sizes; (void)n_in; (void)out_size;
  const float* thought = (const float*)d_in[0];
  const float* vfeat   = (const float*)d_in[1];
  const float* emb     = (const float*)d_in[2];
  const float* w_ih0   = (const float*)d_in[3];
  const float* w_hh0   = (const float*)d_in[4];
  const float* b_ih0   = (const float*)d_in[5];
  const float* b_hh0   = (const float*)d_in[6];
  const float* w_ih1   = (const float*)d_in[7];
  const float* w_hh1   = (const float*)d_in[8];
  const float* b_ih1   = (const float*)d_in[9];
  const float* b_hh1   = (const float*)d_in[10];
  const float* gw1     = (const float*)d_in[11];
  const float* gb1     = (const float*)d_in[12];
  const float* gw2     = (const float*)d_in[13];
  const float* gb2     = (const float*)d_in[14];
  const float* out_w   = (const float*)d_in[15];
  const float* out_b   = (const float*)d_in[16];
  const float* vis_w   = (const float*)d_in[17];
  const float* vis_b   = (const float*)d_in[18];
  const float* ln_g    = (const float*)d_in[19];
  const float* ln_b    = (const float*)d_in[20];
  int* toks = (int*)d_out;

  char* ws = (char*)d_ws;
  size_t off = 0;
  auto alloc = [&](size_t bytes) -> void* {
    void* p = ws + off;
    off += (bytes + 255) & ~(size_t)255;
    return p;
  };
  float* vp      = (float*)alloc((size_t)NB * NNV * NH * 4);
  float* h0a     = (float*)alloc((size_t)NH * NB * 4);
  float* h0b     = (float*)alloc((size_t)NH * NB * 4);
  float* c0a     = (float*)alloc((size_t)NH * NB * 4);
  float* c0b     = (float*)alloc((size_t)NH * NB * 4);
  float* h1a     = (float*)alloc((size_t)NH * NB * 4);
  float* h1b     = (float*)alloc((size_t)NH * NB * 4);
  float* c1a     = (float*)alloc((size_t)NH * NB * 4);
  float* c1b     = (float*)alloc((size_t)NH * NB * 4);
  float* o2t     = (float*)alloc((size_t)NH * NB * 4);
  float* logits  = (float*)alloc((size_t)NB * NVOC * 4);
  float* pbuf    = (float*)alloc((size_t)NB * NVOC * 4);      // radix ping
  float* sortbuf = (float*)alloc((size_t)NB * SORTSTRIDE * 4);// radix pong / sorted
  float* stats   = (float*)alloc((size_t)NB * 4 * 4);
  float* thrv    = (float*)alloc((size_t)NB * 4);
  int*   thrc    = (int*)alloc((size_t)NB * 4);
  if (off > ws_size) return;  // insufficient scratch: fail loudly via wrong output

  k_visproj<<<NB * NNV, 256, 0, stream>>>(vfeat, vis_w, vis_b, ln_g, ln_b, vp);
  k_init<<<(NH * NB + 255) / 256, 256, 0, stream>>>(thought, h0a, c0a, h1a, c1a);

  for (int step = 0; step < NSTEPS; step++){
    float *h0r, *h0w, *c0r, *c0w, *h1r, *h1w, *c1r, *c1w;
    if ((step & 1) == 0){
      h0r = h0a; h0w = h0b; c0r = c0a; c0w = c0b;
      h1r = h1a; h1w = h1b; c1r = c1a; c1w = c1b;
    } else {
      h0r = h0b; h0w = h0a; c0r = c0b; c0w = c0a;
      h1r = h1b; h1w = h1a; c1r = c1b; c1w = c1a;
    }
    k_lstm<NE><<<dim3(32, 2), 256, 0, stream>>>(
        w_ih0, w_hh0, b_ih0, b_hh0, emb, toks, step, h0r, c0r, h0w, c0w);
    k_lstm<NH><<<dim3(32, 2), 256, 0, stream>>>(
        w_ih1, w_hh1, b_ih1, b_hh1, h0w, toks, step, h1r, c1r, h1w, c1w);
    k_gateattn<<<NB, 256, 0, stream>>>(h1w, gw1, gb1, gw2, gb2, vp, o2t);
    k_logits<<<NVOC / 64, 256, 0, stream>>>(o2t, out_w, out_b, toks, step, logits);
    k_rowstats<<<NB, 256, 0, stream>>>(logits, stats);
    k_radix<<<NB, 1024, 0, stream>>>(logits, pbuf, sortbuf);
    k_scan<<<NB, 1024, 0, stream>>>(sortbuf, stats, thrv, thrc);
    k_pick<<<NB, 1024, 0, stream>>>(logits, thrv, thrc, toks, step);
  }
}